// Round 16
// baseline (440.528 us; speedup 1.0000x reference)
//
#include <hip/hip_runtime.h>
#include <stdint.h>

// ---------------------------------------------------------------------------
// 2-layer GCN: relu(gcn(x,W1,b1)) -> batchnorm -> relu(gcn(.,W2,b2))
// n=100000, E=1.6M, f_in=25, hid=128.
// R2: parallel scan (947 -> 681). R6: gemm2 tile + bf16 h (681 -> 593).
// R10: XCD-partitioned direct scatter (593 -> 546).
// R14: 8-deep pipelined propagate gather (546 -> 467).
// R15: gemm2 -> MFMA bf16 (467 -> 415).
// R16: scatter WRITE was still 12x amplified (77MB for 6.4MB edge_src):
//     each group streams 25.6MB edge_index through its 4MB XCD L2, evicting
//     partially-assembled edge_src lines (reads thrash write-coalescing).
//     Fix: non-temporal (nt) loads for the streaming edge_index reads in
//     scatter/count; stores stay cached. + float4 bn_stats (from R13).
// ---------------------------------------------------------------------------

#define HID 128

typedef short bf16x8 __attribute__((ext_vector_type(8)));
typedef float f32x4 __attribute__((ext_vector_type(4)));

__device__ __forceinline__ unsigned short f2bf(float f) {
    unsigned int u = __float_as_uint(f);
    unsigned int r = (u + 0x7FFFu + ((u >> 16) & 1u)) >> 16;  // RNE
    return (unsigned short)r;
}
__device__ __forceinline__ unsigned int pack2bf(float lo, float hi) {
    return (unsigned int)f2bf(lo) | ((unsigned int)f2bf(hi) << 16);
}
__device__ __forceinline__ float bflo(unsigned int v) { return __uint_as_float(v << 16); }
__device__ __forceinline__ float bfhi(unsigned int v) { return __uint_as_float(v & 0xffff0000u); }

// --- detect whether edge_index buffer is int64 or int32 --------------------
__global__ void detect_kernel(const unsigned int* __restrict__ w, int* __restrict__ mode, int nwords) {
    __shared__ int any;
    if (threadIdx.x == 0) any = 0;
    __syncthreads();
    for (int i = threadIdx.x * 2 + 1; i < nwords && i < 8192; i += 512) {
        if (w[i] != 0) atomicOr(&any, 1);
    }
    __syncthreads();
    if (threadIdx.x == 0) *mode = any ? 0 : 1;  // 1 => int64 layout
}

__device__ __forceinline__ int load_idx(const void* ei, size_t i, int mode) {
    return mode ? (int)((const long long*)ei)[i] : ((const int*)ei)[i];
}
// non-temporal (streaming, evict-first) variant
__device__ __forceinline__ int load_idx_nt(const void* ei, size_t i, int mode) {
    return mode ? (int)__builtin_nontemporal_load(((const long long*)ei) + i)
                : __builtin_nontemporal_load(((const int*)ei) + i);
}

// --- in-degree histogram (targets = col) -----------------------------------
__global__ void count_kernel(const void* __restrict__ ei, const int* __restrict__ modep,
                             int* __restrict__ cnt, int E) {
    int e = blockIdx.x * blockDim.x + threadIdx.x;
    if (e >= E) return;
    int mode = *modep;
    int c = load_idx_nt(ei, (size_t)E + e, mode);
    atomicAdd(&cnt[c], 1);  // non-returning: HW wave-coalesced
}

// --- scan phase 1: per-256-chunk sums --------------------------------------
__global__ __launch_bounds__(256) void scan_partial_kernel(const int* __restrict__ cnt,
                                                           int* __restrict__ blocksum, int n) {
    int i = blockIdx.x * 256 + threadIdx.x;
    int s = (i < n) ? cnt[i] : 0;
    #pragma unroll
    for (int off = 32; off > 0; off >>= 1) s += __shfl_down(s, off);
    __shared__ int ls[4];
    if ((threadIdx.x & 63) == 0) ls[threadIdx.x >> 6] = s;
    __syncthreads();
    if (threadIdx.x == 0) blocksum[blockIdx.x] = ls[0] + ls[1] + ls[2] + ls[3];
}

// --- scan phase 2: scan block sums (nb <= 1024) ----------------------------
__global__ __launch_bounds__(1024) void scan_blocksums_kernel(const int* __restrict__ blocksum,
                                                              int* __restrict__ blockoff,
                                                              int* __restrict__ rowptr,
                                                              int nb, int n) {
    __shared__ int s[1024];
    int t = threadIdx.x;
    int own = (t < nb) ? blocksum[t] : 0;
    s[t] = own;
    __syncthreads();
    for (int off = 1; off < 1024; off <<= 1) {
        int v = s[t] + ((t >= off) ? s[t - off] : 0);
        __syncthreads();
        s[t] = v;
        __syncthreads();
    }
    if (t < nb) blockoff[t] = s[t] - own;  // exclusive
    if (t == 1023) rowptr[n] = s[1023];    // total
}

// --- scan phase 3: element prefix + dinv + per-node cursor init ------------
__global__ __launch_bounds__(256) void scan_finalize_kernel(const int* __restrict__ cnt,
                                                            const int* __restrict__ blockoff,
                                                            int* __restrict__ rowptr,
                                                            int* __restrict__ cursor,
                                                            float* __restrict__ dinv, int n) {
    int t = threadIdx.x;
    int i = blockIdx.x * 256 + t;
    int own = (i < n) ? cnt[i] : 0;
    __shared__ int s[256];
    s[t] = own;
    __syncthreads();
    for (int off = 1; off < 256; off <<= 1) {
        int x = s[t] + ((t >= off) ? s[t - off] : 0);
        __syncthreads();
        s[t] = x;
        __syncthreads();
    }
    if (i < n) {
        int e0 = blockoff[blockIdx.x] + s[t] - own;
        rowptr[i] = e0;
        cursor[i] = e0;
        dinv[i] = rsqrtf((float)(own + 1));  // +1 self loop
    }
}

// --- XCD-partitioned direct scatter (nt streaming reads) -------------------
__global__ __launch_bounds__(256) void scatter_part_kernel(
    const void* __restrict__ ei, const int* __restrict__ modep,
    int* __restrict__ cursor, int* __restrict__ edge_src, int E) {
    int g = blockIdx.x & 7;
    int cb = blockIdx.x >> 3;          // chunk index within group
    int nchunks = gridDim.x >> 3;      // blocks per group
    int mode = *modep;
    int stride = nchunks * 256;
    for (int e = cb * 256 + threadIdx.x; e < E; e += stride) {
        int c = load_idx_nt(ei, (size_t)E + e, mode);
        if (((c >> 4) & 7) != g) continue;
        int r = load_idx_nt(ei, (size_t)e, mode);
        int pos = atomicAdd(&cursor[c], 1);
        edge_src[pos] = r;
    }
}

// --- GEMM1: h = bf16(x @ W1)   (K=25, W1 staged in LDS) --------------------
__global__ __launch_bounds__(256) void gemm1_kernel(const float* __restrict__ x,
                                                    const float* __restrict__ W,
                                                    unsigned short* __restrict__ h, int n) {
    __shared__ float lw[25 * HID];
    for (int i = threadIdx.x; i < 25 * HID; i += 256) lw[i] = W[i];
    __syncthreads();
    int g = threadIdx.x >> 7, c = threadIdx.x & 127;
    for (int r = blockIdx.x * 2 + g; r < n; r += gridDim.x * 2) {
        const float* xr = x + (size_t)r * 25;
        float acc = 0.f;
        #pragma unroll
        for (int k = 0; k < 25; ++k) acc = fmaf(xr[k], lw[k * HID + c], acc);
        h[(size_t)r * HID + c] = f2bf(acc);
    }
}

// --- propagation: 8-way unrolled gather loop -------------------------------
__global__ __launch_bounds__(256) void propagate_kernel(
    const unsigned short* __restrict__ h, const int* __restrict__ rowptr,
    const int* __restrict__ edge_src, const float* __restrict__ dinv,
    const float* __restrict__ bias, float* __restrict__ out, int n) {
    int wid = (blockIdx.x * 256 + threadIdx.x) >> 6;
    if (wid >= n) return;
    int lane = threadIdx.x & 63;
    int beg = rowptr[wid], end = rowptr[wid + 1];
    float dc = dinv[wid];
    float ax = 0.f, ay = 0.f;
    const unsigned int* hp = (const unsigned int*)h;  // 64 uints per row
    for (int b = beg; b < end; b += 64) {
        int m = end - b; if (m > 64) m = 64;
        int s = 0; float w = 0.f;
        if (lane < m) { s = edge_src[b + lane]; w = dinv[s]; }
        int j = 0;
        for (; j + 8 <= m; j += 8) {
            int s0 = __shfl(s, j + 0), s1 = __shfl(s, j + 1);
            int s2 = __shfl(s, j + 2), s3 = __shfl(s, j + 3);
            int s4 = __shfl(s, j + 4), s5 = __shfl(s, j + 5);
            int s6 = __shfl(s, j + 6), s7 = __shfl(s, j + 7);
            unsigned int v0 = hp[(size_t)s0 * 64 + lane];
            unsigned int v1 = hp[(size_t)s1 * 64 + lane];
            unsigned int v2 = hp[(size_t)s2 * 64 + lane];
            unsigned int v3 = hp[(size_t)s3 * 64 + lane];
            unsigned int v4 = hp[(size_t)s4 * 64 + lane];
            unsigned int v5 = hp[(size_t)s5 * 64 + lane];
            unsigned int v6 = hp[(size_t)s6 * 64 + lane];
            unsigned int v7 = hp[(size_t)s7 * 64 + lane];
            float w0 = __shfl(w, j + 0), w1 = __shfl(w, j + 1);
            float w2 = __shfl(w, j + 2), w3 = __shfl(w, j + 3);
            float w4 = __shfl(w, j + 4), w5 = __shfl(w, j + 5);
            float w6 = __shfl(w, j + 6), w7 = __shfl(w, j + 7);
            ax = fmaf(bflo(v0), w0, ax); ay = fmaf(bfhi(v0), w0, ay);
            ax = fmaf(bflo(v1), w1, ax); ay = fmaf(bfhi(v1), w1, ay);
            ax = fmaf(bflo(v2), w2, ax); ay = fmaf(bfhi(v2), w2, ay);
            ax = fmaf(bflo(v3), w3, ax); ay = fmaf(bfhi(v3), w3, ay);
            ax = fmaf(bflo(v4), w4, ax); ay = fmaf(bfhi(v4), w4, ay);
            ax = fmaf(bflo(v5), w5, ax); ay = fmaf(bfhi(v5), w5, ay);
            ax = fmaf(bflo(v6), w6, ax); ay = fmaf(bfhi(v6), w6, ay);
            ax = fmaf(bflo(v7), w7, ax); ay = fmaf(bfhi(v7), w7, ay);
        }
        for (; j < m; ++j) {
            int sj = __shfl(s, j);
            float wj = __shfl(w, j);
            unsigned int v = hp[(size_t)sj * 64 + lane];
            ax = fmaf(bflo(v), wj, ax);
            ay = fmaf(bfhi(v), wj, ay);
        }
    }
    {   // self loop
        unsigned int v = hp[(size_t)wid * 64 + lane];
        ax = fmaf(bflo(v), dc, ax);
        ay = fmaf(bfhi(v), dc, ay);
    }
    float bx = bias[lane * 2], by = bias[lane * 2 + 1];
    ax = fmaxf(fmaf(ax, dc, bx), 0.f);
    ay = fmaxf(fmaf(ay, dc, by), 0.f);
    *(float2*)(out + (size_t)wid * HID + lane * 2) = make_float2(ax, ay);
}

// --- BN stats: per-channel sum and sumsq (float4 vectorized) ---------------
__global__ __launch_bounds__(256) void bn_stats_kernel(const float* __restrict__ y,
                                                       float* __restrict__ sum,
                                                       float* __restrict__ sumsq, int n) {
    int c4 = (threadIdx.x & 31) * 4;
    int g = threadIdx.x >> 5;  // 8 row-groups
    float4 s = make_float4(0.f, 0.f, 0.f, 0.f);
    float4 s2 = make_float4(0.f, 0.f, 0.f, 0.f);
    for (int r = blockIdx.x * 8 + g; r < n; r += gridDim.x * 8) {
        float4 v = *(const float4*)(y + (size_t)r * HID + c4);
        s.x += v.x; s.y += v.y; s.z += v.z; s.w += v.w;
        s2.x = fmaf(v.x, v.x, s2.x); s2.y = fmaf(v.y, v.y, s2.y);
        s2.z = fmaf(v.z, v.z, s2.z); s2.w = fmaf(v.w, v.w, s2.w);
    }
    __shared__ float4 ls[256], ls2[256];
    ls[threadIdx.x] = s; ls2[threadIdx.x] = s2;
    __syncthreads();
    if (threadIdx.x < 32) {
        #pragma unroll
        for (int i = 1; i < 8; ++i) {
            float4 a = ls[threadIdx.x + i * 32], b = ls2[threadIdx.x + i * 32];
            s.x += a.x; s.y += a.y; s.z += a.z; s.w += a.w;
            s2.x += b.x; s2.y += b.y; s2.z += b.z; s2.w += b.w;
        }
        atomicAdd(&sum[c4 + 0], s.x);  atomicAdd(&sum[c4 + 1], s.y);
        atomicAdd(&sum[c4 + 2], s.z);  atomicAdd(&sum[c4 + 3], s.w);
        atomicAdd(&sumsq[c4 + 0], s2.x); atomicAdd(&sumsq[c4 + 1], s2.y);
        atomicAdd(&sumsq[c4 + 2], s2.z); atomicAdd(&sumsq[c4 + 3], s2.w);
    }
}

__global__ void bn_finalize_kernel(const float* __restrict__ sum, const float* __restrict__ sumsq,
                                   const float* __restrict__ gamma, const float* __restrict__ beta,
                                   float* __restrict__ scale, float* __restrict__ shift, float inv_n) {
    int c = threadIdx.x;
    float mean = sum[c] * inv_n;
    float var = sumsq[c] * inv_n - mean * mean;
    float sc = gamma[c] * rsqrtf(var + 1e-5f);
    scale[c] = sc;
    shift[c] = beta[c] - mean * sc;
}

// --- W2 transpose + bf16 cast: Wt[c][k] = bf16(W2[k][c]) -------------------
__global__ __launch_bounds__(256) void wt_kernel(const float* __restrict__ W,
                                                 unsigned short* __restrict__ Wt) {
    int idx = blockIdx.x * 256 + threadIdx.x;
    int c = idx >> 7, k = idx & 127;
    Wt[c * 128 + k] = f2bf(W[k * 128 + c]);
}

// --- GEMM2 via MFMA: h2 = bf16(bn(y1) @ W2), K=128 -------------------------
__global__ __launch_bounds__(256) void gemm2_mfma_kernel(
    const float* __restrict__ y, const unsigned short* __restrict__ Wt,
    const float* __restrict__ scale, const float* __restrict__ shift,
    unsigned short* __restrict__ out, int n) {
    __shared__ unsigned short lwt[128 * 136];
    __shared__ unsigned short ly[128 * 136];
    int t = threadIdx.x;
    int base = blockIdx.x * 128;

    // stage Wt: 128 rows x 128 bf16 (64 uints/row), coalesced; LDS stride 68 uints
    {
        const unsigned int* w32 = (const unsigned int*)Wt;
        unsigned int* l32 = (unsigned int*)lwt;
        #pragma unroll
        for (int i = 0; i < 32; ++i) {
            int idx = t + i * 256;
            int r = idx >> 6, cp = idx & 63;
            l32[r * 68 + cp] = w32[r * 64 + cp];
        }
    }
    // stage y tile with BN + bf16 cvt: 2 threads/row, 64 k each
    {
        int r = t >> 1, hh = t & 1;
        int gr = base + r;
        unsigned int* l32 = (unsigned int*)ly;
        const float4* yrow = (const float4*)(y + (size_t)gr * HID + hh * 64);
        #pragma unroll
        for (int j = 0; j < 16; ++j) {
            float4 v = make_float4(0.f, 0.f, 0.f, 0.f);
            if (gr < n) v = yrow[j];
            int gk = hh * 64 + j * 4;
            float a0 = fmaf(v.x, scale[gk + 0], shift[gk + 0]);
            float a1 = fmaf(v.y, scale[gk + 1], shift[gk + 1]);
            float a2 = fmaf(v.z, scale[gk + 2], shift[gk + 2]);
            float a3 = fmaf(v.w, scale[gk + 3], shift[gk + 3]);
            l32[r * 68 + hh * 32 + j * 2 + 0] = pack2bf(a0, a1);
            l32[r * 68 + hh * 32 + j * 2 + 1] = pack2bf(a2, a3);
        }
    }
    __syncthreads();

    int w = t >> 6, lane = t & 63;
    int li = lane & 15, lg = lane >> 4;
    f32x4 acc[2][8];
    #pragma unroll
    for (int a = 0; a < 2; ++a)
        #pragma unroll
        for (int b = 0; b < 8; ++b) acc[a][b] = (f32x4){0.f, 0.f, 0.f, 0.f};

    #pragma unroll
    for (int ks = 0; ks < 4; ++ks) {
        int kb = ks * 32 + lg * 8;
        bf16x8 af[2], bfr[8];
        #pragma unroll
        for (int rt = 0; rt < 2; ++rt)
            af[rt] = *(const bf16x8*)&ly[(w * 32 + rt * 16 + li) * 136 + kb];
        #pragma unroll
        for (int cf = 0; cf < 8; ++cf)
            bfr[cf] = *(const bf16x8*)&lwt[(cf * 16 + li) * 136 + kb];
        #pragma unroll
        for (int rt = 0; rt < 2; ++rt)
            #pragma unroll
            for (int cf = 0; cf < 8; ++cf)
                acc[rt][cf] = __builtin_amdgcn_mfma_f32_16x16x32_bf16(
                    af[rt], bfr[cf], acc[rt][cf], 0, 0, 0);
    }

    // epilogue: D row = (lane>>4)*4 + reg, col = cf*16 + (lane&15)
    #pragma unroll
    for (int rt = 0; rt < 2; ++rt) {
        #pragma unroll
        for (int reg = 0; reg < 4; ++reg) {
            int gr = base + w * 32 + rt * 16 + lg * 4 + reg;
            if (gr < n) {
                #pragma unroll
                for (int cf = 0; cf < 8; ++cf)
                    out[(size_t)gr * HID + cf * 16 + li] = f2bf(acc[rt][cf][reg]);
            }
        }
    }
}

extern "C" void kernel_launch(void* const* d_in, const int* in_sizes, int n_in,
                              void* d_out, int out_size, void* d_ws, size_t ws_size,
                              hipStream_t stream) {
    const float* x     = (const float*)d_in[0];
    const void*  ei    = d_in[1];
    const float* W1    = (const float*)d_in[2];
    const float* b1    = (const float*)d_in[3];
    const float* gamma = (const float*)d_in[4];
    const float* beta  = (const float*)d_in[5];
    const float* W2    = (const float*)d_in[6];
    const float* b2    = (const float*)d_in[7];
    float* out = (float*)d_out;

    const int f_in = 25;
    int n = in_sizes[0] / f_in;
    int E = in_sizes[1] / 2;
    int nb = (n + 255) >> 8;    // 256-node scan chunks

    char* ws = (char*)d_ws;
    size_t off = 0;
    auto alloc = [&](size_t bytes) -> void* {
        void* p = ws + off;
        off += (bytes + 511) & ~(size_t)511;
        return p;
    };
    int*   cnt        = (int*)alloc((size_t)n * 4);
    int*   rowptr     = (int*)alloc(((size_t)n + 1) * 4);
    int*   cursor     = (int*)alloc((size_t)n * 4);
    float* dinv       = (float*)alloc((size_t)n * 4);
    int*   edge_src   = (int*)alloc((size_t)E * 4);
    float* bnacc      = (float*)alloc(256 * 4);   // sum[128] ++ sumsq[128]
    float* sclshift   = (float*)alloc(256 * 4);   // scale[128] ++ shift[128]
    int*   mode       = (int*)alloc(4);
    int*   blocksum   = (int*)alloc((size_t)nb * 4);
    int*   blockoff   = (int*)alloc((size_t)nb * 4);
    unsigned short* Wt = (unsigned short*)alloc(128 * 128 * 2);  // bf16 W2^T
    unsigned short* h  = (unsigned short*)alloc((size_t)n * HID * 2);  // bf16 h1/h2

    hipMemsetAsync(cnt, 0, (size_t)n * 4, stream);
    hipMemsetAsync(bnacc, 0, 256 * 4, stream);

    detect_kernel<<<1, 256, 0, stream>>>((const unsigned int*)ei, mode, 2 * E);
    count_kernel<<<(E + 255) / 256, 256, 0, stream>>>(ei, mode, cnt, E);
    scan_partial_kernel<<<nb, 256, 0, stream>>>(cnt, blocksum, n);
    scan_blocksums_kernel<<<1, 1024, 0, stream>>>(blocksum, blockoff, rowptr, nb, n);
    scan_finalize_kernel<<<nb, 256, 0, stream>>>(cnt, blockoff, rowptr, cursor, dinv, n);
    scatter_part_kernel<<<8 * 784, 256, 0, stream>>>(ei, mode, cursor, edge_src, E);

    // layer 1: h1 = bf16(x@W1) ; y1 = relu(prop(h1) + b1) -> d_out (fp32)
    gemm1_kernel<<<4096, 256, 0, stream>>>(x, W1, h, n);
    propagate_kernel<<<(n + 3) / 4, 256, 0, stream>>>(h, rowptr, edge_src, dinv, b1, out, n);

    // batchnorm stats on y1
    bn_stats_kernel<<<512, 256, 0, stream>>>(out, bnacc, bnacc + 128, n);
    bn_finalize_kernel<<<1, 128, 0, stream>>>(bnacc, bnacc + 128, gamma, beta,
                                              sclshift, sclshift + 128, 1.0f / (float)n);

    // layer 2: h2 = bf16(bn(y1)@W2) via MFMA ; out = relu(prop(h2) + b2)
    wt_kernel<<<64, 256, 0, stream>>>(W2, Wt);
    gemm2_mfma_kernel<<<(n + 127) / 128, 256, 0, stream>>>(out, Wt, sclshift, sclshift + 128, h, n);
    propagate_kernel<<<(n + 3) / 4, 256, 0, stream>>>(h, rowptr, edge_src, dinv, b2, out, n);
}

// Round 17
// 422.844 us; speedup vs baseline: 1.0418x; 1.0418x over previous
//
#include <hip/hip_runtime.h>
#include <stdint.h>

// ---------------------------------------------------------------------------
// 2-layer GCN: relu(gcn(x,W1,b1)) -> batchnorm -> relu(gcn(.,W2,b2))
// n=100000, E=1.6M, f_in=25, hid=128.
// R2: parallel scan (947 -> 681). R6: gemm2 tile + bf16 h (681 -> 593).
// R10: XCD-partitioned direct scatter (593 -> 546).
// R14: 8-deep pipelined propagate gather (546 -> 467).
// R15: gemm2 -> MFMA bf16 (467 -> 415).
// R16 FAILED (415->440): nt loads didn't fix write amplification. REVERTED.
//     Root cause understood: a node's ~16 edge writes span the whole kernel
//     lifetime; no cache policy holds a partial line that long under 25.6MB
//     of streaming reads.
// R17: 3-phase block-private queue binning shortens write lifetimes:
//     count also tallies qcnt[block][group] (LDS, group=(tgt>>4)&7);
//     scan_q -> block-private queue ranges (no global returning atomics);
//     bin: block appends (r,c) to its contiguous 25KB region (clean writes);
//     scatter_c: group g's blocks (bid&7==g) consume g's 1.6MB queue
//     (L2-resident, no evictions) -> edge_src lines coalesce fully.
// ---------------------------------------------------------------------------

#define HID 128
#define NBLK_BIN 512

typedef short bf16x8 __attribute__((ext_vector_type(8)));
typedef float f32x4 __attribute__((ext_vector_type(4)));

__device__ __forceinline__ unsigned short f2bf(float f) {
    unsigned int u = __float_as_uint(f);
    unsigned int r = (u + 0x7FFFu + ((u >> 16) & 1u)) >> 16;  // RNE
    return (unsigned short)r;
}
__device__ __forceinline__ unsigned int pack2bf(float lo, float hi) {
    return (unsigned int)f2bf(lo) | ((unsigned int)f2bf(hi) << 16);
}
__device__ __forceinline__ float bflo(unsigned int v) { return __uint_as_float(v << 16); }
__device__ __forceinline__ float bfhi(unsigned int v) { return __uint_as_float(v & 0xffff0000u); }

// --- detect whether edge_index buffer is int64 or int32 --------------------
__global__ void detect_kernel(const unsigned int* __restrict__ w, int* __restrict__ mode, int nwords) {
    __shared__ int any;
    if (threadIdx.x == 0) any = 0;
    __syncthreads();
    for (int i = threadIdx.x * 2 + 1; i < nwords && i < 8192; i += 512) {
        if (w[i] != 0) atomicOr(&any, 1);
    }
    __syncthreads();
    if (threadIdx.x == 0) *mode = any ? 0 : 1;  // 1 => int64 layout
}

__device__ __forceinline__ int load_idx(const void* ei, size_t i, int mode) {
    return mode ? (int)((const long long*)ei)[i] : ((const int*)ei)[i];
}

// --- count: per-node histogram + per-(block,group) queue counts ------------
__global__ __launch_bounds__(256) void count_kernel(const void* __restrict__ ei,
                                                    const int* __restrict__ modep,
                                                    int* __restrict__ cnt,
                                                    int* __restrict__ qcnt,
                                                    int E, int CHUNK) {
    __shared__ int gc[8];
    if (threadIdx.x < 8) gc[threadIdx.x] = 0;
    __syncthreads();
    int mode = *modep;
    int beg = blockIdx.x * CHUNK;
    int end = beg + CHUNK; if (end > E) end = E;
    for (int e = beg + threadIdx.x; e < end; e += 256) {
        int c = load_idx(ei, (size_t)E + e, mode);
        atomicAdd(&cnt[c], 1);          // non-returning: HW wave-coalesced
        atomicAdd(&gc[(c >> 4) & 7], 1);
    }
    __syncthreads();
    if (threadIdx.x < 8) qcnt[blockIdx.x * 8 + threadIdx.x] = gc[threadIdx.x];
}

// --- scan_q: exclusive scan of qcnt[NBLK_BIN*8] -> qoff (+ total) ----------
__global__ __launch_bounds__(1024) void scan_q_kernel(const int* __restrict__ qcnt,
                                                      int* __restrict__ qoff) {
    const int NQ = NBLK_BIN * 8;  // 4096
    __shared__ int s[1024];
    int t = threadIdx.x;
    int base = t * 4;
    int v[4]; int own = 0;
    #pragma unroll
    for (int i = 0; i < 4; ++i) { v[i] = qcnt[base + i]; own += v[i]; }
    s[t] = own;
    __syncthreads();
    for (int off = 1; off < 1024; off <<= 1) {
        int x = s[t] + ((t >= off) ? s[t - off] : 0);
        __syncthreads();
        s[t] = x;
        __syncthreads();
    }
    int e = s[t] - own;  // exclusive
    #pragma unroll
    for (int i = 0; i < 4; ++i) { qoff[base + i] = e; e += v[i]; }
    if (t == 1023) qoff[NQ] = s[1023];
}

// --- scan phase 1: per-256-chunk sums --------------------------------------
__global__ __launch_bounds__(256) void scan_partial_kernel(const int* __restrict__ cnt,
                                                           int* __restrict__ blocksum, int n) {
    int i = blockIdx.x * 256 + threadIdx.x;
    int s = (i < n) ? cnt[i] : 0;
    #pragma unroll
    for (int off = 32; off > 0; off >>= 1) s += __shfl_down(s, off);
    __shared__ int ls[4];
    if ((threadIdx.x & 63) == 0) ls[threadIdx.x >> 6] = s;
    __syncthreads();
    if (threadIdx.x == 0) blocksum[blockIdx.x] = ls[0] + ls[1] + ls[2] + ls[3];
}

// --- scan phase 2: scan block sums (nb <= 1024) ----------------------------
__global__ __launch_bounds__(1024) void scan_blocksums_kernel(const int* __restrict__ blocksum,
                                                              int* __restrict__ blockoff,
                                                              int* __restrict__ rowptr,
                                                              int nb, int n) {
    __shared__ int s[1024];
    int t = threadIdx.x;
    int own = (t < nb) ? blocksum[t] : 0;
    s[t] = own;
    __syncthreads();
    for (int off = 1; off < 1024; off <<= 1) {
        int v = s[t] + ((t >= off) ? s[t - off] : 0);
        __syncthreads();
        s[t] = v;
        __syncthreads();
    }
    if (t < nb) blockoff[t] = s[t] - own;  // exclusive
    if (t == 1023) rowptr[n] = s[1023];    // total
}

// --- scan phase 3: element prefix + dinv + per-node cursor init ------------
__global__ __launch_bounds__(256) void scan_finalize_kernel(const int* __restrict__ cnt,
                                                            const int* __restrict__ blockoff,
                                                            int* __restrict__ rowptr,
                                                            int* __restrict__ cursor,
                                                            float* __restrict__ dinv, int n) {
    int t = threadIdx.x;
    int i = blockIdx.x * 256 + t;
    int own = (i < n) ? cnt[i] : 0;
    __shared__ int s[256];
    s[t] = own;
    __syncthreads();
    for (int off = 1; off < 256; off <<= 1) {
        int x = s[t] + ((t >= off) ? s[t - off] : 0);
        __syncthreads();
        s[t] = x;
        __syncthreads();
    }
    if (i < n) {
        int e0 = blockoff[blockIdx.x] + s[t] - own;
        rowptr[i] = e0;
        cursor[i] = e0;
        dinv[i] = rsqrtf((float)(own + 1));  // +1 self loop
    }
}

// --- bin: append (r,c) into block-private queue runs (8 per block) ---------
__global__ __launch_bounds__(256) void bin_kernel(const void* __restrict__ ei,
                                                  const int* __restrict__ modep,
                                                  const int* __restrict__ qoff,
                                                  uint2* __restrict__ pairs,
                                                  int E, int CHUNK) {
    __shared__ int cur[8];
    if (threadIdx.x < 8) cur[threadIdx.x] = qoff[blockIdx.x * 8 + threadIdx.x];
    __syncthreads();
    int mode = *modep;
    int beg = blockIdx.x * CHUNK;
    int end = beg + CHUNK; if (end > E) end = E;
    for (int e = beg + threadIdx.x; e < end; e += 256) {
        int c = load_idx(ei, (size_t)E + e, mode);
        int r = load_idx(ei, (size_t)e, mode);
        int pos = atomicAdd(&cur[(c >> 4) & 7], 1);
        pairs[pos] = make_uint2((unsigned)r, (unsigned)c);
    }
}

// --- scatter_c: group g (bid&7==g, one XCD) consumes g's queue segments ----
// Per-group data ~1.6MB => L2-resident; edge_src lines coalesce fully.
__global__ __launch_bounds__(256) void scatter_c_kernel(const uint2* __restrict__ pairs,
                                                        const int* __restrict__ qoff,
                                                        int* __restrict__ cursor,
                                                        int* __restrict__ edge_src) {
    int g = blockIdx.x & 7;
    int k = blockIdx.x >> 3;
    int K = gridDim.x >> 3;
    for (int b = k; b < NBLK_BIN; b += K) {
        int qbeg = qoff[b * 8 + g];
        int qend = qoff[b * 8 + g + 1];
        for (int i = qbeg + threadIdx.x; i < qend; i += 256) {
            uint2 p = pairs[i];
            int pos = atomicAdd(&cursor[p.y], 1);
            edge_src[pos] = (int)p.x;
        }
    }
}

// --- GEMM1: h = bf16(x @ W1)   (K=25, W1 staged in LDS) --------------------
__global__ __launch_bounds__(256) void gemm1_kernel(const float* __restrict__ x,
                                                    const float* __restrict__ W,
                                                    unsigned short* __restrict__ h, int n) {
    __shared__ float lw[25 * HID];
    for (int i = threadIdx.x; i < 25 * HID; i += 256) lw[i] = W[i];
    __syncthreads();
    int g = threadIdx.x >> 7, c = threadIdx.x & 127;
    for (int r = blockIdx.x * 2 + g; r < n; r += gridDim.x * 2) {
        const float* xr = x + (size_t)r * 25;
        float acc = 0.f;
        #pragma unroll
        for (int k = 0; k < 25; ++k) acc = fmaf(xr[k], lw[k * HID + c], acc);
        h[(size_t)r * HID + c] = f2bf(acc);
    }
}

// --- propagation: 8-way unrolled gather loop -------------------------------
__global__ __launch_bounds__(256) void propagate_kernel(
    const unsigned short* __restrict__ h, const int* __restrict__ rowptr,
    const int* __restrict__ edge_src, const float* __restrict__ dinv,
    const float* __restrict__ bias, float* __restrict__ out, int n) {
    int wid = (blockIdx.x * 256 + threadIdx.x) >> 6;
    if (wid >= n) return;
    int lane = threadIdx.x & 63;
    int beg = rowptr[wid], end = rowptr[wid + 1];
    float dc = dinv[wid];
    float ax = 0.f, ay = 0.f;
    const unsigned int* hp = (const unsigned int*)h;  // 64 uints per row
    for (int b = beg; b < end; b += 64) {
        int m = end - b; if (m > 64) m = 64;
        int s = 0; float w = 0.f;
        if (lane < m) { s = edge_src[b + lane]; w = dinv[s]; }
        int j = 0;
        for (; j + 8 <= m; j += 8) {
            int s0 = __shfl(s, j + 0), s1 = __shfl(s, j + 1);
            int s2 = __shfl(s, j + 2), s3 = __shfl(s, j + 3);
            int s4 = __shfl(s, j + 4), s5 = __shfl(s, j + 5);
            int s6 = __shfl(s, j + 6), s7 = __shfl(s, j + 7);
            unsigned int v0 = hp[(size_t)s0 * 64 + lane];
            unsigned int v1 = hp[(size_t)s1 * 64 + lane];
            unsigned int v2 = hp[(size_t)s2 * 64 + lane];
            unsigned int v3 = hp[(size_t)s3 * 64 + lane];
            unsigned int v4 = hp[(size_t)s4 * 64 + lane];
            unsigned int v5 = hp[(size_t)s5 * 64 + lane];
            unsigned int v6 = hp[(size_t)s6 * 64 + lane];
            unsigned int v7 = hp[(size_t)s7 * 64 + lane];
            float w0 = __shfl(w, j + 0), w1 = __shfl(w, j + 1);
            float w2 = __shfl(w, j + 2), w3 = __shfl(w, j + 3);
            float w4 = __shfl(w, j + 4), w5 = __shfl(w, j + 5);
            float w6 = __shfl(w, j + 6), w7 = __shfl(w, j + 7);
            ax = fmaf(bflo(v0), w0, ax); ay = fmaf(bfhi(v0), w0, ay);
            ax = fmaf(bflo(v1), w1, ax); ay = fmaf(bfhi(v1), w1, ay);
            ax = fmaf(bflo(v2), w2, ax); ay = fmaf(bfhi(v2), w2, ay);
            ax = fmaf(bflo(v3), w3, ax); ay = fmaf(bfhi(v3), w3, ay);
            ax = fmaf(bflo(v4), w4, ax); ay = fmaf(bfhi(v4), w4, ay);
            ax = fmaf(bflo(v5), w5, ax); ay = fmaf(bfhi(v5), w5, ay);
            ax = fmaf(bflo(v6), w6, ax); ay = fmaf(bfhi(v6), w6, ay);
            ax = fmaf(bflo(v7), w7, ax); ay = fmaf(bfhi(v7), w7, ay);
        }
        for (; j < m; ++j) {
            int sj = __shfl(s, j);
            float wj = __shfl(w, j);
            unsigned int v = hp[(size_t)sj * 64 + lane];
            ax = fmaf(bflo(v), wj, ax);
            ay = fmaf(bfhi(v), wj, ay);
        }
    }
    {   // self loop
        unsigned int v = hp[(size_t)wid * 64 + lane];
        ax = fmaf(bflo(v), dc, ax);
        ay = fmaf(bfhi(v), dc, ay);
    }
    float bx = bias[lane * 2], by = bias[lane * 2 + 1];
    ax = fmaxf(fmaf(ax, dc, bx), 0.f);
    ay = fmaxf(fmaf(ay, dc, by), 0.f);
    *(float2*)(out + (size_t)wid * HID + lane * 2) = make_float2(ax, ay);
}

// --- BN stats: per-channel sum and sumsq -----------------------------------
__global__ __launch_bounds__(256) void bn_stats_kernel(const float* __restrict__ y,
                                                       float* __restrict__ sum,
                                                       float* __restrict__ sumsq, int n) {
    int c = threadIdx.x & 127;
    int g = threadIdx.x >> 7;
    float s = 0.f, s2 = 0.f;
    for (int r = blockIdx.x * 2 + g; r < n; r += gridDim.x * 2) {
        float v = y[(size_t)r * HID + c];
        s += v;
        s2 = fmaf(v, v, s2);
    }
    __shared__ float ls[256], ls2[256];
    ls[threadIdx.x] = s; ls2[threadIdx.x] = s2;
    __syncthreads();
    if (threadIdx.x < 128) {
        atomicAdd(&sum[c], ls[threadIdx.x] + ls[threadIdx.x + 128]);
        atomicAdd(&sumsq[c], ls2[threadIdx.x] + ls2[threadIdx.x + 128]);
    }
}

__global__ void bn_finalize_kernel(const float* __restrict__ sum, const float* __restrict__ sumsq,
                                   const float* __restrict__ gamma, const float* __restrict__ beta,
                                   float* __restrict__ scale, float* __restrict__ shift, float inv_n) {
    int c = threadIdx.x;
    float mean = sum[c] * inv_n;
    float var = sumsq[c] * inv_n - mean * mean;
    float sc = gamma[c] * rsqrtf(var + 1e-5f);
    scale[c] = sc;
    shift[c] = beta[c] - mean * sc;
}

// --- W2 transpose + bf16 cast: Wt[c][k] = bf16(W2[k][c]) -------------------
__global__ __launch_bounds__(256) void wt_kernel(const float* __restrict__ W,
                                                 unsigned short* __restrict__ Wt) {
    int idx = blockIdx.x * 256 + threadIdx.x;
    int c = idx >> 7, k = idx & 127;
    Wt[c * 128 + k] = f2bf(W[k * 128 + c]);
}

// --- GEMM2 via MFMA: h2 = bf16(bn(y1) @ W2), K=128 -------------------------
__global__ __launch_bounds__(256) void gemm2_mfma_kernel(
    const float* __restrict__ y, const unsigned short* __restrict__ Wt,
    const float* __restrict__ scale, const float* __restrict__ shift,
    unsigned short* __restrict__ out, int n) {
    __shared__ unsigned short lwt[128 * 136];
    __shared__ unsigned short ly[128 * 136];
    int t = threadIdx.x;
    int base = blockIdx.x * 128;

    // stage Wt: 128 rows x 128 bf16 (64 uints/row), coalesced; LDS stride 68 uints
    {
        const unsigned int* w32 = (const unsigned int*)Wt;
        unsigned int* l32 = (unsigned int*)lwt;
        #pragma unroll
        for (int i = 0; i < 32; ++i) {
            int idx = t + i * 256;
            int r = idx >> 6, cp = idx & 63;
            l32[r * 68 + cp] = w32[r * 64 + cp];
        }
    }
    // stage y tile with BN + bf16 cvt: 2 threads/row, 64 k each
    {
        int r = t >> 1, hh = t & 1;
        int gr = base + r;
        unsigned int* l32 = (unsigned int*)ly;
        const float4* yrow = (const float4*)(y + (size_t)gr * HID + hh * 64);
        #pragma unroll
        for (int j = 0; j < 16; ++j) {
            float4 v = make_float4(0.f, 0.f, 0.f, 0.f);
            if (gr < n) v = yrow[j];
            int gk = hh * 64 + j * 4;
            float a0 = fmaf(v.x, scale[gk + 0], shift[gk + 0]);
            float a1 = fmaf(v.y, scale[gk + 1], shift[gk + 1]);
            float a2 = fmaf(v.z, scale[gk + 2], shift[gk + 2]);
            float a3 = fmaf(v.w, scale[gk + 3], shift[gk + 3]);
            l32[r * 68 + hh * 32 + j * 2 + 0] = pack2bf(a0, a1);
            l32[r * 68 + hh * 32 + j * 2 + 1] = pack2bf(a2, a3);
        }
    }
    __syncthreads();

    int w = t >> 6, lane = t & 63;
    int li = lane & 15, lg = lane >> 4;
    f32x4 acc[2][8];
    #pragma unroll
    for (int a = 0; a < 2; ++a)
        #pragma unroll
        for (int b = 0; b < 8; ++b) acc[a][b] = (f32x4){0.f, 0.f, 0.f, 0.f};

    #pragma unroll
    for (int ks = 0; ks < 4; ++ks) {
        int kb = ks * 32 + lg * 8;
        bf16x8 af[2], bfr[8];
        #pragma unroll
        for (int rt = 0; rt < 2; ++rt)
            af[rt] = *(const bf16x8*)&ly[(w * 32 + rt * 16 + li) * 136 + kb];
        #pragma unroll
        for (int cf = 0; cf < 8; ++cf)
            bfr[cf] = *(const bf16x8*)&lwt[(cf * 16 + li) * 136 + kb];
        #pragma unroll
        for (int rt = 0; rt < 2; ++rt)
            #pragma unroll
            for (int cf = 0; cf < 8; ++cf)
                acc[rt][cf] = __builtin_amdgcn_mfma_f32_16x16x32_bf16(
                    af[rt], bfr[cf], acc[rt][cf], 0, 0, 0);
    }

    // epilogue: D row = (lane>>4)*4 + reg, col = cf*16 + (lane&15)
    #pragma unroll
    for (int rt = 0; rt < 2; ++rt) {
        #pragma unroll
        for (int reg = 0; reg < 4; ++reg) {
            int gr = base + w * 32 + rt * 16 + lg * 4 + reg;
            if (gr < n) {
                #pragma unroll
                for (int cf = 0; cf < 8; ++cf)
                    out[(size_t)gr * HID + cf * 16 + li] = f2bf(acc[rt][cf][reg]);
            }
        }
    }
}

extern "C" void kernel_launch(void* const* d_in, const int* in_sizes, int n_in,
                              void* d_out, int out_size, void* d_ws, size_t ws_size,
                              hipStream_t stream) {
    const float* x     = (const float*)d_in[0];
    const void*  ei    = d_in[1];
    const float* W1    = (const float*)d_in[2];
    const float* b1    = (const float*)d_in[3];
    const float* gamma = (const float*)d_in[4];
    const float* beta  = (const float*)d_in[5];
    const float* W2    = (const float*)d_in[6];
    const float* b2    = (const float*)d_in[7];
    float* out = (float*)d_out;

    const int f_in = 25;
    int n = in_sizes[0] / f_in;
    int E = in_sizes[1] / 2;
    int nb = (n + 255) >> 8;                      // 256-node scan chunks
    int CHUNK = (E + NBLK_BIN - 1) / NBLK_BIN;    // edges per bin block

    char* ws = (char*)d_ws;
    size_t off = 0;
    auto alloc = [&](size_t bytes) -> void* {
        void* p = ws + off;
        off += (bytes + 511) & ~(size_t)511;
        return p;
    };
    int*   cnt        = (int*)alloc((size_t)n * 4);
    int*   rowptr     = (int*)alloc(((size_t)n + 1) * 4);
    int*   cursor     = (int*)alloc((size_t)n * 4);
    float* dinv       = (float*)alloc((size_t)n * 4);
    int*   edge_src   = (int*)alloc((size_t)E * 4);
    uint2* pairs      = (uint2*)alloc((size_t)E * 8);
    int*   qcnt       = (int*)alloc((size_t)NBLK_BIN * 8 * 4);
    int*   qoff       = (int*)alloc(((size_t)NBLK_BIN * 8 + 1) * 4);
    float* bnacc      = (float*)alloc(256 * 4);   // sum[128] ++ sumsq[128]
    float* sclshift   = (float*)alloc(256 * 4);   // scale[128] ++ shift[128]
    int*   mode       = (int*)alloc(4);
    int*   blocksum   = (int*)alloc((size_t)nb * 4);
    int*   blockoff   = (int*)alloc((size_t)nb * 4);
    unsigned short* Wt = (unsigned short*)alloc(128 * 128 * 2);  // bf16 W2^T
    unsigned short* h  = (unsigned short*)alloc((size_t)n * HID * 2);  // bf16 h1/h2

    hipMemsetAsync(cnt, 0, (size_t)n * 4, stream);
    hipMemsetAsync(bnacc, 0, 256 * 4, stream);

    detect_kernel<<<1, 256, 0, stream>>>((const unsigned int*)ei, mode, 2 * E);
    count_kernel<<<NBLK_BIN, 256, 0, stream>>>(ei, mode, cnt, qcnt, E, CHUNK);
    scan_q_kernel<<<1, 1024, 0, stream>>>(qcnt, qoff);
    scan_partial_kernel<<<nb, 256, 0, stream>>>(cnt, blocksum, n);
    scan_blocksums_kernel<<<1, 1024, 0, stream>>>(blocksum, blockoff, rowptr, nb, n);
    scan_finalize_kernel<<<nb, 256, 0, stream>>>(cnt, blockoff, rowptr, cursor, dinv, n);
    bin_kernel<<<NBLK_BIN, 256, 0, stream>>>(ei, mode, qoff, pairs, E, CHUNK);
    scatter_c_kernel<<<8 * 128, 256, 0, stream>>>(pairs, qoff, cursor, edge_src);

    // layer 1: h1 = bf16(x@W1) ; y1 = relu(prop(h1) + b1) -> d_out (fp32)
    gemm1_kernel<<<4096, 256, 0, stream>>>(x, W1, h, n);
    propagate_kernel<<<(n + 3) / 4, 256, 0, stream>>>(h, rowptr, edge_src, dinv, b1, out, n);

    // batchnorm stats on y1
    bn_stats_kernel<<<512, 256, 0, stream>>>(out, bnacc, bnacc + 128, n);
    bn_finalize_kernel<<<1, 128, 0, stream>>>(bnacc, bnacc + 128, gamma, beta,
                                              sclshift, sclshift + 128, 1.0f / (float)n);

    // layer 2: h2 = bf16(bn(y1)@W2) via MFMA ; out = relu(prop(h2) + b2)
    wt_kernel<<<64, 256, 0, stream>>>(W2, Wt);
    gemm2_mfma_kernel<<<(n + 127) / 128, 256, 0, stream>>>(out, Wt, sclshift, sclshift + 128, h, n);
    propagate_kernel<<<(n + 3) / 4, 256, 0, stream>>>(h, rowptr, edge_src, dinv, b2, out, n);
}

// Round 18
// 312.138 us; speedup vs baseline: 1.4113x; 1.3547x over previous
//
#include <hip/hip_runtime.h>
#include <stdint.h>

// ---------------------------------------------------------------------------
// 2-layer GCN: relu(gcn(x,W1,b1)) -> batchnorm -> relu(gcn(.,W2,b2))
// n=100000, E=1.6M, f_in=25, hid=128.
// R2 scan / R6 bf16+tile / R10 scatter / R14 pipelined gather / R15 MFMA.
// R16/R17 taught: ~65-94MB WRITE in every build variant == 1.6M returning
//     device-scope atomicAdds (memory-side RMW ~40B each, for cross-XCD
//     coherence). The atomics ARE the traffic.
// R18: zero-global-atomic CSR build. q-major privatized queues:
//     count_q: per-(block,chunk) LDS tallies -> qcnt (no atomics)
//     scan_q:  3-phase scan in q-major order -> qoff; chunk q's pair range
//              [qoff[q*512], qoff[(q+1)*512]) == its edge_src range
//     bin:     blocks append packed (c&255)<<24|r via LDS cursors
//     chunk_build: block q = LDS histogram + block scan -> rowptr/dinv,
//              then LDS-cursor placement into private 16KB edge_src region.
// ---------------------------------------------------------------------------

#define HID 128
#define NBB 512          // binning blocks (power of 2; segment index j = q*512+b)

typedef short bf16x8 __attribute__((ext_vector_type(8)));
typedef float f32x4 __attribute__((ext_vector_type(4)));

__device__ __forceinline__ unsigned short f2bf(float f) {
    unsigned int u = __float_as_uint(f);
    unsigned int r = (u + 0x7FFFu + ((u >> 16) & 1u)) >> 16;  // RNE
    return (unsigned short)r;
}
__device__ __forceinline__ unsigned int pack2bf(float lo, float hi) {
    return (unsigned int)f2bf(lo) | ((unsigned int)f2bf(hi) << 16);
}
__device__ __forceinline__ float bflo(unsigned int v) { return __uint_as_float(v << 16); }
__device__ __forceinline__ float bfhi(unsigned int v) { return __uint_as_float(v & 0xffff0000u); }

// --- detect whether edge_index buffer is int64 or int32 --------------------
__global__ void detect_kernel(const unsigned int* __restrict__ w, int* __restrict__ mode, int nwords) {
    __shared__ int any;
    if (threadIdx.x == 0) any = 0;
    __syncthreads();
    for (int i = threadIdx.x * 2 + 1; i < nwords && i < 8192; i += 512) {
        if (w[i] != 0) atomicOr(&any, 1);
    }
    __syncthreads();
    if (threadIdx.x == 0) *mode = any ? 0 : 1;  // 1 => int64 layout
}

__device__ __forceinline__ int load_idx(const void* ei, size_t i, int mode) {
    return mode ? (int)((const long long*)ei)[i] : ((const int*)ei)[i];
}

// --- count_q: per-(block, 256-node-chunk) tallies, LDS only ----------------
__global__ __launch_bounds__(256) void count_q_kernel(const void* __restrict__ ei,
                                                      const int* __restrict__ modep,
                                                      int* __restrict__ qcnt,
                                                      int E, int CHUNK, int nchunk) {
    __shared__ int qc[512];
    for (int i = threadIdx.x; i < nchunk; i += 256) qc[i] = 0;
    __syncthreads();
    int mode = *modep;
    int beg = blockIdx.x * CHUNK;
    int end = beg + CHUNK; if (end > E) end = E;
    for (int e = beg + threadIdx.x; e < end; e += 256) {
        int c = load_idx(ei, (size_t)E + e, mode);
        atomicAdd(&qc[c >> 8], 1);       // LDS atomic
    }
    __syncthreads();
    for (int i = threadIdx.x; i < nchunk; i += 256)
        qcnt[blockIdx.x * nchunk + i] = qc[i];   // b-major storage, coalesced
}

// --- scan_q phase 1: partial sums over scan-order positions ----------------
// scan order j = q*NBB + b  (q-major);  qcnt stored b-major: qcnt[b*nchunk+q]
__global__ __launch_bounds__(256) void scanq_partial_kernel(const int* __restrict__ qcnt,
                                                            int* __restrict__ blocksum,
                                                            int NQ, int nchunk) {
    int j0 = blockIdx.x * 2048 + threadIdx.x * 8;
    int s = 0;
    #pragma unroll
    for (int i = 0; i < 8; ++i) {
        int j = j0 + i;
        if (j < NQ) {
            int q = j >> 9, b = j & (NBB - 1);
            s += qcnt[b * nchunk + q];
        }
    }
    #pragma unroll
    for (int off = 32; off > 0; off >>= 1) s += __shfl_down(s, off);
    __shared__ int ls[4];
    if ((threadIdx.x & 63) == 0) ls[threadIdx.x >> 6] = s;
    __syncthreads();
    if (threadIdx.x == 0) blocksum[blockIdx.x] = ls[0] + ls[1] + ls[2] + ls[3];
}

// --- scan_q phase 2: scan block sums (nsb <= 1024) -------------------------
__global__ __launch_bounds__(1024) void scanq_blocksums_kernel(const int* __restrict__ blocksum,
                                                               int* __restrict__ blockoff,
                                                               int* __restrict__ qoff,
                                                               int nsb, int NQ) {
    __shared__ int s[1024];
    int t = threadIdx.x;
    int own = (t < nsb) ? blocksum[t] : 0;
    s[t] = own;
    __syncthreads();
    for (int off = 1; off < 1024; off <<= 1) {
        int v = s[t] + ((t >= off) ? s[t - off] : 0);
        __syncthreads();
        s[t] = v;
        __syncthreads();
    }
    if (t < nsb) blockoff[t] = s[t] - own;   // exclusive
    if (t == 1023) qoff[NQ] = s[1023];       // total == E
}

// --- scan_q phase 3: per-position exclusive prefix -> qoff -----------------
__global__ __launch_bounds__(256) void scanq_finalize_kernel(const int* __restrict__ qcnt,
                                                             const int* __restrict__ blockoff,
                                                             int* __restrict__ qoff,
                                                             int NQ, int nchunk) {
    int t = threadIdx.x;
    int j0 = blockIdx.x * 2048 + t * 8;
    int v[8], own = 0;
    #pragma unroll
    for (int i = 0; i < 8; ++i) {
        int j = j0 + i;
        v[i] = 0;
        if (j < NQ) {
            int q = j >> 9, b = j & (NBB - 1);
            v[i] = qcnt[b * nchunk + q];
        }
        own += v[i];
    }
    __shared__ int s[256];
    s[t] = own;
    __syncthreads();
    for (int off = 1; off < 256; off <<= 1) {
        int x = s[t] + ((t >= off) ? s[t - off] : 0);
        __syncthreads();
        s[t] = x;
        __syncthreads();
    }
    int e = blockoff[blockIdx.x] + s[t] - own;
    #pragma unroll
    for (int i = 0; i < 8; ++i) {
        int j = j0 + i;
        if (j < NQ) qoff[j] = e;
        e += v[i];
    }
}

// --- bin: append packed (c&255)<<24 | r into private segments (LDS cursors)-
__global__ __launch_bounds__(256) void bin_kernel(const void* __restrict__ ei,
                                                  const int* __restrict__ modep,
                                                  const int* __restrict__ qoff,
                                                  unsigned int* __restrict__ packed,
                                                  int E, int CHUNK, int nchunk) {
    __shared__ int cur[512];
    for (int i = threadIdx.x; i < nchunk; i += 256)
        cur[i] = qoff[i * NBB + blockIdx.x];
    __syncthreads();
    int mode = *modep;
    int beg = blockIdx.x * CHUNK;
    int end = beg + CHUNK; if (end > E) end = E;
    for (int e = beg + threadIdx.x; e < end; e += 256) {
        int c = load_idx(ei, (size_t)E + e, mode);
        int r = load_idx(ei, (size_t)e, mode);
        int pos = atomicAdd(&cur[c >> 8], 1);    // LDS atomic
        packed[pos] = ((unsigned)(c & 255) << 24) | (unsigned)r;
    }
}

// --- chunk_build: per-chunk histogram + scan -> rowptr/dinv, then place ----
__global__ __launch_bounds__(256) void chunk_build_kernel(
    const unsigned int* __restrict__ packed, const int* __restrict__ qoff,
    int* __restrict__ rowptr, float* __restrict__ dinv,
    int* __restrict__ edge_src, int n, int E) {
    int q = blockIdx.x;
    int t = threadIdx.x;
    int pbeg = qoff[q * NBB];
    int pend = qoff[(q + 1) * NBB];   // last chunk: (q+1)*NBB == NQ, qoff[NQ]=E
    __shared__ int cnt256[256], cur[256], s[256];
    cnt256[t] = 0;
    __syncthreads();
    for (int i = pbeg + t; i < pend; i += 256)
        atomicAdd(&cnt256[packed[i] >> 24], 1);  // LDS atomic
    __syncthreads();
    int own = cnt256[t];
    s[t] = own;
    __syncthreads();
    for (int off = 1; off < 256; off <<= 1) {
        int x = s[t] + ((t >= off) ? s[t - off] : 0);
        __syncthreads();
        s[t] = x;
        __syncthreads();
    }
    int pref = s[t] - own;   // exclusive within chunk
    int node = (q << 8) + t;
    if (node < n) {
        rowptr[node] = pbeg + pref;
        dinv[node] = rsqrtf((float)(own + 1));   // +1 self loop
    }
    cur[t] = pbeg + pref;
    if (q == gridDim.x - 1 && t == 0) rowptr[n] = E;
    __syncthreads();
    for (int i = pbeg + t; i < pend; i += 256) {
        unsigned int u = packed[i];
        int pos = atomicAdd(&cur[u >> 24], 1);   // LDS atomic
        edge_src[pos] = (int)(u & 0xFFFFFFu);
    }
}

// --- GEMM1: h = bf16(x @ W1)   (K=25, W1 staged in LDS) --------------------
__global__ __launch_bounds__(256) void gemm1_kernel(const float* __restrict__ x,
                                                    const float* __restrict__ W,
                                                    unsigned short* __restrict__ h, int n) {
    __shared__ float lw[25 * HID];
    for (int i = threadIdx.x; i < 25 * HID; i += 256) lw[i] = W[i];
    __syncthreads();
    int g = threadIdx.x >> 7, c = threadIdx.x & 127;
    for (int r = blockIdx.x * 2 + g; r < n; r += gridDim.x * 2) {
        const float* xr = x + (size_t)r * 25;
        float acc = 0.f;
        #pragma unroll
        for (int k = 0; k < 25; ++k) acc = fmaf(xr[k], lw[k * HID + c], acc);
        h[(size_t)r * HID + c] = f2bf(acc);
    }
}

// --- propagation: 8-way unrolled gather loop -------------------------------
__global__ __launch_bounds__(256) void propagate_kernel(
    const unsigned short* __restrict__ h, const int* __restrict__ rowptr,
    const int* __restrict__ edge_src, const float* __restrict__ dinv,
    const float* __restrict__ bias, float* __restrict__ out, int n) {
    int wid = (blockIdx.x * 256 + threadIdx.x) >> 6;
    if (wid >= n) return;
    int lane = threadIdx.x & 63;
    int beg = rowptr[wid], end = rowptr[wid + 1];
    float dc = dinv[wid];
    float ax = 0.f, ay = 0.f;
    const unsigned int* hp = (const unsigned int*)h;  // 64 uints per row
    for (int b = beg; b < end; b += 64) {
        int m = end - b; if (m > 64) m = 64;
        int s = 0; float w = 0.f;
        if (lane < m) { s = edge_src[b + lane]; w = dinv[s]; }
        int j = 0;
        for (; j + 8 <= m; j += 8) {
            int s0 = __shfl(s, j + 0), s1 = __shfl(s, j + 1);
            int s2 = __shfl(s, j + 2), s3 = __shfl(s, j + 3);
            int s4 = __shfl(s, j + 4), s5 = __shfl(s, j + 5);
            int s6 = __shfl(s, j + 6), s7 = __shfl(s, j + 7);
            unsigned int v0 = hp[(size_t)s0 * 64 + lane];
            unsigned int v1 = hp[(size_t)s1 * 64 + lane];
            unsigned int v2 = hp[(size_t)s2 * 64 + lane];
            unsigned int v3 = hp[(size_t)s3 * 64 + lane];
            unsigned int v4 = hp[(size_t)s4 * 64 + lane];
            unsigned int v5 = hp[(size_t)s5 * 64 + lane];
            unsigned int v6 = hp[(size_t)s6 * 64 + lane];
            unsigned int v7 = hp[(size_t)s7 * 64 + lane];
            float w0 = __shfl(w, j + 0), w1 = __shfl(w, j + 1);
            float w2 = __shfl(w, j + 2), w3 = __shfl(w, j + 3);
            float w4 = __shfl(w, j + 4), w5 = __shfl(w, j + 5);
            float w6 = __shfl(w, j + 6), w7 = __shfl(w, j + 7);
            ax = fmaf(bflo(v0), w0, ax); ay = fmaf(bfhi(v0), w0, ay);
            ax = fmaf(bflo(v1), w1, ax); ay = fmaf(bfhi(v1), w1, ay);
            ax = fmaf(bflo(v2), w2, ax); ay = fmaf(bfhi(v2), w2, ay);
            ax = fmaf(bflo(v3), w3, ax); ay = fmaf(bfhi(v3), w3, ay);
            ax = fmaf(bflo(v4), w4, ax); ay = fmaf(bfhi(v4), w4, ay);
            ax = fmaf(bflo(v5), w5, ax); ay = fmaf(bfhi(v5), w5, ay);
            ax = fmaf(bflo(v6), w6, ax); ay = fmaf(bfhi(v6), w6, ay);
            ax = fmaf(bflo(v7), w7, ax); ay = fmaf(bfhi(v7), w7, ay);
        }
        for (; j < m; ++j) {
            int sj = __shfl(s, j);
            float wj = __shfl(w, j);
            unsigned int v = hp[(size_t)sj * 64 + lane];
            ax = fmaf(bflo(v), wj, ax);
            ay = fmaf(bfhi(v), wj, ay);
        }
    }
    {   // self loop
        unsigned int v = hp[(size_t)wid * 64 + lane];
        ax = fmaf(bflo(v), dc, ax);
        ay = fmaf(bfhi(v), dc, ay);
    }
    float bx = bias[lane * 2], by = bias[lane * 2 + 1];
    ax = fmaxf(fmaf(ax, dc, bx), 0.f);
    ay = fmaxf(fmaf(ay, dc, by), 0.f);
    *(float2*)(out + (size_t)wid * HID + lane * 2) = make_float2(ax, ay);
}

// --- BN stats: per-channel sum and sumsq -----------------------------------
__global__ __launch_bounds__(256) void bn_stats_kernel(const float* __restrict__ y,
                                                       float* __restrict__ sum,
                                                       float* __restrict__ sumsq, int n) {
    int c = threadIdx.x & 127;
    int g = threadIdx.x >> 7;
    float s = 0.f, s2 = 0.f;
    for (int r = blockIdx.x * 2 + g; r < n; r += gridDim.x * 2) {
        float v = y[(size_t)r * HID + c];
        s += v;
        s2 = fmaf(v, v, s2);
    }
    __shared__ float ls[256], ls2[256];
    ls[threadIdx.x] = s; ls2[threadIdx.x] = s2;
    __syncthreads();
    if (threadIdx.x < 128) {
        atomicAdd(&sum[c], ls[threadIdx.x] + ls[threadIdx.x + 128]);
        atomicAdd(&sumsq[c], ls2[threadIdx.x] + ls2[threadIdx.x + 128]);
    }
}

__global__ void bn_finalize_kernel(const float* __restrict__ sum, const float* __restrict__ sumsq,
                                   const float* __restrict__ gamma, const float* __restrict__ beta,
                                   float* __restrict__ scale, float* __restrict__ shift, float inv_n) {
    int c = threadIdx.x;
    float mean = sum[c] * inv_n;
    float var = sumsq[c] * inv_n - mean * mean;
    float sc = gamma[c] * rsqrtf(var + 1e-5f);
    scale[c] = sc;
    shift[c] = beta[c] - mean * sc;
}

// --- W2 transpose + bf16 cast: Wt[c][k] = bf16(W2[k][c]) -------------------
__global__ __launch_bounds__(256) void wt_kernel(const float* __restrict__ W,
                                                 unsigned short* __restrict__ Wt) {
    int idx = blockIdx.x * 256 + threadIdx.x;
    int c = idx >> 7, k = idx & 127;
    Wt[c * 128 + k] = f2bf(W[k * 128 + c]);
}

// --- GEMM2 via MFMA: h2 = bf16(bn(y1) @ W2), K=128 -------------------------
__global__ __launch_bounds__(256) void gemm2_mfma_kernel(
    const float* __restrict__ y, const unsigned short* __restrict__ Wt,
    const float* __restrict__ scale, const float* __restrict__ shift,
    unsigned short* __restrict__ out, int n) {
    __shared__ unsigned short lwt[128 * 136];
    __shared__ unsigned short ly[128 * 136];
    int t = threadIdx.x;
    int base = blockIdx.x * 128;

    // stage Wt: 128 rows x 128 bf16 (64 uints/row), coalesced; LDS stride 68 uints
    {
        const unsigned int* w32 = (const unsigned int*)Wt;
        unsigned int* l32 = (unsigned int*)lwt;
        #pragma unroll
        for (int i = 0; i < 32; ++i) {
            int idx = t + i * 256;
            int r = idx >> 6, cp = idx & 63;
            l32[r * 68 + cp] = w32[r * 64 + cp];
        }
    }
    // stage y tile with BN + bf16 cvt: 2 threads/row, 64 k each
    {
        int r = t >> 1, hh = t & 1;
        int gr = base + r;
        unsigned int* l32 = (unsigned int*)ly;
        const float4* yrow = (const float4*)(y + (size_t)gr * HID + hh * 64);
        #pragma unroll
        for (int j = 0; j < 16; ++j) {
            float4 v = make_float4(0.f, 0.f, 0.f, 0.f);
            if (gr < n) v = yrow[j];
            int gk = hh * 64 + j * 4;
            float a0 = fmaf(v.x, scale[gk + 0], shift[gk + 0]);
            float a1 = fmaf(v.y, scale[gk + 1], shift[gk + 1]);
            float a2 = fmaf(v.z, scale[gk + 2], shift[gk + 2]);
            float a3 = fmaf(v.w, scale[gk + 3], shift[gk + 3]);
            l32[r * 68 + hh * 32 + j * 2 + 0] = pack2bf(a0, a1);
            l32[r * 68 + hh * 32 + j * 2 + 1] = pack2bf(a2, a3);
        }
    }
    __syncthreads();

    int w = t >> 6, lane = t & 63;
    int li = lane & 15, lg = lane >> 4;
    f32x4 acc[2][8];
    #pragma unroll
    for (int a = 0; a < 2; ++a)
        #pragma unroll
        for (int b = 0; b < 8; ++b) acc[a][b] = (f32x4){0.f, 0.f, 0.f, 0.f};

    #pragma unroll
    for (int ks = 0; ks < 4; ++ks) {
        int kb = ks * 32 + lg * 8;
        bf16x8 af[2], bfr[8];
        #pragma unroll
        for (int rt = 0; rt < 2; ++rt)
            af[rt] = *(const bf16x8*)&ly[(w * 32 + rt * 16 + li) * 136 + kb];
        #pragma unroll
        for (int cf = 0; cf < 8; ++cf)
            bfr[cf] = *(const bf16x8*)&lwt[(cf * 16 + li) * 136 + kb];
        #pragma unroll
        for (int rt = 0; rt < 2; ++rt)
            #pragma unroll
            for (int cf = 0; cf < 8; ++cf)
                acc[rt][cf] = __builtin_amdgcn_mfma_f32_16x16x32_bf16(
                    af[rt], bfr[cf], acc[rt][cf], 0, 0, 0);
    }

    // epilogue: D row = (lane>>4)*4 + reg, col = cf*16 + (lane&15)
    #pragma unroll
    for (int rt = 0; rt < 2; ++rt) {
        #pragma unroll
        for (int reg = 0; reg < 4; ++reg) {
            int gr = base + w * 32 + rt * 16 + lg * 4 + reg;
            if (gr < n) {
                #pragma unroll
                for (int cf = 0; cf < 8; ++cf)
                    out[(size_t)gr * HID + cf * 16 + li] = f2bf(acc[rt][cf][reg]);
            }
        }
    }
}

extern "C" void kernel_launch(void* const* d_in, const int* in_sizes, int n_in,
                              void* d_out, int out_size, void* d_ws, size_t ws_size,
                              hipStream_t stream) {
    const float* x     = (const float*)d_in[0];
    const void*  ei    = d_in[1];
    const float* W1    = (const float*)d_in[2];
    const float* b1    = (const float*)d_in[3];
    const float* gamma = (const float*)d_in[4];
    const float* beta  = (const float*)d_in[5];
    const float* W2    = (const float*)d_in[6];
    const float* b2    = (const float*)d_in[7];
    float* out = (float*)d_out;

    const int f_in = 25;
    int n = in_sizes[0] / f_in;
    int E = in_sizes[1] / 2;
    int nchunk = (n + 255) >> 8;                 // 256-node chunks (391)
    int NQ = nchunk * NBB;                       // queue segments (200192)
    int nsb = (NQ + 2047) / 2048;                // scan blocks (98, <=1024)
    int CHUNK = (E + NBB - 1) / NBB;             // edges per bin block

    char* ws = (char*)d_ws;
    size_t off = 0;
    auto alloc = [&](size_t bytes) -> void* {
        void* p = ws + off;
        off += (bytes + 511) & ~(size_t)511;
        return p;
    };
    int*   rowptr    = (int*)alloc(((size_t)n + 1) * 4);
    float* dinv      = (float*)alloc((size_t)n * 4);
    int*   edge_src  = (int*)alloc((size_t)E * 4);
    unsigned int* packed = (unsigned int*)alloc((size_t)E * 4);
    int*   qcnt      = (int*)alloc((size_t)NQ * 4);
    int*   qoff      = (int*)alloc(((size_t)NQ + 1) * 4);
    int*   blocksum  = (int*)alloc((size_t)nsb * 4);
    int*   blockoff  = (int*)alloc((size_t)nsb * 4);
    float* bnacc     = (float*)alloc(256 * 4);   // sum[128] ++ sumsq[128]
    float* sclshift  = (float*)alloc(256 * 4);   // scale[128] ++ shift[128]
    int*   mode      = (int*)alloc(4);
    unsigned short* Wt = (unsigned short*)alloc(128 * 128 * 2);  // bf16 W2^T
    unsigned short* h  = (unsigned short*)alloc((size_t)n * HID * 2);  // bf16 h1/h2

    hipMemsetAsync(bnacc, 0, 256 * 4, stream);

    detect_kernel<<<1, 256, 0, stream>>>((const unsigned int*)ei, mode, 2 * E);
    count_q_kernel<<<NBB, 256, 0, stream>>>(ei, mode, qcnt, E, CHUNK, nchunk);
    scanq_partial_kernel<<<nsb, 256, 0, stream>>>(qcnt, blocksum, NQ, nchunk);
    scanq_blocksums_kernel<<<1, 1024, 0, stream>>>(blocksum, blockoff, qoff, nsb, NQ);
    scanq_finalize_kernel<<<nsb, 256, 0, stream>>>(qcnt, blockoff, qoff, NQ, nchunk);
    bin_kernel<<<NBB, 256, 0, stream>>>(ei, mode, qoff, packed, E, CHUNK, nchunk);
    chunk_build_kernel<<<nchunk, 256, 0, stream>>>(packed, qoff, rowptr, dinv, edge_src, n, E);

    // layer 1: h1 = bf16(x@W1) ; y1 = relu(prop(h1) + b1) -> d_out (fp32)
    gemm1_kernel<<<4096, 256, 0, stream>>>(x, W1, h, n);
    propagate_kernel<<<(n + 3) / 4, 256, 0, stream>>>(h, rowptr, edge_src, dinv, b1, out, n);

    // batchnorm stats on y1
    bn_stats_kernel<<<512, 256, 0, stream>>>(out, bnacc, bnacc + 128, n);
    bn_finalize_kernel<<<1, 128, 0, stream>>>(bnacc, bnacc + 128, gamma, beta,
                                              sclshift, sclshift + 128, 1.0f / (float)n);

    // layer 2: h2 = bf16(bn(y1)@W2) via MFMA ; out = relu(prop(h2) + b2)
    wt_kernel<<<64, 256, 0, stream>>>(W2, Wt);
    gemm2_mfma_kernel<<<(n + 127) / 128, 256, 0, stream>>>(out, Wt, sclshift, sclshift + 128, h, n);
    propagate_kernel<<<(n + 3) / 4, 256, 0, stream>>>(h, rowptr, edge_src, dinv, b2, out, n);
}

// Round 20
// 282.359 us; speedup vs baseline: 1.5602x; 1.1055x over previous
//
#include <hip/hip_runtime.h>
#include <stdint.h>

// ---------------------------------------------------------------------------
// 2-layer GCN: relu(gcn(x,W1,b1)) -> batchnorm -> relu(gcn(.,W2,b2))
// n=100000, E=1.6M, f_in=25, hid=128.
// R2 scan / R6 bf16+tile / R10 scatter / R14 pipelined gather / R15 MFMA /
// R18 zero-global-atomic CSR build (423 -> 312).
// R19: layer-1 propagate commuted into input space: A_hat@(x@W1) ==
//     (A_hat@x)@W1. x padded to bf16[n][32] (64B rows, 6.4MB => L2-RESIDENT
//     per XCD, kills the 8x fabric replication that made propagate fetch
//     196MB). prop_x: 16 lanes/edge, 4 edges/wave-step, group partials +
//     shfl_xor reduce. gemm1 now consumes y0 and fuses bias+relu.
//     Layer-2 propagate (128-dim, 68us) unchanged.
// R20: resubmit — R19 bench died on the unresponsive container (infra).
// ---------------------------------------------------------------------------

#define HID 128
#define NBB 512          // binning blocks (power of 2; segment index j = q*512+b)

typedef short bf16x8 __attribute__((ext_vector_type(8)));
typedef float f32x4 __attribute__((ext_vector_type(4)));

__device__ __forceinline__ unsigned short f2bf(float f) {
    unsigned int u = __float_as_uint(f);
    unsigned int r = (u + 0x7FFFu + ((u >> 16) & 1u)) >> 16;  // RNE
    return (unsigned short)r;
}
__device__ __forceinline__ unsigned int pack2bf(float lo, float hi) {
    return (unsigned int)f2bf(lo) | ((unsigned int)f2bf(hi) << 16);
}
__device__ __forceinline__ float bflo(unsigned int v) { return __uint_as_float(v << 16); }
__device__ __forceinline__ float bfhi(unsigned int v) { return __uint_as_float(v & 0xffff0000u); }

// --- detect whether edge_index buffer is int64 or int32 --------------------
__global__ void detect_kernel(const unsigned int* __restrict__ w, int* __restrict__ mode, int nwords) {
    __shared__ int any;
    if (threadIdx.x == 0) any = 0;
    __syncthreads();
    for (int i = threadIdx.x * 2 + 1; i < nwords && i < 8192; i += 512) {
        if (w[i] != 0) atomicOr(&any, 1);
    }
    __syncthreads();
    if (threadIdx.x == 0) *mode = any ? 0 : 1;  // 1 => int64 layout
}

__device__ __forceinline__ int load_idx(const void* ei, size_t i, int mode) {
    return mode ? (int)((const long long*)ei)[i] : ((const int*)ei)[i];
}

// --- count_q: per-(block, 256-node-chunk) tallies, LDS only ----------------
__global__ __launch_bounds__(256) void count_q_kernel(const void* __restrict__ ei,
                                                      const int* __restrict__ modep,
                                                      int* __restrict__ qcnt,
                                                      int E, int CHUNK, int nchunk) {
    __shared__ int qc[512];
    for (int i = threadIdx.x; i < nchunk; i += 256) qc[i] = 0;
    __syncthreads();
    int mode = *modep;
    int beg = blockIdx.x * CHUNK;
    int end = beg + CHUNK; if (end > E) end = E;
    for (int e = beg + threadIdx.x; e < end; e += 256) {
        int c = load_idx(ei, (size_t)E + e, mode);
        atomicAdd(&qc[c >> 8], 1);       // LDS atomic
    }
    __syncthreads();
    for (int i = threadIdx.x; i < nchunk; i += 256)
        qcnt[blockIdx.x * nchunk + i] = qc[i];   // b-major storage, coalesced
}

// --- scan_q phase 1: partial sums over scan-order positions ----------------
// scan order j = q*NBB + b  (q-major);  qcnt stored b-major: qcnt[b*nchunk+q]
__global__ __launch_bounds__(256) void scanq_partial_kernel(const int* __restrict__ qcnt,
                                                            int* __restrict__ blocksum,
                                                            int NQ, int nchunk) {
    int j0 = blockIdx.x * 2048 + threadIdx.x * 8;
    int s = 0;
    #pragma unroll
    for (int i = 0; i < 8; ++i) {
        int j = j0 + i;
        if (j < NQ) {
            int q = j >> 9, b = j & (NBB - 1);
            s += qcnt[b * nchunk + q];
        }
    }
    #pragma unroll
    for (int off = 32; off > 0; off >>= 1) s += __shfl_down(s, off);
    __shared__ int ls[4];
    if ((threadIdx.x & 63) == 0) ls[threadIdx.x >> 6] = s;
    __syncthreads();
    if (threadIdx.x == 0) blocksum[blockIdx.x] = ls[0] + ls[1] + ls[2] + ls[3];
}

// --- scan_q phase 2: scan block sums (nsb <= 1024) -------------------------
__global__ __launch_bounds__(1024) void scanq_blocksums_kernel(const int* __restrict__ blocksum,
                                                               int* __restrict__ blockoff,
                                                               int* __restrict__ qoff,
                                                               int nsb, int NQ) {
    __shared__ int s[1024];
    int t = threadIdx.x;
    int own = (t < nsb) ? blocksum[t] : 0;
    s[t] = own;
    __syncthreads();
    for (int off = 1; off < 1024; off <<= 1) {
        int v = s[t] + ((t >= off) ? s[t - off] : 0);
        __syncthreads();
        s[t] = v;
        __syncthreads();
    }
    if (t < nsb) blockoff[t] = s[t] - own;   // exclusive
    if (t == 1023) qoff[NQ] = s[1023];       // total == E
}

// --- scan_q phase 3: per-position exclusive prefix -> qoff -----------------
__global__ __launch_bounds__(256) void scanq_finalize_kernel(const int* __restrict__ qcnt,
                                                             const int* __restrict__ blockoff,
                                                             int* __restrict__ qoff,
                                                             int NQ, int nchunk) {
    int t = threadIdx.x;
    int j0 = blockIdx.x * 2048 + t * 8;
    int v[8], own = 0;
    #pragma unroll
    for (int i = 0; i < 8; ++i) {
        int j = j0 + i;
        v[i] = 0;
        if (j < NQ) {
            int q = j >> 9, b = j & (NBB - 1);
            v[i] = qcnt[b * nchunk + q];
        }
        own += v[i];
    }
    __shared__ int s[256];
    s[t] = own;
    __syncthreads();
    for (int off = 1; off < 256; off <<= 1) {
        int x = s[t] + ((t >= off) ? s[t - off] : 0);
        __syncthreads();
        s[t] = x;
        __syncthreads();
    }
    int e = blockoff[blockIdx.x] + s[t] - own;
    #pragma unroll
    for (int i = 0; i < 8; ++i) {
        int j = j0 + i;
        if (j < NQ) qoff[j] = e;
        e += v[i];
    }
}

// --- bin: append packed (c&255)<<24 | r into private segments (LDS cursors)-
__global__ __launch_bounds__(256) void bin_kernel(const void* __restrict__ ei,
                                                  const int* __restrict__ modep,
                                                  const int* __restrict__ qoff,
                                                  unsigned int* __restrict__ packed,
                                                  int E, int CHUNK, int nchunk) {
    __shared__ int cur[512];
    for (int i = threadIdx.x; i < nchunk; i += 256)
        cur[i] = qoff[i * NBB + blockIdx.x];
    __syncthreads();
    int mode = *modep;
    int beg = blockIdx.x * CHUNK;
    int end = beg + CHUNK; if (end > E) end = E;
    for (int e = beg + threadIdx.x; e < end; e += 256) {
        int c = load_idx(ei, (size_t)E + e, mode);
        int r = load_idx(ei, (size_t)e, mode);
        int pos = atomicAdd(&cur[c >> 8], 1);    // LDS atomic
        packed[pos] = ((unsigned)(c & 255) << 24) | (unsigned)r;
    }
}

// --- chunk_build: per-chunk histogram + scan -> rowptr/dinv, then place ----
__global__ __launch_bounds__(256) void chunk_build_kernel(
    const unsigned int* __restrict__ packed, const int* __restrict__ qoff,
    int* __restrict__ rowptr, float* __restrict__ dinv,
    int* __restrict__ edge_src, int n, int E) {
    int q = blockIdx.x;
    int t = threadIdx.x;
    int pbeg = qoff[q * NBB];
    int pend = qoff[(q + 1) * NBB];   // last chunk: (q+1)*NBB == NQ, qoff[NQ]=E
    __shared__ int cnt256[256], cur[256], s[256];
    cnt256[t] = 0;
    __syncthreads();
    for (int i = pbeg + t; i < pend; i += 256)
        atomicAdd(&cnt256[packed[i] >> 24], 1);  // LDS atomic
    __syncthreads();
    int own = cnt256[t];
    s[t] = own;
    __syncthreads();
    for (int off = 1; off < 256; off <<= 1) {
        int x = s[t] + ((t >= off) ? s[t - off] : 0);
        __syncthreads();
        s[t] = x;
        __syncthreads();
    }
    int pref = s[t] - own;   // exclusive within chunk
    int node = (q << 8) + t;
    if (node < n) {
        rowptr[node] = pbeg + pref;
        dinv[node] = rsqrtf((float)(own + 1));   // +1 self loop
    }
    cur[t] = pbeg + pref;
    if (q == gridDim.x - 1 && t == 0) rowptr[n] = E;
    __syncthreads();
    for (int i = pbeg + t; i < pend; i += 256) {
        unsigned int u = packed[i];
        int pos = atomicAdd(&cur[u >> 24], 1);   // LDS atomic
        edge_src[pos] = (int)(u & 0xFFFFFFu);
    }
}

// --- xpad: x fp32 [n][25] -> bf16 [n][32] (zero-padded) --------------------
__global__ __launch_bounds__(256) void xpad_kernel(const float* __restrict__ x,
                                                   unsigned int* __restrict__ xp, int n) {
    int r = blockIdx.x * 256 + threadIdx.x;
    if (r >= n) return;
    const float* xr = x + (size_t)r * 25;
    unsigned int* o = xp + (size_t)r * 16;
    #pragma unroll
    for (int j = 0; j < 12; ++j)
        o[j] = pack2bf(xr[j * 2], xr[j * 2 + 1]);
    o[12] = pack2bf(xr[24], 0.f);
    o[13] = 0u; o[14] = 0u; o[15] = 0u;
}

// --- prop_x: y0 = dinv[c]*(sum_e x[r]*dinv[r] + x[c]*dinv[c]) in 32-dim ----
// 16 lanes/edge (64B row), 4 edges per wave-step; group partials, shfl_xor
// cross-group reduce; self loop added by group 0 only.
__global__ __launch_bounds__(256) void prop_x_kernel(
    const unsigned int* __restrict__ xp, const int* __restrict__ rowptr,
    const int* __restrict__ edge_src, const float* __restrict__ dinv,
    unsigned int* __restrict__ y0, int n) {
    int wid = (blockIdx.x * 256 + threadIdx.x) >> 6;
    if (wid >= n) return;
    int lane = threadIdx.x & 63;
    int g = lane >> 4, i = lane & 15;
    int beg = rowptr[wid], end = rowptr[wid + 1];
    float dc = dinv[wid];
    float ax = 0.f, ay = 0.f;
    for (int b = beg; b < end; b += 64) {
        int m = end - b; if (m > 64) m = 64;
        int s = 0; float w = 0.f;
        if (lane < m) { s = edge_src[b + lane]; w = dinv[s]; }
        int nsteps = (m + 3) >> 2;
        for (int t = 0; t < nsteps; ++t) {
            int e = 4 * t + g;
            int sj = __shfl(s, e & 63);
            float wj = __shfl(w, e & 63);
            if (e >= m) { sj = 0; wj = 0.f; }
            unsigned int u = xp[(size_t)sj * 16 + i];
            ax = fmaf(bflo(u), wj, ax);
            ay = fmaf(bfhi(u), wj, ay);
        }
    }
    if (g == 0) {   // self loop, once
        unsigned int u = xp[(size_t)wid * 16 + i];
        ax = fmaf(bflo(u), dc, ax);
        ay = fmaf(bfhi(u), dc, ay);
    }
    // reduce across the 4 groups
    ax += __shfl_xor(ax, 16); ax += __shfl_xor(ax, 32);
    ay += __shfl_xor(ay, 16); ay += __shfl_xor(ay, 32);
    if (lane < 16)
        y0[(size_t)wid * 16 + i] = pack2bf(ax * dc, ay * dc);
}

// --- GEMM1: y1 = relu(y0 @ W1 + b1)  (y0 bf16[n][32], K=25 real) -----------
__global__ __launch_bounds__(256) void gemm1_kernel(const unsigned int* __restrict__ y0,
                                                    const float* __restrict__ W,
                                                    const float* __restrict__ bias,
                                                    float* __restrict__ y1, int n) {
    __shared__ float lw[25 * HID];
    for (int i = threadIdx.x; i < 25 * HID; i += 256) lw[i] = W[i];
    __syncthreads();
    int g = threadIdx.x >> 7, c = threadIdx.x & 127;
    float bc = bias[c];
    for (int r = blockIdx.x * 2 + g; r < n; r += gridDim.x * 2) {
        const unsigned int* yr = y0 + (size_t)r * 16;
        float acc = bc;
        #pragma unroll
        for (int j = 0; j < 12; ++j) {
            unsigned int u = yr[j];
            acc = fmaf(bflo(u), lw[(j * 2 + 0) * HID + c], acc);
            acc = fmaf(bfhi(u), lw[(j * 2 + 1) * HID + c], acc);
        }
        acc = fmaf(bflo(yr[12]), lw[24 * HID + c], acc);
        y1[(size_t)r * HID + c] = fmaxf(acc, 0.f);
    }
}

// --- propagation (128-dim, layer 2): 8-way unrolled gather loop ------------
__global__ __launch_bounds__(256) void propagate_kernel(
    const unsigned short* __restrict__ h, const int* __restrict__ rowptr,
    const int* __restrict__ edge_src, const float* __restrict__ dinv,
    const float* __restrict__ bias, float* __restrict__ out, int n) {
    int wid = (blockIdx.x * 256 + threadIdx.x) >> 6;
    if (wid >= n) return;
    int lane = threadIdx.x & 63;
    int beg = rowptr[wid], end = rowptr[wid + 1];
    float dc = dinv[wid];
    float ax = 0.f, ay = 0.f;
    const unsigned int* hp = (const unsigned int*)h;  // 64 uints per row
    for (int b = beg; b < end; b += 64) {
        int m = end - b; if (m > 64) m = 64;
        int s = 0; float w = 0.f;
        if (lane < m) { s = edge_src[b + lane]; w = dinv[s]; }
        int j = 0;
        for (; j + 8 <= m; j += 8) {
            int s0 = __shfl(s, j + 0), s1 = __shfl(s, j + 1);
            int s2 = __shfl(s, j + 2), s3 = __shfl(s, j + 3);
            int s4 = __shfl(s, j + 4), s5 = __shfl(s, j + 5);
            int s6 = __shfl(s, j + 6), s7 = __shfl(s, j + 7);
            unsigned int v0 = hp[(size_t)s0 * 64 + lane];
            unsigned int v1 = hp[(size_t)s1 * 64 + lane];
            unsigned int v2 = hp[(size_t)s2 * 64 + lane];
            unsigned int v3 = hp[(size_t)s3 * 64 + lane];
            unsigned int v4 = hp[(size_t)s4 * 64 + lane];
            unsigned int v5 = hp[(size_t)s5 * 64 + lane];
            unsigned int v6 = hp[(size_t)s6 * 64 + lane];
            unsigned int v7 = hp[(size_t)s7 * 64 + lane];
            float w0 = __shfl(w, j + 0), w1 = __shfl(w, j + 1);
            float w2 = __shfl(w, j + 2), w3 = __shfl(w, j + 3);
            float w4 = __shfl(w, j + 4), w5 = __shfl(w, j + 5);
            float w6 = __shfl(w, j + 6), w7 = __shfl(w, j + 7);
            ax = fmaf(bflo(v0), w0, ax); ay = fmaf(bfhi(v0), w0, ay);
            ax = fmaf(bflo(v1), w1, ax); ay = fmaf(bfhi(v1), w1, ay);
            ax = fmaf(bflo(v2), w2, ax); ay = fmaf(bfhi(v2), w2, ay);
            ax = fmaf(bflo(v3), w3, ax); ay = fmaf(bfhi(v3), w3, ay);
            ax = fmaf(bflo(v4), w4, ax); ay = fmaf(bfhi(v4), w4, ay);
            ax = fmaf(bflo(v5), w5, ax); ay = fmaf(bfhi(v5), w5, ay);
            ax = fmaf(bflo(v6), w6, ax); ay = fmaf(bfhi(v6), w6, ay);
            ax = fmaf(bflo(v7), w7, ax); ay = fmaf(bfhi(v7), w7, ay);
        }
        for (; j < m; ++j) {
            int sj = __shfl(s, j);
            float wj = __shfl(w, j);
            unsigned int v = hp[(size_t)sj * 64 + lane];
            ax = fmaf(bflo(v), wj, ax);
            ay = fmaf(bfhi(v), wj, ay);
        }
    }
    {   // self loop
        unsigned int v = hp[(size_t)wid * 64 + lane];
        ax = fmaf(bflo(v), dc, ax);
        ay = fmaf(bfhi(v), dc, ay);
    }
    float bx = bias[lane * 2], by = bias[lane * 2 + 1];
    ax = fmaxf(fmaf(ax, dc, bx), 0.f);
    ay = fmaxf(fmaf(ay, dc, by), 0.f);
    *(float2*)(out + (size_t)wid * HID + lane * 2) = make_float2(ax, ay);
}

// --- BN stats: per-channel sum and sumsq -----------------------------------
__global__ __launch_bounds__(256) void bn_stats_kernel(const float* __restrict__ y,
                                                       float* __restrict__ sum,
                                                       float* __restrict__ sumsq, int n) {
    int c = threadIdx.x & 127;
    int g = threadIdx.x >> 7;
    float s = 0.f, s2 = 0.f;
    for (int r = blockIdx.x * 2 + g; r < n; r += gridDim.x * 2) {
        float v = y[(size_t)r * HID + c];
        s += v;
        s2 = fmaf(v, v, s2);
    }
    __shared__ float ls[256], ls2[256];
    ls[threadIdx.x] = s; ls2[threadIdx.x] = s2;
    __syncthreads();
    if (threadIdx.x < 128) {
        atomicAdd(&sum[c], ls[threadIdx.x] + ls[threadIdx.x + 128]);
        atomicAdd(&sumsq[c], ls2[threadIdx.x] + ls2[threadIdx.x + 128]);
    }
}

__global__ void bn_finalize_kernel(const float* __restrict__ sum, const float* __restrict__ sumsq,
                                   const float* __restrict__ gamma, const float* __restrict__ beta,
                                   float* __restrict__ scale, float* __restrict__ shift, float inv_n) {
    int c = threadIdx.x;
    float mean = sum[c] * inv_n;
    float var = sumsq[c] * inv_n - mean * mean;
    float sc = gamma[c] * rsqrtf(var + 1e-5f);
    scale[c] = sc;
    shift[c] = beta[c] - mean * sc;
}

// --- W2 transpose + bf16 cast: Wt[c][k] = bf16(W2[k][c]) -------------------
__global__ __launch_bounds__(256) void wt_kernel(const float* __restrict__ W,
                                                 unsigned short* __restrict__ Wt) {
    int idx = blockIdx.x * 256 + threadIdx.x;
    int c = idx >> 7, k = idx & 127;
    Wt[c * 128 + k] = f2bf(W[k * 128 + c]);
}

// --- GEMM2 via MFMA: h2 = bf16(bn(y1) @ W2), K=128 -------------------------
__global__ __launch_bounds__(256) void gemm2_mfma_kernel(
    const float* __restrict__ y, const unsigned short* __restrict__ Wt,
    const float* __restrict__ scale, const float* __restrict__ shift,
    unsigned short* __restrict__ out, int n) {
    __shared__ unsigned short lwt[128 * 136];
    __shared__ unsigned short ly[128 * 136];
    int t = threadIdx.x;
    int base = blockIdx.x * 128;

    // stage Wt: 128 rows x 128 bf16 (64 uints/row), coalesced; LDS stride 68 uints
    {
        const unsigned int* w32 = (const unsigned int*)Wt;
        unsigned int* l32 = (unsigned int*)lwt;
        #pragma unroll
        for (int i = 0; i < 32; ++i) {
            int idx = t + i * 256;
            int r = idx >> 6, cp = idx & 63;
            l32[r * 68 + cp] = w32[r * 64 + cp];
        }
    }
    // stage y tile with BN + bf16 cvt: 2 threads/row, 64 k each
    {
        int r = t >> 1, hh = t & 1;
        int gr = base + r;
        unsigned int* l32 = (unsigned int*)ly;
        const float4* yrow = (const float4*)(y + (size_t)gr * HID + hh * 64);
        #pragma unroll
        for (int j = 0; j < 16; ++j) {
            float4 v = make_float4(0.f, 0.f, 0.f, 0.f);
            if (gr < n) v = yrow[j];
            int gk = hh * 64 + j * 4;
            float a0 = fmaf(v.x, scale[gk + 0], shift[gk + 0]);
            float a1 = fmaf(v.y, scale[gk + 1], shift[gk + 1]);
            float a2 = fmaf(v.z, scale[gk + 2], shift[gk + 2]);
            float a3 = fmaf(v.w, scale[gk + 3], shift[gk + 3]);
            l32[r * 68 + hh * 32 + j * 2 + 0] = pack2bf(a0, a1);
            l32[r * 68 + hh * 32 + j * 2 + 1] = pack2bf(a2, a3);
        }
    }
    __syncthreads();

    int w = t >> 6, lane = t & 63;
    int li = lane & 15, lg = lane >> 4;
    f32x4 acc[2][8];
    #pragma unroll
    for (int a = 0; a < 2; ++a)
        #pragma unroll
        for (int b = 0; b < 8; ++b) acc[a][b] = (f32x4){0.f, 0.f, 0.f, 0.f};

    #pragma unroll
    for (int ks = 0; ks < 4; ++ks) {
        int kb = ks * 32 + lg * 8;
        bf16x8 af[2], bfr[8];
        #pragma unroll
        for (int rt = 0; rt < 2; ++rt)
            af[rt] = *(const bf16x8*)&ly[(w * 32 + rt * 16 + li) * 136 + kb];
        #pragma unroll
        for (int cf = 0; cf < 8; ++cf)
            bfr[cf] = *(const bf16x8*)&lwt[(cf * 16 + li) * 136 + kb];
        #pragma unroll
        for (int rt = 0; rt < 2; ++rt)
            #pragma unroll
            for (int cf = 0; cf < 8; ++cf)
                acc[rt][cf] = __builtin_amdgcn_mfma_f32_16x16x32_bf16(
                    af[rt], bfr[cf], acc[rt][cf], 0, 0, 0);
    }

    // epilogue: D row = (lane>>4)*4 + reg, col = cf*16 + (lane&15)
    #pragma unroll
    for (int rt = 0; rt < 2; ++rt) {
        #pragma unroll
        for (int reg = 0; reg < 4; ++reg) {
            int gr = base + w * 32 + rt * 16 + lg * 4 + reg;
            if (gr < n) {
                #pragma unroll
                for (int cf = 0; cf < 8; ++cf)
                    out[(size_t)gr * HID + cf * 16 + li] = f2bf(acc[rt][cf][reg]);
            }
        }
    }
}

extern "C" void kernel_launch(void* const* d_in, const int* in_sizes, int n_in,
                              void* d_out, int out_size, void* d_ws, size_t ws_size,
                              hipStream_t stream) {
    const float* x     = (const float*)d_in[0];
    const void*  ei    = d_in[1];
    const float* W1    = (const float*)d_in[2];
    const float* b1    = (const float*)d_in[3];
    const float* gamma = (const float*)d_in[4];
    const float* beta  = (const float*)d_in[5];
    const float* W2    = (const float*)d_in[6];
    const float* b2    = (const float*)d_in[7];
    float* out = (float*)d_out;

    const int f_in = 25;
    int n = in_sizes[0] / f_in;
    int E = in_sizes[1] / 2;
    int nchunk = (n + 255) >> 8;                 // 256-node chunks (391)
    int NQ = nchunk * NBB;                       // queue segments (200192)
    int nsb = (NQ + 2047) / 2048;                // scan blocks (98, <=1024)
    int CHUNK = (E + NBB - 1) / NBB;             // edges per bin block

    char* ws = (char*)d_ws;
    size_t off = 0;
    auto alloc = [&](size_t bytes) -> void* {
        void* p = ws + off;
        off += (bytes + 511) & ~(size_t)511;
        return p;
    };
    int*   rowptr    = (int*)alloc(((size_t)n + 1) * 4);
    float* dinv      = (float*)alloc((size_t)n * 4);
    int*   edge_src  = (int*)alloc((size_t)E * 4);
    unsigned int* packed = (unsigned int*)alloc((size_t)E * 4);
    int*   qcnt      = (int*)alloc((size_t)NQ * 4);
    int*   qoff      = (int*)alloc(((size_t)NQ + 1) * 4);
    int*   blocksum  = (int*)alloc((size_t)nsb * 4);
    int*   blockoff  = (int*)alloc((size_t)nsb * 4);
    float* bnacc     = (float*)alloc(256 * 4);   // sum[128] ++ sumsq[128]
    float* sclshift  = (float*)alloc(256 * 4);   // scale[128] ++ shift[128]
    int*   mode      = (int*)alloc(4);
    unsigned int* xp  = (unsigned int*)alloc((size_t)n * 16 * 4);  // bf16[n][32]
    unsigned int* y0  = (unsigned int*)alloc((size_t)n * 16 * 4);  // bf16[n][32]
    unsigned short* Wt = (unsigned short*)alloc(128 * 128 * 2);    // bf16 W2^T
    unsigned short* h  = (unsigned short*)alloc((size_t)n * HID * 2);  // bf16 h2

    hipMemsetAsync(bnacc, 0, 256 * 4, stream);

    detect_kernel<<<1, 256, 0, stream>>>((const unsigned int*)ei, mode, 2 * E);
    count_q_kernel<<<NBB, 256, 0, stream>>>(ei, mode, qcnt, E, CHUNK, nchunk);
    scanq_partial_kernel<<<nsb, 256, 0, stream>>>(qcnt, blocksum, NQ, nchunk);
    scanq_blocksums_kernel<<<1, 1024, 0, stream>>>(blocksum, blockoff, qoff, nsb, NQ);
    scanq_finalize_kernel<<<nsb, 256, 0, stream>>>(qcnt, blockoff, qoff, NQ, nchunk);
    bin_kernel<<<NBB, 256, 0, stream>>>(ei, mode, qoff, packed, E, CHUNK, nchunk);
    chunk_build_kernel<<<nchunk, 256, 0, stream>>>(packed, qoff, rowptr, dinv, edge_src, n, E);

    // layer 1 (commuted): y0 = A_hat@x (32-dim bf16, L2-resident gather);
    // y1 = relu(y0@W1 + b1) -> d_out (fp32)
    xpad_kernel<<<(n + 255) / 256, 256, 0, stream>>>(x, xp, n);
    prop_x_kernel<<<(n + 3) / 4, 256, 0, stream>>>(xp, rowptr, edge_src, dinv, y0, n);
    gemm1_kernel<<<4096, 256, 0, stream>>>(y0, W1, b1, out, n);

    // batchnorm stats on y1
    bn_stats_kernel<<<512, 256, 0, stream>>>(out, bnacc, bnacc + 128, n);
    bn_finalize_kernel<<<1, 128, 0, stream>>>(bnacc, bnacc + 128, gamma, beta,
                                              sclshift, sclshift + 128, 1.0f / (float)n);

    // layer 2: h2 = bf16(bn(y1)@W2) via MFMA ; out = relu(prop(h2) + b2)
    wt_kernel<<<64, 256, 0, stream>>>(W2, Wt);
    gemm2_mfma_kernel<<<(n + 127) / 128, 256, 0, stream>>>(out, Wt, sclshift, sclshift + 128, h, n);
    propagate_kernel<<<(n + 3) / 4, 256, 0, stream>>>(h, rowptr, edge_src, dinv, b2, out, n);
}

// Round 21
// 278.865 us; speedup vs baseline: 1.5797x; 1.0125x over previous
//
#include <hip/hip_runtime.h>
#include <stdint.h>

// ---------------------------------------------------------------------------
// 2-layer GCN: relu(gcn(x,W1,b1)) -> batchnorm -> relu(gcn(.,W2,b2))
// n=100000, E=1.6M, f_in=25, hid=128.
// R2 scan / R6 bf16+tile / R10 scatter / R14 pipelined gather / R15 MFMA /
// R18 zero-atomic CSR build / R19 commuted layer-1 (312 -> 282).
// R21: (a) layer-2 propagate: 2 edges/step via uint2 loads (4 feats/lane,
//     lanes 0-31 even edge, 32-63 odd; per-lane-index shfl; pair-combine
//     shfl_xor(32)). Halves gather instrs; was 78% of the 196MB/3.7TB/s
//     fetch floor. (b) BN stats fused into gemm1 epilogue (y1 values are
//     already in registers; saves the separate 51MB bn_stats read pass).
// ---------------------------------------------------------------------------

#define HID 128
#define NBB 512          // binning blocks (power of 2; segment index j = q*512+b)

typedef short bf16x8 __attribute__((ext_vector_type(8)));
typedef float f32x4 __attribute__((ext_vector_type(4)));

__device__ __forceinline__ unsigned short f2bf(float f) {
    unsigned int u = __float_as_uint(f);
    unsigned int r = (u + 0x7FFFu + ((u >> 16) & 1u)) >> 16;  // RNE
    return (unsigned short)r;
}
__device__ __forceinline__ unsigned int pack2bf(float lo, float hi) {
    return (unsigned int)f2bf(lo) | ((unsigned int)f2bf(hi) << 16);
}
__device__ __forceinline__ float bflo(unsigned int v) { return __uint_as_float(v << 16); }
__device__ __forceinline__ float bfhi(unsigned int v) { return __uint_as_float(v & 0xffff0000u); }

// --- detect whether edge_index buffer is int64 or int32 --------------------
__global__ void detect_kernel(const unsigned int* __restrict__ w, int* __restrict__ mode, int nwords) {
    __shared__ int any;
    if (threadIdx.x == 0) any = 0;
    __syncthreads();
    for (int i = threadIdx.x * 2 + 1; i < nwords && i < 8192; i += 512) {
        if (w[i] != 0) atomicOr(&any, 1);
    }
    __syncthreads();
    if (threadIdx.x == 0) *mode = any ? 0 : 1;  // 1 => int64 layout
}

__device__ __forceinline__ int load_idx(const void* ei, size_t i, int mode) {
    return mode ? (int)((const long long*)ei)[i] : ((const int*)ei)[i];
}

// --- count_q: per-(block, 256-node-chunk) tallies, LDS only ----------------
__global__ __launch_bounds__(256) void count_q_kernel(const void* __restrict__ ei,
                                                      const int* __restrict__ modep,
                                                      int* __restrict__ qcnt,
                                                      int E, int CHUNK, int nchunk) {
    __shared__ int qc[512];
    for (int i = threadIdx.x; i < nchunk; i += 256) qc[i] = 0;
    __syncthreads();
    int mode = *modep;
    int beg = blockIdx.x * CHUNK;
    int end = beg + CHUNK; if (end > E) end = E;
    for (int e = beg + threadIdx.x; e < end; e += 256) {
        int c = load_idx(ei, (size_t)E + e, mode);
        atomicAdd(&qc[c >> 8], 1);       // LDS atomic
    }
    __syncthreads();
    for (int i = threadIdx.x; i < nchunk; i += 256)
        qcnt[blockIdx.x * nchunk + i] = qc[i];   // b-major storage, coalesced
}

// --- scan_q phase 1: partial sums over scan-order positions ----------------
// scan order j = q*NBB + b  (q-major);  qcnt stored b-major: qcnt[b*nchunk+q]
__global__ __launch_bounds__(256) void scanq_partial_kernel(const int* __restrict__ qcnt,
                                                            int* __restrict__ blocksum,
                                                            int NQ, int nchunk) {
    int j0 = blockIdx.x * 2048 + threadIdx.x * 8;
    int s = 0;
    #pragma unroll
    for (int i = 0; i < 8; ++i) {
        int j = j0 + i;
        if (j < NQ) {
            int q = j >> 9, b = j & (NBB - 1);
            s += qcnt[b * nchunk + q];
        }
    }
    #pragma unroll
    for (int off = 32; off > 0; off >>= 1) s += __shfl_down(s, off);
    __shared__ int ls[4];
    if ((threadIdx.x & 63) == 0) ls[threadIdx.x >> 6] = s;
    __syncthreads();
    if (threadIdx.x == 0) blocksum[blockIdx.x] = ls[0] + ls[1] + ls[2] + ls[3];
}

// --- scan_q phase 2: scan block sums (nsb <= 1024) -------------------------
__global__ __launch_bounds__(1024) void scanq_blocksums_kernel(const int* __restrict__ blocksum,
                                                               int* __restrict__ blockoff,
                                                               int* __restrict__ qoff,
                                                               int nsb, int NQ) {
    __shared__ int s[1024];
    int t = threadIdx.x;
    int own = (t < nsb) ? blocksum[t] : 0;
    s[t] = own;
    __syncthreads();
    for (int off = 1; off < 1024; off <<= 1) {
        int v = s[t] + ((t >= off) ? s[t - off] : 0);
        __syncthreads();
        s[t] = v;
        __syncthreads();
    }
    if (t < nsb) blockoff[t] = s[t] - own;   // exclusive
    if (t == 1023) qoff[NQ] = s[1023];       // total == E
}

// --- scan_q phase 3: per-position exclusive prefix -> qoff -----------------
__global__ __launch_bounds__(256) void scanq_finalize_kernel(const int* __restrict__ qcnt,
                                                             const int* __restrict__ blockoff,
                                                             int* __restrict__ qoff,
                                                             int NQ, int nchunk) {
    int t = threadIdx.x;
    int j0 = blockIdx.x * 2048 + t * 8;
    int v[8], own = 0;
    #pragma unroll
    for (int i = 0; i < 8; ++i) {
        int j = j0 + i;
        v[i] = 0;
        if (j < NQ) {
            int q = j >> 9, b = j & (NBB - 1);
            v[i] = qcnt[b * nchunk + q];
        }
        own += v[i];
    }
    __shared__ int s[256];
    s[t] = own;
    __syncthreads();
    for (int off = 1; off < 256; off <<= 1) {
        int x = s[t] + ((t >= off) ? s[t - off] : 0);
        __syncthreads();
        s[t] = x;
        __syncthreads();
    }
    int e = blockoff[blockIdx.x] + s[t] - own;
    #pragma unroll
    for (int i = 0; i < 8; ++i) {
        int j = j0 + i;
        if (j < NQ) qoff[j] = e;
        e += v[i];
    }
}

// --- bin: append packed (c&255)<<24 | r into private segments (LDS cursors)-
__global__ __launch_bounds__(256) void bin_kernel(const void* __restrict__ ei,
                                                  const int* __restrict__ modep,
                                                  const int* __restrict__ qoff,
                                                  unsigned int* __restrict__ packed,
                                                  int E, int CHUNK, int nchunk) {
    __shared__ int cur[512];
    for (int i = threadIdx.x; i < nchunk; i += 256)
        cur[i] = qoff[i * NBB + blockIdx.x];
    __syncthreads();
    int mode = *modep;
    int beg = blockIdx.x * CHUNK;
    int end = beg + CHUNK; if (end > E) end = E;
    for (int e = beg + threadIdx.x; e < end; e += 256) {
        int c = load_idx(ei, (size_t)E + e, mode);
        int r = load_idx(ei, (size_t)e, mode);
        int pos = atomicAdd(&cur[c >> 8], 1);    // LDS atomic
        packed[pos] = ((unsigned)(c & 255) << 24) | (unsigned)r;
    }
}

// --- chunk_build: per-chunk histogram + scan -> rowptr/dinv, then place ----
__global__ __launch_bounds__(256) void chunk_build_kernel(
    const unsigned int* __restrict__ packed, const int* __restrict__ qoff,
    int* __restrict__ rowptr, float* __restrict__ dinv,
    int* __restrict__ edge_src, int n, int E) {
    int q = blockIdx.x;
    int t = threadIdx.x;
    int pbeg = qoff[q * NBB];
    int pend = qoff[(q + 1) * NBB];   // last chunk: (q+1)*NBB == NQ, qoff[NQ]=E
    __shared__ int cnt256[256], cur[256], s[256];
    cnt256[t] = 0;
    __syncthreads();
    for (int i = pbeg + t; i < pend; i += 256)
        atomicAdd(&cnt256[packed[i] >> 24], 1);  // LDS atomic
    __syncthreads();
    int own = cnt256[t];
    s[t] = own;
    __syncthreads();
    for (int off = 1; off < 256; off <<= 1) {
        int x = s[t] + ((t >= off) ? s[t - off] : 0);
        __syncthreads();
        s[t] = x;
        __syncthreads();
    }
    int pref = s[t] - own;   // exclusive within chunk
    int node = (q << 8) + t;
    if (node < n) {
        rowptr[node] = pbeg + pref;
        dinv[node] = rsqrtf((float)(own + 1));   // +1 self loop
    }
    cur[t] = pbeg + pref;
    if (q == gridDim.x - 1 && t == 0) rowptr[n] = E;
    __syncthreads();
    for (int i = pbeg + t; i < pend; i += 256) {
        unsigned int u = packed[i];
        int pos = atomicAdd(&cur[u >> 24], 1);   // LDS atomic
        edge_src[pos] = (int)(u & 0xFFFFFFu);
    }
}

// --- xpad: x fp32 [n][25] -> bf16 [n][32] (zero-padded) --------------------
__global__ __launch_bounds__(256) void xpad_kernel(const float* __restrict__ x,
                                                   unsigned int* __restrict__ xp, int n) {
    int r = blockIdx.x * 256 + threadIdx.x;
    if (r >= n) return;
    const float* xr = x + (size_t)r * 25;
    unsigned int* o = xp + (size_t)r * 16;
    #pragma unroll
    for (int j = 0; j < 12; ++j)
        o[j] = pack2bf(xr[j * 2], xr[j * 2 + 1]);
    o[12] = pack2bf(xr[24], 0.f);
    o[13] = 0u; o[14] = 0u; o[15] = 0u;
}

// --- prop_x: y0 = dinv[c]*(sum_e x[r]*dinv[r] + x[c]*dinv[c]) in 32-dim ----
__global__ __launch_bounds__(256) void prop_x_kernel(
    const unsigned int* __restrict__ xp, const int* __restrict__ rowptr,
    const int* __restrict__ edge_src, const float* __restrict__ dinv,
    unsigned int* __restrict__ y0, int n) {
    int wid = (blockIdx.x * 256 + threadIdx.x) >> 6;
    if (wid >= n) return;
    int lane = threadIdx.x & 63;
    int g = lane >> 4, i = lane & 15;
    int beg = rowptr[wid], end = rowptr[wid + 1];
    float dc = dinv[wid];
    float ax = 0.f, ay = 0.f;
    for (int b = beg; b < end; b += 64) {
        int m = end - b; if (m > 64) m = 64;
        int s = 0; float w = 0.f;
        if (lane < m) { s = edge_src[b + lane]; w = dinv[s]; }
        int nsteps = (m + 3) >> 2;
        for (int t = 0; t < nsteps; ++t) {
            int e = 4 * t + g;
            int sj = __shfl(s, e & 63);
            float wj = __shfl(w, e & 63);
            if (e >= m) { sj = 0; wj = 0.f; }
            unsigned int u = xp[(size_t)sj * 16 + i];
            ax = fmaf(bflo(u), wj, ax);
            ay = fmaf(bfhi(u), wj, ay);
        }
    }
    if (g == 0) {   // self loop, once
        unsigned int u = xp[(size_t)wid * 16 + i];
        ax = fmaf(bflo(u), dc, ax);
        ay = fmaf(bfhi(u), dc, ay);
    }
    ax += __shfl_xor(ax, 16); ax += __shfl_xor(ax, 32);
    ay += __shfl_xor(ay, 16); ay += __shfl_xor(ay, 32);
    if (lane < 16)
        y0[(size_t)wid * 16 + i] = pack2bf(ax * dc, ay * dc);
}

// --- GEMM1 + fused BN stats: y1 = relu(y0@W1 + b1); accumulate sum/sumsq ---
__global__ __launch_bounds__(256) void gemm1_kernel(const unsigned int* __restrict__ y0,
                                                    const float* __restrict__ W,
                                                    const float* __restrict__ bias,
                                                    float* __restrict__ y1,
                                                    float* __restrict__ bnsum,
                                                    float* __restrict__ bnsumsq, int n) {
    __shared__ float lw[25 * HID];
    for (int i = threadIdx.x; i < 25 * HID; i += 256) lw[i] = W[i];
    __syncthreads();
    int g = threadIdx.x >> 7, c = threadIdx.x & 127;
    float bc = bias[c];
    float s = 0.f, s2 = 0.f;
    for (int r = blockIdx.x * 2 + g; r < n; r += gridDim.x * 2) {
        const unsigned int* yr = y0 + (size_t)r * 16;
        float acc = bc;
        #pragma unroll
        for (int j = 0; j < 12; ++j) {
            unsigned int u = yr[j];
            acc = fmaf(bflo(u), lw[(j * 2 + 0) * HID + c], acc);
            acc = fmaf(bfhi(u), lw[(j * 2 + 1) * HID + c], acc);
        }
        acc = fmaf(bflo(yr[12]), lw[24 * HID + c], acc);
        acc = fmaxf(acc, 0.f);
        y1[(size_t)r * HID + c] = acc;
        s += acc;
        s2 = fmaf(acc, acc, s2);
    }
    __shared__ float ls[256], ls2[256];
    ls[threadIdx.x] = s; ls2[threadIdx.x] = s2;
    __syncthreads();
    if (threadIdx.x < 128) {
        atomicAdd(&bnsum[c], ls[threadIdx.x] + ls[threadIdx.x + 128]);
        atomicAdd(&bnsumsq[c], ls2[threadIdx.x] + ls2[threadIdx.x + 128]);
    }
}

// --- propagation (128-dim, layer 2): 2 edges/step, uint2 (4 feats/lane) ----
// lanes 0-31 process even edges, 32-63 odd; pair-combine via shfl_xor(32).
__global__ __launch_bounds__(256) void propagate_kernel(
    const unsigned short* __restrict__ h, const int* __restrict__ rowptr,
    const int* __restrict__ edge_src, const float* __restrict__ dinv,
    const float* __restrict__ bias, float* __restrict__ out, int n) {
    int wid = (blockIdx.x * 256 + threadIdx.x) >> 6;
    if (wid >= n) return;
    int lane = threadIdx.x & 63;
    int half = lane >> 5;        // 0: even edges, 1: odd edges
    int f = lane & 31;           // feature block (4 bf16 = 1 uint2)
    int beg = rowptr[wid], end = rowptr[wid + 1];
    float dc = dinv[wid];
    float a0 = 0.f, a1 = 0.f, a2 = 0.f, a3 = 0.f;
    const uint2* hp = (const uint2*)h;  // 32 uint2 per row
    for (int b = beg; b < end; b += 64) {
        int m = end - b; if (m > 64) m = 64;
        int s = 0; float w = 0.f;
        if (lane < m) { s = edge_src[b + lane]; w = dinv[s]; }
        int j = 0;
        for (; j + 16 <= m; j += 16) {
            int e0_ = j + half,      e1_ = j + 2 + half,  e2_ = j + 4 + half,  e3_ = j + 6 + half;
            int e4_ = j + 8 + half,  e5_ = j + 10 + half, e6_ = j + 12 + half, e7_ = j + 14 + half;
            int t0 = __shfl(s, e0_), t1 = __shfl(s, e1_), t2 = __shfl(s, e2_), t3 = __shfl(s, e3_);
            int t4 = __shfl(s, e4_), t5 = __shfl(s, e5_), t6 = __shfl(s, e6_), t7 = __shfl(s, e7_);
            uint2 v0 = hp[(size_t)t0 * 32 + f];
            uint2 v1 = hp[(size_t)t1 * 32 + f];
            uint2 v2 = hp[(size_t)t2 * 32 + f];
            uint2 v3 = hp[(size_t)t3 * 32 + f];
            uint2 v4 = hp[(size_t)t4 * 32 + f];
            uint2 v5 = hp[(size_t)t5 * 32 + f];
            uint2 v6 = hp[(size_t)t6 * 32 + f];
            uint2 v7 = hp[(size_t)t7 * 32 + f];
            float w0 = __shfl(w, e0_), w1 = __shfl(w, e1_), w2 = __shfl(w, e2_), w3 = __shfl(w, e3_);
            float w4 = __shfl(w, e4_), w5 = __shfl(w, e5_), w6 = __shfl(w, e6_), w7 = __shfl(w, e7_);
            a0 = fmaf(bflo(v0.x), w0, a0); a1 = fmaf(bfhi(v0.x), w0, a1);
            a2 = fmaf(bflo(v0.y), w0, a2); a3 = fmaf(bfhi(v0.y), w0, a3);
            a0 = fmaf(bflo(v1.x), w1, a0); a1 = fmaf(bfhi(v1.x), w1, a1);
            a2 = fmaf(bflo(v1.y), w1, a2); a3 = fmaf(bfhi(v1.y), w1, a3);
            a0 = fmaf(bflo(v2.x), w2, a0); a1 = fmaf(bfhi(v2.x), w2, a1);
            a2 = fmaf(bflo(v2.y), w2, a2); a3 = fmaf(bfhi(v2.y), w2, a3);
            a0 = fmaf(bflo(v3.x), w3, a0); a1 = fmaf(bfhi(v3.x), w3, a1);
            a2 = fmaf(bflo(v3.y), w3, a2); a3 = fmaf(bfhi(v3.y), w3, a3);
            a0 = fmaf(bflo(v4.x), w4, a0); a1 = fmaf(bfhi(v4.x), w4, a1);
            a2 = fmaf(bflo(v4.y), w4, a2); a3 = fmaf(bfhi(v4.y), w4, a3);
            a0 = fmaf(bflo(v5.x), w5, a0); a1 = fmaf(bfhi(v5.x), w5, a1);
            a2 = fmaf(bflo(v5.y), w5, a2); a3 = fmaf(bfhi(v5.y), w5, a3);
            a0 = fmaf(bflo(v6.x), w6, a0); a1 = fmaf(bfhi(v6.x), w6, a1);
            a2 = fmaf(bflo(v6.y), w6, a2); a3 = fmaf(bfhi(v6.y), w6, a3);
            a0 = fmaf(bflo(v7.x), w7, a0); a1 = fmaf(bfhi(v7.x), w7, a1);
            a2 = fmaf(bflo(v7.y), w7, a2); a3 = fmaf(bfhi(v7.y), w7, a3);
        }
        for (; j < m; j += 2) {
            int e = j + half;
            int sj = __shfl(s, e & 63);
            float wj = __shfl(w, e & 63);
            if (e >= m) { sj = 0; wj = 0.f; }
            uint2 v = hp[(size_t)sj * 32 + f];
            a0 = fmaf(bflo(v.x), wj, a0); a1 = fmaf(bfhi(v.x), wj, a1);
            a2 = fmaf(bflo(v.y), wj, a2); a3 = fmaf(bfhi(v.y), wj, a3);
        }
    }
    // combine even/odd halves
    a0 += __shfl_xor(a0, 32);
    a1 += __shfl_xor(a1, 32);
    a2 += __shfl_xor(a2, 32);
    a3 += __shfl_xor(a3, 32);
    {   // self loop (post-combine; both halves compute, lanes<32 write)
        uint2 v = hp[(size_t)wid * 32 + f];
        a0 = fmaf(bflo(v.x), dc, a0); a1 = fmaf(bfhi(v.x), dc, a1);
        a2 = fmaf(bflo(v.y), dc, a2); a3 = fmaf(bfhi(v.y), dc, a3);
    }
    if (lane < 32) {
        float4 bv = ((const float4*)bias)[f];
        float4 r;
        r.x = fmaxf(fmaf(a0, dc, bv.x), 0.f);
        r.y = fmaxf(fmaf(a1, dc, bv.y), 0.f);
        r.z = fmaxf(fmaf(a2, dc, bv.z), 0.f);
        r.w = fmaxf(fmaf(a3, dc, bv.w), 0.f);
        *(float4*)(out + (size_t)wid * HID + f * 4) = r;
    }
}

__global__ void bn_finalize_kernel(const float* __restrict__ sum, const float* __restrict__ sumsq,
                                   const float* __restrict__ gamma, const float* __restrict__ beta,
                                   float* __restrict__ scale, float* __restrict__ shift, float inv_n) {
    int c = threadIdx.x;
    float mean = sum[c] * inv_n;
    float var = sumsq[c] * inv_n - mean * mean;
    float sc = gamma[c] * rsqrtf(var + 1e-5f);
    scale[c] = sc;
    shift[c] = beta[c] - mean * sc;
}

// --- W2 transpose + bf16 cast: Wt[c][k] = bf16(W2[k][c]) -------------------
__global__ __launch_bounds__(256) void wt_kernel(const float* __restrict__ W,
                                                 unsigned short* __restrict__ Wt) {
    int idx = blockIdx.x * 256 + threadIdx.x;
    int c = idx >> 7, k = idx & 127;
    Wt[c * 128 + k] = f2bf(W[k * 128 + c]);
}

// --- GEMM2 via MFMA: h2 = bf16(bn(y1) @ W2), K=128 -------------------------
__global__ __launch_bounds__(256) void gemm2_mfma_kernel(
    const float* __restrict__ y, const unsigned short* __restrict__ Wt,
    const float* __restrict__ scale, const float* __restrict__ shift,
    unsigned short* __restrict__ out, int n) {
    __shared__ unsigned short lwt[128 * 136];
    __shared__ unsigned short ly[128 * 136];
    int t = threadIdx.x;
    int base = blockIdx.x * 128;

    {
        const unsigned int* w32 = (const unsigned int*)Wt;
        unsigned int* l32 = (unsigned int*)lwt;
        #pragma unroll
        for (int i = 0; i < 32; ++i) {
            int idx = t + i * 256;
            int r = idx >> 6, cp = idx & 63;
            l32[r * 68 + cp] = w32[r * 64 + cp];
        }
    }
    {
        int r = t >> 1, hh = t & 1;
        int gr = base + r;
        unsigned int* l32 = (unsigned int*)ly;
        const float4* yrow = (const float4*)(y + (size_t)gr * HID + hh * 64);
        #pragma unroll
        for (int j = 0; j < 16; ++j) {
            float4 v = make_float4(0.f, 0.f, 0.f, 0.f);
            if (gr < n) v = yrow[j];
            int gk = hh * 64 + j * 4;
            float a0 = fmaf(v.x, scale[gk + 0], shift[gk + 0]);
            float a1 = fmaf(v.y, scale[gk + 1], shift[gk + 1]);
            float a2 = fmaf(v.z, scale[gk + 2], shift[gk + 2]);
            float a3 = fmaf(v.w, scale[gk + 3], shift[gk + 3]);
            l32[r * 68 + hh * 32 + j * 2 + 0] = pack2bf(a0, a1);
            l32[r * 68 + hh * 32 + j * 2 + 1] = pack2bf(a2, a3);
        }
    }
    __syncthreads();

    int w = t >> 6, lane = t & 63;
    int li = lane & 15, lg = lane >> 4;
    f32x4 acc[2][8];
    #pragma unroll
    for (int a = 0; a < 2; ++a)
        #pragma unroll
        for (int b = 0; b < 8; ++b) acc[a][b] = (f32x4){0.f, 0.f, 0.f, 0.f};

    #pragma unroll
    for (int ks = 0; ks < 4; ++ks) {
        int kb = ks * 32 + lg * 8;
        bf16x8 af[2], bfr[8];
        #pragma unroll
        for (int rt = 0; rt < 2; ++rt)
            af[rt] = *(const bf16x8*)&ly[(w * 32 + rt * 16 + li) * 136 + kb];
        #pragma unroll
        for (int cf = 0; cf < 8; ++cf)
            bfr[cf] = *(const bf16x8*)&lwt[(cf * 16 + li) * 136 + kb];
        #pragma unroll
        for (int rt = 0; rt < 2; ++rt)
            #pragma unroll
            for (int cf = 0; cf < 8; ++cf)
                acc[rt][cf] = __builtin_amdgcn_mfma_f32_16x16x32_bf16(
                    af[rt], bfr[cf], acc[rt][cf], 0, 0, 0);
    }

    #pragma unroll
    for (int rt = 0; rt < 2; ++rt) {
        #pragma unroll
        for (int reg = 0; reg < 4; ++reg) {
            int gr = base + w * 32 + rt * 16 + lg * 4 + reg;
            if (gr < n) {
                #pragma unroll
                for (int cf = 0; cf < 8; ++cf)
                    out[(size_t)gr * HID + cf * 16 + li] = f2bf(acc[rt][cf][reg]);
            }
        }
    }
}

extern "C" void kernel_launch(void* const* d_in, const int* in_sizes, int n_in,
                              void* d_out, int out_size, void* d_ws, size_t ws_size,
                              hipStream_t stream) {
    const float* x     = (const float*)d_in[0];
    const void*  ei    = d_in[1];
    const float* W1    = (const float*)d_in[2];
    const float* b1    = (const float*)d_in[3];
    const float* gamma = (const float*)d_in[4];
    const float* beta  = (const float*)d_in[5];
    const float* W2    = (const float*)d_in[6];
    const float* b2    = (const float*)d_in[7];
    float* out = (float*)d_out;

    const int f_in = 25;
    int n = in_sizes[0] / f_in;
    int E = in_sizes[1] / 2;
    int nchunk = (n + 255) >> 8;                 // 256-node chunks (391)
    int NQ = nchunk * NBB;                       // queue segments (200192)
    int nsb = (NQ + 2047) / 2048;                // scan blocks (98, <=1024)
    int CHUNK = (E + NBB - 1) / NBB;             // edges per bin block

    char* ws = (char*)d_ws;
    size_t off = 0;
    auto alloc = [&](size_t bytes) -> void* {
        void* p = ws + off;
        off += (bytes + 511) & ~(size_t)511;
        return p;
    };
    int*   rowptr    = (int*)alloc(((size_t)n + 1) * 4);
    float* dinv      = (float*)alloc((size_t)n * 4);
    int*   edge_src  = (int*)alloc((size_t)E * 4);
    unsigned int* packed = (unsigned int*)alloc((size_t)E * 4);
    int*   qcnt      = (int*)alloc((size_t)NQ * 4);
    int*   qoff      = (int*)alloc(((size_t)NQ + 1) * 4);
    int*   blocksum  = (int*)alloc((size_t)nsb * 4);
    int*   blockoff  = (int*)alloc((size_t)nsb * 4);
    float* bnacc     = (float*)alloc(256 * 4);   // sum[128] ++ sumsq[128]
    float* sclshift  = (float*)alloc(256 * 4);   // scale[128] ++ shift[128]
    int*   mode      = (int*)alloc(4);
    unsigned int* xp  = (unsigned int*)alloc((size_t)n * 16 * 4);  // bf16[n][32]
    unsigned int* y0  = (unsigned int*)alloc((size_t)n * 16 * 4);  // bf16[n][32]
    unsigned short* Wt = (unsigned short*)alloc(128 * 128 * 2);    // bf16 W2^T
    unsigned short* h  = (unsigned short*)alloc((size_t)n * HID * 2);  // bf16 h2

    hipMemsetAsync(bnacc, 0, 256 * 4, stream);

    detect_kernel<<<1, 256, 0, stream>>>((const unsigned int*)ei, mode, 2 * E);
    count_q_kernel<<<NBB, 256, 0, stream>>>(ei, mode, qcnt, E, CHUNK, nchunk);
    scanq_partial_kernel<<<nsb, 256, 0, stream>>>(qcnt, blocksum, NQ, nchunk);
    scanq_blocksums_kernel<<<1, 1024, 0, stream>>>(blocksum, blockoff, qoff, nsb, NQ);
    scanq_finalize_kernel<<<nsb, 256, 0, stream>>>(qcnt, blockoff, qoff, NQ, nchunk);
    bin_kernel<<<NBB, 256, 0, stream>>>(ei, mode, qoff, packed, E, CHUNK, nchunk);
    chunk_build_kernel<<<nchunk, 256, 0, stream>>>(packed, qoff, rowptr, dinv, edge_src, n, E);

    // layer 1 (commuted): y0 = A_hat@x ; y1 = relu(y0@W1 + b1) -> d_out,
    // with BN stats fused into gemm1
    xpad_kernel<<<(n + 255) / 256, 256, 0, stream>>>(x, xp, n);
    prop_x_kernel<<<(n + 3) / 4, 256, 0, stream>>>(xp, rowptr, edge_src, dinv, y0, n);
    gemm1_kernel<<<1024, 256, 0, stream>>>(y0, W1, b1, out, bnacc, bnacc + 128, n);

    bn_finalize_kernel<<<1, 128, 0, stream>>>(bnacc, bnacc + 128, gamma, beta,
                                              sclshift, sclshift + 128, 1.0f / (float)n);

    // layer 2: h2 = bf16(bn(y1)@W2) via MFMA ; out = relu(prop(h2) + b2)
    wt_kernel<<<64, 256, 0, stream>>>(W2, Wt);
    gemm2_mfma_kernel<<<(n + 127) / 128, 256, 0, stream>>>(out, Wt, sclshift, sclshift + 128, h, n);
    propagate_kernel<<<(n + 3) / 4, 256, 0, stream>>>(h, rowptr, edge_src, dinv, b2, out, n);
}

// Round 23
// 264.891 us; speedup vs baseline: 1.6631x; 1.0528x over previous
//
#include <hip/hip_runtime.h>
#include <stdint.h>

// ---------------------------------------------------------------------------
// 2-layer GCN: relu(gcn(x,W1,b1)) -> batchnorm -> relu(gcn(.,W2,b2))
// n=100000, E=1.6M, f_in=25, hid=128.
// R2 scan / R6 bf16+tile / R10 scatter / R14 pipelined gather / R15 MFMA /
// R18 zero-atomic CSR build / R19 commuted layer-1 / R21 BN-fusion (282->279).
// R22: (a) REVERT propagate to R20 scalar-uint 8-deep (R21's uint2 variant
//     regressed 68.4->75: per-lane-varying shfl index => ds_bpermute instead
//     of broadcast readlane, + VGPR 28->36 occupancy drop).
//     (b) y1 intermediate stored bf16 (gemm1 writes bf16; gemm2 stages from
//     bf16) - saves ~51MB of fp32 stream between the two GEMMs.
// R23: resubmit — R22 bench died on the unresponsive container (infra).
// ---------------------------------------------------------------------------

#define HID 128
#define NBB 512          // binning blocks (power of 2; segment index j = q*512+b)

typedef short bf16x8 __attribute__((ext_vector_type(8)));
typedef float f32x4 __attribute__((ext_vector_type(4)));

__device__ __forceinline__ unsigned short f2bf(float f) {
    unsigned int u = __float_as_uint(f);
    unsigned int r = (u + 0x7FFFu + ((u >> 16) & 1u)) >> 16;  // RNE
    return (unsigned short)r;
}
__device__ __forceinline__ unsigned int pack2bf(float lo, float hi) {
    return (unsigned int)f2bf(lo) | ((unsigned int)f2bf(hi) << 16);
}
__device__ __forceinline__ float bflo(unsigned int v) { return __uint_as_float(v << 16); }
__device__ __forceinline__ float bfhi(unsigned int v) { return __uint_as_float(v & 0xffff0000u); }

// --- detect whether edge_index buffer is int64 or int32 --------------------
__global__ void detect_kernel(const unsigned int* __restrict__ w, int* __restrict__ mode, int nwords) {
    __shared__ int any;
    if (threadIdx.x == 0) any = 0;
    __syncthreads();
    for (int i = threadIdx.x * 2 + 1; i < nwords && i < 8192; i += 512) {
        if (w[i] != 0) atomicOr(&any, 1);
    }
    __syncthreads();
    if (threadIdx.x == 0) *mode = any ? 0 : 1;  // 1 => int64 layout
}

__device__ __forceinline__ int load_idx(const void* ei, size_t i, int mode) {
    return mode ? (int)((const long long*)ei)[i] : ((const int*)ei)[i];
}

// --- count_q: per-(block, 256-node-chunk) tallies, LDS only ----------------
__global__ __launch_bounds__(256) void count_q_kernel(const void* __restrict__ ei,
                                                      const int* __restrict__ modep,
                                                      int* __restrict__ qcnt,
                                                      int E, int CHUNK, int nchunk) {
    __shared__ int qc[512];
    for (int i = threadIdx.x; i < nchunk; i += 256) qc[i] = 0;
    __syncthreads();
    int mode = *modep;
    int beg = blockIdx.x * CHUNK;
    int end = beg + CHUNK; if (end > E) end = E;
    for (int e = beg + threadIdx.x; e < end; e += 256) {
        int c = load_idx(ei, (size_t)E + e, mode);
        atomicAdd(&qc[c >> 8], 1);       // LDS atomic
    }
    __syncthreads();
    for (int i = threadIdx.x; i < nchunk; i += 256)
        qcnt[blockIdx.x * nchunk + i] = qc[i];   // b-major storage, coalesced
}

// --- scan_q phase 1: partial sums over scan-order positions ----------------
// scan order j = q*NBB + b  (q-major);  qcnt stored b-major: qcnt[b*nchunk+q]
__global__ __launch_bounds__(256) void scanq_partial_kernel(const int* __restrict__ qcnt,
                                                            int* __restrict__ blocksum,
                                                            int NQ, int nchunk) {
    int j0 = blockIdx.x * 2048 + threadIdx.x * 8;
    int s = 0;
    #pragma unroll
    for (int i = 0; i < 8; ++i) {
        int j = j0 + i;
        if (j < NQ) {
            int q = j >> 9, b = j & (NBB - 1);
            s += qcnt[b * nchunk + q];
        }
    }
    #pragma unroll
    for (int off = 32; off > 0; off >>= 1) s += __shfl_down(s, off);
    __shared__ int ls[4];
    if ((threadIdx.x & 63) == 0) ls[threadIdx.x >> 6] = s;
    __syncthreads();
    if (threadIdx.x == 0) blocksum[blockIdx.x] = ls[0] + ls[1] + ls[2] + ls[3];
}

// --- scan_q phase 2: scan block sums (nsb <= 1024) -------------------------
__global__ __launch_bounds__(1024) void scanq_blocksums_kernel(const int* __restrict__ blocksum,
                                                               int* __restrict__ blockoff,
                                                               int* __restrict__ qoff,
                                                               int nsb, int NQ) {
    __shared__ int s[1024];
    int t = threadIdx.x;
    int own = (t < nsb) ? blocksum[t] : 0;
    s[t] = own;
    __syncthreads();
    for (int off = 1; off < 1024; off <<= 1) {
        int v = s[t] + ((t >= off) ? s[t - off] : 0);
        __syncthreads();
        s[t] = v;
        __syncthreads();
    }
    if (t < nsb) blockoff[t] = s[t] - own;   // exclusive
    if (t == 1023) qoff[NQ] = s[1023];       // total == E
}

// --- scan_q phase 3: per-position exclusive prefix -> qoff -----------------
__global__ __launch_bounds__(256) void scanq_finalize_kernel(const int* __restrict__ qcnt,
                                                             const int* __restrict__ blockoff,
                                                             int* __restrict__ qoff,
                                                             int NQ, int nchunk) {
    int t = threadIdx.x;
    int j0 = blockIdx.x * 2048 + t * 8;
    int v[8], own = 0;
    #pragma unroll
    for (int i = 0; i < 8; ++i) {
        int j = j0 + i;
        v[i] = 0;
        if (j < NQ) {
            int q = j >> 9, b = j & (NBB - 1);
            v[i] = qcnt[b * nchunk + q];
        }
        own += v[i];
    }
    __shared__ int s[256];
    s[t] = own;
    __syncthreads();
    for (int off = 1; off < 256; off <<= 1) {
        int x = s[t] + ((t >= off) ? s[t - off] : 0);
        __syncthreads();
        s[t] = x;
        __syncthreads();
    }
    int e = blockoff[blockIdx.x] + s[t] - own;
    #pragma unroll
    for (int i = 0; i < 8; ++i) {
        int j = j0 + i;
        if (j < NQ) qoff[j] = e;
        e += v[i];
    }
}

// --- bin: append packed (c&255)<<24 | r into private segments (LDS cursors)-
__global__ __launch_bounds__(256) void bin_kernel(const void* __restrict__ ei,
                                                  const int* __restrict__ modep,
                                                  const int* __restrict__ qoff,
                                                  unsigned int* __restrict__ packed,
                                                  int E, int CHUNK, int nchunk) {
    __shared__ int cur[512];
    for (int i = threadIdx.x; i < nchunk; i += 256)
        cur[i] = qoff[i * NBB + blockIdx.x];
    __syncthreads();
    int mode = *modep;
    int beg = blockIdx.x * CHUNK;
    int end = beg + CHUNK; if (end > E) end = E;
    for (int e = beg + threadIdx.x; e < end; e += 256) {
        int c = load_idx(ei, (size_t)E + e, mode);
        int r = load_idx(ei, (size_t)e, mode);
        int pos = atomicAdd(&cur[c >> 8], 1);    // LDS atomic
        packed[pos] = ((unsigned)(c & 255) << 24) | (unsigned)r;
    }
}

// --- chunk_build: per-chunk histogram + scan -> rowptr/dinv, then place ----
__global__ __launch_bounds__(256) void chunk_build_kernel(
    const unsigned int* __restrict__ packed, const int* __restrict__ qoff,
    int* __restrict__ rowptr, float* __restrict__ dinv,
    int* __restrict__ edge_src, int n, int E) {
    int q = blockIdx.x;
    int t = threadIdx.x;
    int pbeg = qoff[q * NBB];
    int pend = qoff[(q + 1) * NBB];   // last chunk: (q+1)*NBB == NQ, qoff[NQ]=E
    __shared__ int cnt256[256], cur[256], s[256];
    cnt256[t] = 0;
    __syncthreads();
    for (int i = pbeg + t; i < pend; i += 256)
        atomicAdd(&cnt256[packed[i] >> 24], 1);  // LDS atomic
    __syncthreads();
    int own = cnt256[t];
    s[t] = own;
    __syncthreads();
    for (int off = 1; off < 256; off <<= 1) {
        int x = s[t] + ((t >= off) ? s[t - off] : 0);
        __syncthreads();
        s[t] = x;
        __syncthreads();
    }
    int pref = s[t] - own;   // exclusive within chunk
    int node = (q << 8) + t;
    if (node < n) {
        rowptr[node] = pbeg + pref;
        dinv[node] = rsqrtf((float)(own + 1));   // +1 self loop
    }
    cur[t] = pbeg + pref;
    if (q == gridDim.x - 1 && t == 0) rowptr[n] = E;
    __syncthreads();
    for (int i = pbeg + t; i < pend; i += 256) {
        unsigned int u = packed[i];
        int pos = atomicAdd(&cur[u >> 24], 1);   // LDS atomic
        edge_src[pos] = (int)(u & 0xFFFFFFu);
    }
}

// --- xpad: x fp32 [n][25] -> bf16 [n][32] (zero-padded) --------------------
__global__ __launch_bounds__(256) void xpad_kernel(const float* __restrict__ x,
                                                   unsigned int* __restrict__ xp, int n) {
    int r = blockIdx.x * 256 + threadIdx.x;
    if (r >= n) return;
    const float* xr = x + (size_t)r * 25;
    unsigned int* o = xp + (size_t)r * 16;
    #pragma unroll
    for (int j = 0; j < 12; ++j)
        o[j] = pack2bf(xr[j * 2], xr[j * 2 + 1]);
    o[12] = pack2bf(xr[24], 0.f);
    o[13] = 0u; o[14] = 0u; o[15] = 0u;
}

// --- prop_x: y0 = dinv[c]*(sum_e x[r]*dinv[r] + x[c]*dinv[c]) in 32-dim ----
__global__ __launch_bounds__(256) void prop_x_kernel(
    const unsigned int* __restrict__ xp, const int* __restrict__ rowptr,
    const int* __restrict__ edge_src, const float* __restrict__ dinv,
    unsigned int* __restrict__ y0, int n) {
    int wid = (blockIdx.x * 256 + threadIdx.x) >> 6;
    if (wid >= n) return;
    int lane = threadIdx.x & 63;
    int g = lane >> 4, i = lane & 15;
    int beg = rowptr[wid], end = rowptr[wid + 1];
    float dc = dinv[wid];
    float ax = 0.f, ay = 0.f;
    for (int b = beg; b < end; b += 64) {
        int m = end - b; if (m > 64) m = 64;
        int s = 0; float w = 0.f;
        if (lane < m) { s = edge_src[b + lane]; w = dinv[s]; }
        int nsteps = (m + 3) >> 2;
        for (int t = 0; t < nsteps; ++t) {
            int e = 4 * t + g;
            int sj = __shfl(s, e & 63);
            float wj = __shfl(w, e & 63);
            if (e >= m) { sj = 0; wj = 0.f; }
            unsigned int u = xp[(size_t)sj * 16 + i];
            ax = fmaf(bflo(u), wj, ax);
            ay = fmaf(bfhi(u), wj, ay);
        }
    }
    if (g == 0) {   // self loop, once
        unsigned int u = xp[(size_t)wid * 16 + i];
        ax = fmaf(bflo(u), dc, ax);
        ay = fmaf(bfhi(u), dc, ay);
    }
    ax += __shfl_xor(ax, 16); ax += __shfl_xor(ax, 32);
    ay += __shfl_xor(ay, 16); ay += __shfl_xor(ay, 32);
    if (lane < 16)
        y0[(size_t)wid * 16 + i] = pack2bf(ax * dc, ay * dc);
}

// --- GEMM1 + fused BN stats: y1 = bf16(relu(y0@W1 + b1)); sum/sumsq fp32 ---
__global__ __launch_bounds__(256) void gemm1_kernel(const unsigned int* __restrict__ y0,
                                                    const float* __restrict__ W,
                                                    const float* __restrict__ bias,
                                                    unsigned short* __restrict__ y1,
                                                    float* __restrict__ bnsum,
                                                    float* __restrict__ bnsumsq, int n) {
    __shared__ float lw[25 * HID];
    for (int i = threadIdx.x; i < 25 * HID; i += 256) lw[i] = W[i];
    __syncthreads();
    int g = threadIdx.x >> 7, c = threadIdx.x & 127;
    float bc = bias[c];
    float s = 0.f, s2 = 0.f;
    for (int r = blockIdx.x * 2 + g; r < n; r += gridDim.x * 2) {
        const unsigned int* yr = y0 + (size_t)r * 16;
        float acc = bc;
        #pragma unroll
        for (int j = 0; j < 12; ++j) {
            unsigned int u = yr[j];
            acc = fmaf(bflo(u), lw[(j * 2 + 0) * HID + c], acc);
            acc = fmaf(bfhi(u), lw[(j * 2 + 1) * HID + c], acc);
        }
        acc = fmaf(bflo(yr[12]), lw[24 * HID + c], acc);
        acc = fmaxf(acc, 0.f);
        y1[(size_t)r * HID + c] = f2bf(acc);
        s += acc;
        s2 = fmaf(acc, acc, s2);
    }
    __shared__ float ls[256], ls2[256];
    ls[threadIdx.x] = s; ls2[threadIdx.x] = s2;
    __syncthreads();
    if (threadIdx.x < 128) {
        atomicAdd(&bnsum[c], ls[threadIdx.x] + ls[threadIdx.x + 128]);
        atomicAdd(&bnsumsq[c], ls2[threadIdx.x] + ls2[threadIdx.x + 128]);
    }
}

// --- propagation (128-dim, layer 2): 8-way unrolled gather (R20 version) ---
__global__ __launch_bounds__(256) void propagate_kernel(
    const unsigned short* __restrict__ h, const int* __restrict__ rowptr,
    const int* __restrict__ edge_src, const float* __restrict__ dinv,
    const float* __restrict__ bias, float* __restrict__ out, int n) {
    int wid = (blockIdx.x * 256 + threadIdx.x) >> 6;
    if (wid >= n) return;
    int lane = threadIdx.x & 63;
    int beg = rowptr[wid], end = rowptr[wid + 1];
    float dc = dinv[wid];
    float ax = 0.f, ay = 0.f;
    const unsigned int* hp = (const unsigned int*)h;  // 64 uints per row
    for (int b = beg; b < end; b += 64) {
        int m = end - b; if (m > 64) m = 64;
        int s = 0; float w = 0.f;
        if (lane < m) { s = edge_src[b + lane]; w = dinv[s]; }
        int j = 0;
        for (; j + 8 <= m; j += 8) {
            int s0 = __shfl(s, j + 0), s1 = __shfl(s, j + 1);
            int s2 = __shfl(s, j + 2), s3 = __shfl(s, j + 3);
            int s4 = __shfl(s, j + 4), s5 = __shfl(s, j + 5);
            int s6 = __shfl(s, j + 6), s7 = __shfl(s, j + 7);
            unsigned int v0 = hp[(size_t)s0 * 64 + lane];
            unsigned int v1 = hp[(size_t)s1 * 64 + lane];
            unsigned int v2 = hp[(size_t)s2 * 64 + lane];
            unsigned int v3 = hp[(size_t)s3 * 64 + lane];
            unsigned int v4 = hp[(size_t)s4 * 64 + lane];
            unsigned int v5 = hp[(size_t)s5 * 64 + lane];
            unsigned int v6 = hp[(size_t)s6 * 64 + lane];
            unsigned int v7 = hp[(size_t)s7 * 64 + lane];
            float w0 = __shfl(w, j + 0), w1 = __shfl(w, j + 1);
            float w2 = __shfl(w, j + 2), w3 = __shfl(w, j + 3);
            float w4 = __shfl(w, j + 4), w5 = __shfl(w, j + 5);
            float w6 = __shfl(w, j + 6), w7 = __shfl(w, j + 7);
            ax = fmaf(bflo(v0), w0, ax); ay = fmaf(bfhi(v0), w0, ay);
            ax = fmaf(bflo(v1), w1, ax); ay = fmaf(bfhi(v1), w1, ay);
            ax = fmaf(bflo(v2), w2, ax); ay = fmaf(bfhi(v2), w2, ay);
            ax = fmaf(bflo(v3), w3, ax); ay = fmaf(bfhi(v3), w3, ay);
            ax = fmaf(bflo(v4), w4, ax); ay = fmaf(bfhi(v4), w4, ay);
            ax = fmaf(bflo(v5), w5, ax); ay = fmaf(bfhi(v5), w5, ay);
            ax = fmaf(bflo(v6), w6, ax); ay = fmaf(bfhi(v6), w6, ay);
            ax = fmaf(bflo(v7), w7, ax); ay = fmaf(bfhi(v7), w7, ay);
        }
        for (; j < m; ++j) {
            int sj = __shfl(s, j);
            float wj = __shfl(w, j);
            unsigned int v = hp[(size_t)sj * 64 + lane];
            ax = fmaf(bflo(v), wj, ax);
            ay = fmaf(bfhi(v), wj, ay);
        }
    }
    {   // self loop
        unsigned int v = hp[(size_t)wid * 64 + lane];
        ax = fmaf(bflo(v), dc, ax);
        ay = fmaf(bfhi(v), dc, ay);
    }
    float bx = bias[lane * 2], by = bias[lane * 2 + 1];
    ax = fmaxf(fmaf(ax, dc, bx), 0.f);
    ay = fmaxf(fmaf(ay, dc, by), 0.f);
    *(float2*)(out + (size_t)wid * HID + lane * 2) = make_float2(ax, ay);
}

__global__ void bn_finalize_kernel(const float* __restrict__ sum, const float* __restrict__ sumsq,
                                   const float* __restrict__ gamma, const float* __restrict__ beta,
                                   float* __restrict__ scale, float* __restrict__ shift, float inv_n) {
    int c = threadIdx.x;
    float mean = sum[c] * inv_n;
    float var = sumsq[c] * inv_n - mean * mean;
    float sc = gamma[c] * rsqrtf(var + 1e-5f);
    scale[c] = sc;
    shift[c] = beta[c] - mean * sc;
}

// --- W2 transpose + bf16 cast: Wt[c][k] = bf16(W2[k][c]) -------------------
__global__ __launch_bounds__(256) void wt_kernel(const float* __restrict__ W,
                                                 unsigned short* __restrict__ Wt) {
    int idx = blockIdx.x * 256 + threadIdx.x;
    int c = idx >> 7, k = idx & 127;
    Wt[c * 128 + k] = f2bf(W[k * 128 + c]);
}

// --- GEMM2 via MFMA: h2 = bf16(bn(y1) @ W2), K=128, y1 bf16 ----------------
__global__ __launch_bounds__(256) void gemm2_mfma_kernel(
    const unsigned short* __restrict__ yb, const unsigned short* __restrict__ Wt,
    const float* __restrict__ scale, const float* __restrict__ shift,
    unsigned short* __restrict__ out, int n) {
    __shared__ unsigned short lwt[128 * 136];
    __shared__ unsigned short ly[128 * 136];
    int t = threadIdx.x;
    int base = blockIdx.x * 128;

    // stage Wt: 128 rows x 128 bf16 (64 uints/row), coalesced; LDS stride 68 uints
    {
        const unsigned int* w32 = (const unsigned int*)Wt;
        unsigned int* l32 = (unsigned int*)lwt;
        #pragma unroll
        for (int i = 0; i < 32; ++i) {
            int idx = t + i * 256;
            int r = idx >> 6, cp = idx & 63;
            l32[r * 68 + cp] = w32[r * 64 + cp];
        }
    }
    // stage y tile (bf16 source) with BN fused: 2 threads/row, 64 k each
    {
        int r = t >> 1, hh = t & 1;
        int gr = base + r;
        unsigned int* l32 = (unsigned int*)ly;
        const uint4* yrow = (const uint4*)(yb + (size_t)gr * HID + hh * 64);
        #pragma unroll
        for (int j = 0; j < 8; ++j) {
            uint4 u = make_uint4(0u, 0u, 0u, 0u);
            if (gr < n) u = yrow[j];
            int gk = hh * 64 + j * 8;
            float a0 = fmaf(bflo(u.x), scale[gk + 0], shift[gk + 0]);
            float a1 = fmaf(bfhi(u.x), scale[gk + 1], shift[gk + 1]);
            float a2 = fmaf(bflo(u.y), scale[gk + 2], shift[gk + 2]);
            float a3 = fmaf(bfhi(u.y), scale[gk + 3], shift[gk + 3]);
            float a4 = fmaf(bflo(u.z), scale[gk + 4], shift[gk + 4]);
            float a5 = fmaf(bfhi(u.z), scale[gk + 5], shift[gk + 5]);
            float a6 = fmaf(bflo(u.w), scale[gk + 6], shift[gk + 6]);
            float a7 = fmaf(bfhi(u.w), scale[gk + 7], shift[gk + 7]);
            l32[r * 68 + hh * 32 + j * 4 + 0] = pack2bf(a0, a1);
            l32[r * 68 + hh * 32 + j * 4 + 1] = pack2bf(a2, a3);
            l32[r * 68 + hh * 32 + j * 4 + 2] = pack2bf(a4, a5);
            l32[r * 68 + hh * 32 + j * 4 + 3] = pack2bf(a6, a7);
        }
    }
    __syncthreads();

    int w = t >> 6, lane = t & 63;
    int li = lane & 15, lg = lane >> 4;
    f32x4 acc[2][8];
    #pragma unroll
    for (int a = 0; a < 2; ++a)
        #pragma unroll
        for (int b = 0; b < 8; ++b) acc[a][b] = (f32x4){0.f, 0.f, 0.f, 0.f};

    #pragma unroll
    for (int ks = 0; ks < 4; ++ks) {
        int kb = ks * 32 + lg * 8;
        bf16x8 af[2], bfr[8];
        #pragma unroll
        for (int rt = 0; rt < 2; ++rt)
            af[rt] = *(const bf16x8*)&ly[(w * 32 + rt * 16 + li) * 136 + kb];
        #pragma unroll
        for (int cf = 0; cf < 8; ++cf)
            bfr[cf] = *(const bf16x8*)&lwt[(cf * 16 + li) * 136 + kb];
        #pragma unroll
        for (int rt = 0; rt < 2; ++rt)
            #pragma unroll
            for (int cf = 0; cf < 8; ++cf)
                acc[rt][cf] = __builtin_amdgcn_mfma_f32_16x16x32_bf16(
                    af[rt], bfr[cf], acc[rt][cf], 0, 0, 0);
    }

    // epilogue: D row = (lane>>4)*4 + reg, col = cf*16 + (lane&15)
    #pragma unroll
    for (int rt = 0; rt < 2; ++rt) {
        #pragma unroll
        for (int reg = 0; reg < 4; ++reg) {
            int gr = base + w * 32 + rt * 16 + lg * 4 + reg;
            if (gr < n) {
                #pragma unroll
                for (int cf = 0; cf < 8; ++cf)
                    out[(size_t)gr * HID + cf * 16 + li] = f2bf(acc[rt][cf][reg]);
            }
        }
    }
}

extern "C" void kernel_launch(void* const* d_in, const int* in_sizes, int n_in,
                              void* d_out, int out_size, void* d_ws, size_t ws_size,
                              hipStream_t stream) {
    const float* x     = (const float*)d_in[0];
    const void*  ei    = d_in[1];
    const float* W1    = (const float*)d_in[2];
    const float* b1    = (const float*)d_in[3];
    const float* gamma = (const float*)d_in[4];
    const float* beta  = (const float*)d_in[5];
    const float* W2    = (const float*)d_in[6];
    const float* b2    = (const float*)d_in[7];
    float* out = (float*)d_out;

    const int f_in = 25;
    int n = in_sizes[0] / f_in;
    int E = in_sizes[1] / 2;
    int nchunk = (n + 255) >> 8;                 // 256-node chunks (391)
    int NQ = nchunk * NBB;                       // queue segments (200192)
    int nsb = (NQ + 2047) / 2048;                // scan blocks (98, <=1024)
    int CHUNK = (E + NBB - 1) / NBB;             // edges per bin block

    char* ws = (char*)d_ws;
    size_t off = 0;
    auto alloc = [&](size_t bytes) -> void* {
        void* p = ws + off;
        off += (bytes + 511) & ~(size_t)511;
        return p;
    };
    int*   rowptr    = (int*)alloc(((size_t)n + 1) * 4);
    float* dinv      = (float*)alloc((size_t)n * 4);
    int*   edge_src  = (int*)alloc((size_t)E * 4);
    unsigned int* packed = (unsigned int*)alloc((size_t)E * 4);
    int*   qcnt      = (int*)alloc((size_t)NQ * 4);
    int*   qoff      = (int*)alloc(((size_t)NQ + 1) * 4);
    int*   blocksum  = (int*)alloc((size_t)nsb * 4);
    int*   blockoff  = (int*)alloc((size_t)nsb * 4);
    float* bnacc     = (float*)alloc(256 * 4);   // sum[128] ++ sumsq[128]
    float* sclshift  = (float*)alloc(256 * 4);   // scale[128] ++ shift[128]
    int*   mode      = (int*)alloc(4);
    unsigned int* xp   = (unsigned int*)alloc((size_t)n * 16 * 4);   // bf16[n][32]
    unsigned int* y0   = (unsigned int*)alloc((size_t)n * 16 * 4);   // bf16[n][32]
    unsigned short* y1 = (unsigned short*)alloc((size_t)n * HID * 2);// bf16[n][128]
    unsigned short* Wt = (unsigned short*)alloc(128 * 128 * 2);      // bf16 W2^T
    unsigned short* h  = (unsigned short*)alloc((size_t)n * HID * 2);// bf16 h2

    hipMemsetAsync(bnacc, 0, 256 * 4, stream);

    detect_kernel<<<1, 256, 0, stream>>>((const unsigned int*)ei, mode, 2 * E);
    count_q_kernel<<<NBB, 256, 0, stream>>>(ei, mode, qcnt, E, CHUNK, nchunk);
    scanq_partial_kernel<<<nsb, 256, 0, stream>>>(qcnt, blocksum, NQ, nchunk);
    scanq_blocksums_kernel<<<1, 1024, 0, stream>>>(blocksum, blockoff, qoff, nsb, NQ);
    scanq_finalize_kernel<<<nsb, 256, 0, stream>>>(qcnt, blockoff, qoff, NQ, nchunk);
    bin_kernel<<<NBB, 256, 0, stream>>>(ei, mode, qoff, packed, E, CHUNK, nchunk);
    chunk_build_kernel<<<nchunk, 256, 0, stream>>>(packed, qoff, rowptr, dinv, edge_src, n, E);

    // layer 1 (commuted): y0 = A_hat@x ; y1 = bf16(relu(y0@W1 + b1)),
    // BN stats fused into gemm1
    xpad_kernel<<<(n + 255) / 256, 256, 0, stream>>>(x, xp, n);
    prop_x_kernel<<<(n + 3) / 4, 256, 0, stream>>>(xp, rowptr, edge_src, dinv, y0, n);
    gemm1_kernel<<<1024, 256, 0, stream>>>(y0, W1, b1, y1, bnacc, bnacc + 128, n);

    bn_finalize_kernel<<<1, 128, 0, stream>>>(bnacc, bnacc + 128, gamma, beta,
                                              sclshift, sclshift + 128, 1.0f / (float)n);

    // layer 2: h2 = bf16(bn(y1)@W2) via MFMA ; out = relu(prop(h2) + b2)
    wt_kernel<<<64, 256, 0, stream>>>(W2, Wt);
    gemm2_mfma_kernel<<<(n + 127) / 128, 256, 0, stream>>>(y1, Wt, sclshift, sclshift + 128, h, n);
    propagate_kernel<<<(n + 3) / 4, 256, 0, stream>>>(h, rowptr, edge_src, dinv, b2, out, n);
}

// Round 26
// 255.455 us; speedup vs baseline: 1.7245x; 1.0369x over previous
//
#include <hip/hip_runtime.h>
#include <stdint.h>

// ---------------------------------------------------------------------------
// 2-layer GCN: relu(gcn(x,W1,b1)) -> batchnorm -> relu(gcn(.,W2,b2))
// n=100000, E=1.6M, f_in=25, hid=128.
// R2 scan / R6 bf16+tile / R10 scatter / R14 pipelined gather / R15 MFMA /
// R18 zero-atomic build / R19 commuted layer-1 / R21 BN-fuse / R22 bf16 y1
// (-> 265us).
// R24: (a) propagate tail: lanes>=m hold s=0,w=0 and j+u<=63 always, so the
//     serial remainder loop is unneeded - run ceil(m/8) full 8-batches
//     (zeros self-mask). (b) prop_x+gemm1 fused into l1_kernel: butterfly
//     reduce gives every lane the y0 sums; uniform-shfl broadcast of the 25
//     feats; y1=relu(y0@W1+b1) from LDS W1. Kills the y0 12.8MB round-trip,
//     one launch, and one bf16 rounding.
// R25/R26: resubmits — benches died on the unresponsive container (infra).
// ---------------------------------------------------------------------------

#define HID 128
#define NBB 512          // binning blocks (power of 2; segment index j = q*512+b)

typedef short bf16x8 __attribute__((ext_vector_type(8)));
typedef float f32x4 __attribute__((ext_vector_type(4)));

__device__ __forceinline__ unsigned short f2bf(float f) {
    unsigned int u = __float_as_uint(f);
    unsigned int r = (u + 0x7FFFu + ((u >> 16) & 1u)) >> 16;  // RNE
    return (unsigned short)r;
}
__device__ __forceinline__ unsigned int pack2bf(float lo, float hi) {
    return (unsigned int)f2bf(lo) | ((unsigned int)f2bf(hi) << 16);
}
__device__ __forceinline__ float bflo(unsigned int v) { return __uint_as_float(v << 16); }
__device__ __forceinline__ float bfhi(unsigned int v) { return __uint_as_float(v & 0xffff0000u); }

// --- detect whether edge_index buffer is int64 or int32 --------------------
__global__ void detect_kernel(const unsigned int* __restrict__ w, int* __restrict__ mode, int nwords) {
    __shared__ int any;
    if (threadIdx.x == 0) any = 0;
    __syncthreads();
    for (int i = threadIdx.x * 2 + 1; i < nwords && i < 8192; i += 512) {
        if (w[i] != 0) atomicOr(&any, 1);
    }
    __syncthreads();
    if (threadIdx.x == 0) *mode = any ? 0 : 1;  // 1 => int64 layout
}

__device__ __forceinline__ int load_idx(const void* ei, size_t i, int mode) {
    return mode ? (int)((const long long*)ei)[i] : ((const int*)ei)[i];
}

// --- count_q: per-(block, 256-node-chunk) tallies, LDS only ----------------
__global__ __launch_bounds__(256) void count_q_kernel(const void* __restrict__ ei,
                                                      const int* __restrict__ modep,
                                                      int* __restrict__ qcnt,
                                                      int E, int CHUNK, int nchunk) {
    __shared__ int qc[512];
    for (int i = threadIdx.x; i < nchunk; i += 256) qc[i] = 0;
    __syncthreads();
    int mode = *modep;
    int beg = blockIdx.x * CHUNK;
    int end = beg + CHUNK; if (end > E) end = E;
    for (int e = beg + threadIdx.x; e < end; e += 256) {
        int c = load_idx(ei, (size_t)E + e, mode);
        atomicAdd(&qc[c >> 8], 1);       // LDS atomic
    }
    __syncthreads();
    for (int i = threadIdx.x; i < nchunk; i += 256)
        qcnt[blockIdx.x * nchunk + i] = qc[i];   // b-major storage, coalesced
}

// --- scan_q phase 1: partial sums over scan-order positions ----------------
// scan order j = q*NBB + b  (q-major);  qcnt stored b-major: qcnt[b*nchunk+q]
__global__ __launch_bounds__(256) void scanq_partial_kernel(const int* __restrict__ qcnt,
                                                            int* __restrict__ blocksum,
                                                            int NQ, int nchunk) {
    int j0 = blockIdx.x * 2048 + threadIdx.x * 8;
    int s = 0;
    #pragma unroll
    for (int i = 0; i < 8; ++i) {
        int j = j0 + i;
        if (j < NQ) {
            int q = j >> 9, b = j & (NBB - 1);
            s += qcnt[b * nchunk + q];
        }
    }
    #pragma unroll
    for (int off = 32; off > 0; off >>= 1) s += __shfl_down(s, off);
    __shared__ int ls[4];
    if ((threadIdx.x & 63) == 0) ls[threadIdx.x >> 6] = s;
    __syncthreads();
    if (threadIdx.x == 0) blocksum[blockIdx.x] = ls[0] + ls[1] + ls[2] + ls[3];
}

// --- scan_q phase 2: scan block sums (nsb <= 1024) -------------------------
__global__ __launch_bounds__(1024) void scanq_blocksums_kernel(const int* __restrict__ blocksum,
                                                               int* __restrict__ blockoff,
                                                               int* __restrict__ qoff,
                                                               int nsb, int NQ) {
    __shared__ int s[1024];
    int t = threadIdx.x;
    int own = (t < nsb) ? blocksum[t] : 0;
    s[t] = own;
    __syncthreads();
    for (int off = 1; off < 1024; off <<= 1) {
        int v = s[t] + ((t >= off) ? s[t - off] : 0);
        __syncthreads();
        s[t] = v;
        __syncthreads();
    }
    if (t < nsb) blockoff[t] = s[t] - own;   // exclusive
    if (t == 1023) qoff[NQ] = s[1023];       // total == E
}

// --- scan_q phase 3: per-position exclusive prefix -> qoff -----------------
__global__ __launch_bounds__(256) void scanq_finalize_kernel(const int* __restrict__ qcnt,
                                                             const int* __restrict__ blockoff,
                                                             int* __restrict__ qoff,
                                                             int NQ, int nchunk) {
    int t = threadIdx.x;
    int j0 = blockIdx.x * 2048 + t * 8;
    int v[8], own = 0;
    #pragma unroll
    for (int i = 0; i < 8; ++i) {
        int j = j0 + i;
        v[i] = 0;
        if (j < NQ) {
            int q = j >> 9, b = j & (NBB - 1);
            v[i] = qcnt[b * nchunk + q];
        }
        own += v[i];
    }
    __shared__ int s[256];
    s[t] = own;
    __syncthreads();
    for (int off = 1; off < 256; off <<= 1) {
        int x = s[t] + ((t >= off) ? s[t - off] : 0);
        __syncthreads();
        s[t] = x;
        __syncthreads();
    }
    int e = blockoff[blockIdx.x] + s[t] - own;
    #pragma unroll
    for (int i = 0; i < 8; ++i) {
        int j = j0 + i;
        if (j < NQ) qoff[j] = e;
        e += v[i];
    }
}

// --- bin: append packed (c&255)<<24 | r into private segments (LDS cursors)-
__global__ __launch_bounds__(256) void bin_kernel(const void* __restrict__ ei,
                                                  const int* __restrict__ modep,
                                                  const int* __restrict__ qoff,
                                                  unsigned int* __restrict__ packed,
                                                  int E, int CHUNK, int nchunk) {
    __shared__ int cur[512];
    for (int i = threadIdx.x; i < nchunk; i += 256)
        cur[i] = qoff[i * NBB + blockIdx.x];
    __syncthreads();
    int mode = *modep;
    int beg = blockIdx.x * CHUNK;
    int end = beg + CHUNK; if (end > E) end = E;
    for (int e = beg + threadIdx.x; e < end; e += 256) {
        int c = load_idx(ei, (size_t)E + e, mode);
        int r = load_idx(ei, (size_t)e, mode);
        int pos = atomicAdd(&cur[c >> 8], 1);    // LDS atomic
        packed[pos] = ((unsigned)(c & 255) << 24) | (unsigned)r;
    }
}

// --- chunk_build: per-chunk histogram + scan -> rowptr/dinv, then place ----
__global__ __launch_bounds__(256) void chunk_build_kernel(
    const unsigned int* __restrict__ packed, const int* __restrict__ qoff,
    int* __restrict__ rowptr, float* __restrict__ dinv,
    int* __restrict__ edge_src, int n, int E) {
    int q = blockIdx.x;
    int t = threadIdx.x;
    int pbeg = qoff[q * NBB];
    int pend = qoff[(q + 1) * NBB];   // last chunk: (q+1)*NBB == NQ, qoff[NQ]=E
    __shared__ int cnt256[256], cur[256], s[256];
    cnt256[t] = 0;
    __syncthreads();
    for (int i = pbeg + t; i < pend; i += 256)
        atomicAdd(&cnt256[packed[i] >> 24], 1);  // LDS atomic
    __syncthreads();
    int own = cnt256[t];
    s[t] = own;
    __syncthreads();
    for (int off = 1; off < 256; off <<= 1) {
        int x = s[t] + ((t >= off) ? s[t - off] : 0);
        __syncthreads();
        s[t] = x;
        __syncthreads();
    }
    int pref = s[t] - own;   // exclusive within chunk
    int node = (q << 8) + t;
    if (node < n) {
        rowptr[node] = pbeg + pref;
        dinv[node] = rsqrtf((float)(own + 1));   // +1 self loop
    }
    cur[t] = pbeg + pref;
    if (q == gridDim.x - 1 && t == 0) rowptr[n] = E;
    __syncthreads();
    for (int i = pbeg + t; i < pend; i += 256) {
        unsigned int u = packed[i];
        int pos = atomicAdd(&cur[u >> 24], 1);   // LDS atomic
        edge_src[pos] = (int)(u & 0xFFFFFFu);
    }
}

// --- xpad: x fp32 [n][25] -> bf16 [n][32] (zero-padded) --------------------
__global__ __launch_bounds__(256) void xpad_kernel(const float* __restrict__ x,
                                                   unsigned int* __restrict__ xp, int n) {
    int r = blockIdx.x * 256 + threadIdx.x;
    if (r >= n) return;
    const float* xr = x + (size_t)r * 25;
    unsigned int* o = xp + (size_t)r * 16;
    #pragma unroll
    for (int j = 0; j < 12; ++j)
        o[j] = pack2bf(xr[j * 2], xr[j * 2 + 1]);
    o[12] = pack2bf(xr[24], 0.f);
    o[13] = 0u; o[14] = 0u; o[15] = 0u;
}

// --- l1: fused y0 = A_hat@x (32-dim gather) ; y1 = bf16(relu(y0@W1+b1)) ----
// + BN stat accumulation. One wave per node (grid-stride, 4096 waves).
__global__ __launch_bounds__(256) void l1_kernel(
    const unsigned int* __restrict__ xp, const int* __restrict__ rowptr,
    const int* __restrict__ edge_src, const float* __restrict__ dinv,
    const float* __restrict__ W, const float* __restrict__ bias,
    unsigned short* __restrict__ y1, float* __restrict__ bnsum,
    float* __restrict__ bnsumsq, int n) {
    __shared__ float lw[25 * HID];
    __shared__ float lb[HID];
    for (int i = threadIdx.x; i < 25 * HID; i += 256) lw[i] = W[i];
    if (threadIdx.x < HID) lb[threadIdx.x] = bias[threadIdx.x];
    __syncthreads();
    int lane = threadIdx.x & 63;
    int g = lane >> 4, i = lane & 15;
    int wid0 = (blockIdx.x * 256 + threadIdx.x) >> 6;
    float s0 = 0.f, q0 = 0.f, s1 = 0.f, q1 = 0.f;   // bn partials c=lane, lane+64
    for (int node = wid0; node < n; node += 4096) {
        int beg = rowptr[node], end = rowptr[node + 1];
        float dc = dinv[node];
        float ax = 0.f, ay = 0.f;
        for (int b = beg; b < end; b += 64) {
            int m = end - b; if (m > 64) m = 64;
            int s = 0; float w = 0.f;
            if (lane < m) { s = edge_src[b + lane]; w = dinv[s]; }
            int nsteps = (m + 3) >> 2;
            for (int t = 0; t < nsteps; ++t) {
                int e = 4 * t + g;          // <=63 always; lanes>=m hold zeros
                int sj = __shfl(s, e);
                float wj = __shfl(w, e);
                unsigned int u = xp[(size_t)sj * 16 + i];
                ax = fmaf(bflo(u), wj, ax);
                ay = fmaf(bfhi(u), wj, ay);
            }
        }
        if (g == 0) {   // self loop, once
            unsigned int u = xp[(size_t)node * 16 + i];
            ax = fmaf(bflo(u), dc, ax);
            ay = fmaf(bfhi(u), dc, ay);
        }
        ax += __shfl_xor(ax, 16); ax += __shfl_xor(ax, 32);
        ay += __shfl_xor(ay, 16); ay += __shfl_xor(ay, 32);
        ax *= dc; ay *= dc;   // lane holds y0[2i], y0[2i+1] (fp32, no rounding)
        float acc0 = lb[lane], acc1 = lb[lane + 64];
        #pragma unroll
        for (int k = 0; k < 25; ++k) {
            float yk = (k & 1) ? __shfl(ay, k >> 1) : __shfl(ax, k >> 1);
            acc0 = fmaf(yk, lw[k * HID + lane], acc0);
            acc1 = fmaf(yk, lw[k * HID + lane + 64], acc1);
        }
        acc0 = fmaxf(acc0, 0.f);
        acc1 = fmaxf(acc1, 0.f);
        y1[(size_t)node * HID + lane] = f2bf(acc0);
        y1[(size_t)node * HID + lane + 64] = f2bf(acc1);
        s0 += acc0; q0 = fmaf(acc0, acc0, q0);
        s1 += acc1; q1 = fmaf(acc1, acc1, q1);
    }
    __shared__ float r0[256], r1[256], r2[256], r3[256];
    r0[threadIdx.x] = s0; r1[threadIdx.x] = q0;
    r2[threadIdx.x] = s1; r3[threadIdx.x] = q1;
    __syncthreads();
    if (threadIdx.x < 64) {
        int l = threadIdx.x;
        float a = r0[l] + r0[l + 64] + r0[l + 128] + r0[l + 192];
        float b = r1[l] + r1[l + 64] + r1[l + 128] + r1[l + 192];
        float c = r2[l] + r2[l + 64] + r2[l + 128] + r2[l + 192];
        float d = r3[l] + r3[l + 64] + r3[l + 128] + r3[l + 192];
        atomicAdd(&bnsum[l], a);
        atomicAdd(&bnsumsq[l], b);
        atomicAdd(&bnsum[l + 64], c);
        atomicAdd(&bnsumsq[l + 64], d);
    }
}

// --- propagation (128-dim, layer 2): full 8-batches (zeros self-mask) ------
__global__ __launch_bounds__(256) void propagate_kernel(
    const unsigned short* __restrict__ h, const int* __restrict__ rowptr,
    const int* __restrict__ edge_src, const float* __restrict__ dinv,
    const float* __restrict__ bias, float* __restrict__ out, int n) {
    int wid = (blockIdx.x * 256 + threadIdx.x) >> 6;
    if (wid >= n) return;
    int lane = threadIdx.x & 63;
    int beg = rowptr[wid], end = rowptr[wid + 1];
    float dc = dinv[wid];
    float ax = 0.f, ay = 0.f;
    const unsigned int* hp = (const unsigned int*)h;  // 64 uints per row
    for (int b = beg; b < end; b += 64) {
        int m = end - b; if (m > 64) m = 64;
        int s = 0; float w = 0.f;
        if (lane < m) { s = edge_src[b + lane]; w = dinv[s]; }
        // j+7 <= 63 always (j multiple of 8, j < m <= 64); lanes >= m are zero
        for (int j = 0; j < m; j += 8) {
            int s0 = __shfl(s, j + 0), s1 = __shfl(s, j + 1);
            int s2 = __shfl(s, j + 2), s3 = __shfl(s, j + 3);
            int s4 = __shfl(s, j + 4), s5 = __shfl(s, j + 5);
            int s6 = __shfl(s, j + 6), s7 = __shfl(s, j + 7);
            unsigned int v0 = hp[(size_t)s0 * 64 + lane];
            unsigned int v1 = hp[(size_t)s1 * 64 + lane];
            unsigned int v2 = hp[(size_t)s2 * 64 + lane];
            unsigned int v3 = hp[(size_t)s3 * 64 + lane];
            unsigned int v4 = hp[(size_t)s4 * 64 + lane];
            unsigned int v5 = hp[(size_t)s5 * 64 + lane];
            unsigned int v6 = hp[(size_t)s6 * 64 + lane];
            unsigned int v7 = hp[(size_t)s7 * 64 + lane];
            float w0 = __shfl(w, j + 0), w1 = __shfl(w, j + 1);
            float w2 = __shfl(w, j + 2), w3 = __shfl(w, j + 3);
            float w4 = __shfl(w, j + 4), w5 = __shfl(w, j + 5);
            float w6 = __shfl(w, j + 6), w7 = __shfl(w, j + 7);
            ax = fmaf(bflo(v0), w0, ax); ay = fmaf(bfhi(v0), w0, ay);
            ax = fmaf(bflo(v1), w1, ax); ay = fmaf(bfhi(v1), w1, ay);
            ax = fmaf(bflo(v2), w2, ax); ay = fmaf(bfhi(v2), w2, ay);
            ax = fmaf(bflo(v3), w3, ax); ay = fmaf(bfhi(v3), w3, ay);
            ax = fmaf(bflo(v4), w4, ax); ay = fmaf(bfhi(v4), w4, ay);
            ax = fmaf(bflo(v5), w5, ax); ay = fmaf(bfhi(v5), w5, ay);
            ax = fmaf(bflo(v6), w6, ax); ay = fmaf(bfhi(v6), w6, ay);
            ax = fmaf(bflo(v7), w7, ax); ay = fmaf(bfhi(v7), w7, ay);
        }
    }
    {   // self loop
        unsigned int v = hp[(size_t)wid * 64 + lane];
        ax = fmaf(bflo(v), dc, ax);
        ay = fmaf(bfhi(v), dc, ay);
    }
    float bx = bias[lane * 2], by = bias[lane * 2 + 1];
    ax = fmaxf(fmaf(ax, dc, bx), 0.f);
    ay = fmaxf(fmaf(ay, dc, by), 0.f);
    *(float2*)(out + (size_t)wid * HID + lane * 2) = make_float2(ax, ay);
}

__global__ void bn_finalize_kernel(const float* __restrict__ sum, const float* __restrict__ sumsq,
                                   const float* __restrict__ gamma, const float* __restrict__ beta,
                                   float* __restrict__ scale, float* __restrict__ shift, float inv_n) {
    int c = threadIdx.x;
    float mean = sum[c] * inv_n;
    float var = sumsq[c] * inv_n - mean * mean;
    float sc = gamma[c] * rsqrtf(var + 1e-5f);
    scale[c] = sc;
    shift[c] = beta[c] - mean * sc;
}

// --- W2 transpose + bf16 cast: Wt[c][k] = bf16(W2[k][c]) -------------------
__global__ __launch_bounds__(256) void wt_kernel(const float* __restrict__ W,
                                                 unsigned short* __restrict__ Wt) {
    int idx = blockIdx.x * 256 + threadIdx.x;
    int c = idx >> 7, k = idx & 127;
    Wt[c * 128 + k] = f2bf(W[k * 128 + c]);
}

// --- GEMM2 via MFMA: h2 = bf16(bn(y1) @ W2), K=128, y1 bf16 ----------------
__global__ __launch_bounds__(256) void gemm2_mfma_kernel(
    const unsigned short* __restrict__ yb, const unsigned short* __restrict__ Wt,
    const float* __restrict__ scale, const float* __restrict__ shift,
    unsigned short* __restrict__ out, int n) {
    __shared__ unsigned short lwt[128 * 136];
    __shared__ unsigned short ly[128 * 136];
    int t = threadIdx.x;
    int base = blockIdx.x * 128;

    {
        const unsigned int* w32 = (const unsigned int*)Wt;
        unsigned int* l32 = (unsigned int*)lwt;
        #pragma unroll
        for (int i = 0; i < 32; ++i) {
            int idx = t + i * 256;
            int r = idx >> 6, cp = idx & 63;
            l32[r * 68 + cp] = w32[r * 64 + cp];
        }
    }
    {
        int r = t >> 1, hh = t & 1;
        int gr = base + r;
        unsigned int* l32 = (unsigned int*)ly;
        const uint4* yrow = (const uint4*)(yb + (size_t)gr * HID + hh * 64);
        #pragma unroll
        for (int j = 0; j < 8; ++j) {
            uint4 u = make_uint4(0u, 0u, 0u, 0u);
            if (gr < n) u = yrow[j];
            int gk = hh * 64 + j * 8;
            float a0 = fmaf(bflo(u.x), scale[gk + 0], shift[gk + 0]);
            float a1 = fmaf(bfhi(u.x), scale[gk + 1], shift[gk + 1]);
            float a2 = fmaf(bflo(u.y), scale[gk + 2], shift[gk + 2]);
            float a3 = fmaf(bfhi(u.y), scale[gk + 3], shift[gk + 3]);
            float a4 = fmaf(bflo(u.z), scale[gk + 4], shift[gk + 4]);
            float a5 = fmaf(bfhi(u.z), scale[gk + 5], shift[gk + 5]);
            float a6 = fmaf(bflo(u.w), scale[gk + 6], shift[gk + 6]);
            float a7 = fmaf(bfhi(u.w), scale[gk + 7], shift[gk + 7]);
            l32[r * 68 + hh * 32 + j * 4 + 0] = pack2bf(a0, a1);
            l32[r * 68 + hh * 32 + j * 4 + 1] = pack2bf(a2, a3);
            l32[r * 68 + hh * 32 + j * 4 + 2] = pack2bf(a4, a5);
            l32[r * 68 + hh * 32 + j * 4 + 3] = pack2bf(a6, a7);
        }
    }
    __syncthreads();

    int w = t >> 6, lane = t & 63;
    int li = lane & 15, lg = lane >> 4;
    f32x4 acc[2][8];
    #pragma unroll
    for (int a = 0; a < 2; ++a)
        #pragma unroll
        for (int b = 0; b < 8; ++b) acc[a][b] = (f32x4){0.f, 0.f, 0.f, 0.f};

    #pragma unroll
    for (int ks = 0; ks < 4; ++ks) {
        int kb = ks * 32 + lg * 8;
        bf16x8 af[2], bfr[8];
        #pragma unroll
        for (int rt = 0; rt < 2; ++rt)
            af[rt] = *(const bf16x8*)&ly[(w * 32 + rt * 16 + li) * 136 + kb];
        #pragma unroll
        for (int cf = 0; cf < 8; ++cf)
            bfr[cf] = *(const bf16x8*)&lwt[(cf * 16 + li) * 136 + kb];
        #pragma unroll
        for (int rt = 0; rt < 2; ++rt)
            #pragma unroll
            for (int cf = 0; cf < 8; ++cf)
                acc[rt][cf] = __builtin_amdgcn_mfma_f32_16x16x32_bf16(
                    af[rt], bfr[cf], acc[rt][cf], 0, 0, 0);
    }

    #pragma unroll
    for (int rt = 0; rt < 2; ++rt) {
        #pragma unroll
        for (int reg = 0; reg < 4; ++reg) {
            int gr = base + w * 32 + rt * 16 + lg * 4 + reg;
            if (gr < n) {
                #pragma unroll
                for (int cf = 0; cf < 8; ++cf)
                    out[(size_t)gr * HID + cf * 16 + li] = f2bf(acc[rt][cf][reg]);
            }
        }
    }
}

extern "C" void kernel_launch(void* const* d_in, const int* in_sizes, int n_in,
                              void* d_out, int out_size, void* d_ws, size_t ws_size,
                              hipStream_t stream) {
    const float* x     = (const float*)d_in[0];
    const void*  ei    = d_in[1];
    const float* W1    = (const float*)d_in[2];
    const float* b1    = (const float*)d_in[3];
    const float* gamma = (const float*)d_in[4];
    const float* beta  = (const float*)d_in[5];
    const float* W2    = (const float*)d_in[6];
    const float* b2    = (const float*)d_in[7];
    float* out = (float*)d_out;

    const int f_in = 25;
    int n = in_sizes[0] / f_in;
    int E = in_sizes[1] / 2;
    int nchunk = (n + 255) >> 8;                 // 256-node chunks (391)
    int NQ = nchunk * NBB;                       // queue segments (200192)
    int nsb = (NQ + 2047) / 2048;                // scan blocks (98, <=1024)
    int CHUNK = (E + NBB - 1) / NBB;             // edges per bin block

    char* ws = (char*)d_ws;
    size_t off = 0;
    auto alloc = [&](size_t bytes) -> void* {
        void* p = ws + off;
        off += (bytes + 511) & ~(size_t)511;
        return p;
    };
    int*   rowptr    = (int*)alloc(((size_t)n + 1) * 4);
    float* dinv      = (float*)alloc((size_t)n * 4);
    int*   edge_src  = (int*)alloc((size_t)E * 4);
    unsigned int* packed = (unsigned int*)alloc((size_t)E * 4);
    int*   qcnt      = (int*)alloc((size_t)NQ * 4);
    int*   qoff      = (int*)alloc(((size_t)NQ + 1) * 4);
    int*   blocksum  = (int*)alloc((size_t)nsb * 4);
    int*   blockoff  = (int*)alloc((size_t)nsb * 4);
    float* bnacc     = (float*)alloc(256 * 4);   // sum[128] ++ sumsq[128]
    float* sclshift  = (float*)alloc(256 * 4);   // scale[128] ++ shift[128]
    int*   mode      = (int*)alloc(4);
    unsigned int* xp   = (unsigned int*)alloc((size_t)n * 16 * 4);   // bf16[n][32]
    unsigned short* y1 = (unsigned short*)alloc((size_t)n * HID * 2);// bf16[n][128]
    unsigned short* Wt = (unsigned short*)alloc(128 * 128 * 2);      // bf16 W2^T
    unsigned short* h  = (unsigned short*)alloc((size_t)n * HID * 2);// bf16 h2

    hipMemsetAsync(bnacc, 0, 256 * 4, stream);

    detect_kernel<<<1, 256, 0, stream>>>((const unsigned int*)ei, mode, 2 * E);
    count_q_kernel<<<NBB, 256, 0, stream>>>(ei, mode, qcnt, E, CHUNK, nchunk);
    scanq_partial_kernel<<<nsb, 256, 0, stream>>>(qcnt, blocksum, NQ, nchunk);
    scanq_blocksums_kernel<<<1, 1024, 0, stream>>>(blocksum, blockoff, qoff, nsb, NQ);
    scanq_finalize_kernel<<<nsb, 256, 0, stream>>>(qcnt, blockoff, qoff, NQ, nchunk);
    bin_kernel<<<NBB, 256, 0, stream>>>(ei, mode, qoff, packed, E, CHUNK, nchunk);
    chunk_build_kernel<<<nchunk, 256, 0, stream>>>(packed, qoff, rowptr, dinv, edge_src, n, E);

    // layer 1 (commuted, fused): y1 = bf16(relu((A_hat@x)@W1 + b1)) + BN stats
    xpad_kernel<<<(n + 255) / 256, 256, 0, stream>>>(x, xp, n);
    l1_kernel<<<1024, 256, 0, stream>>>(xp, rowptr, edge_src, dinv, W1, b1,
                                        y1, bnacc, bnacc + 128, n);

    bn_finalize_kernel<<<1, 128, 0, stream>>>(bnacc, bnacc + 128, gamma, beta,
                                              sclshift, sclshift + 128, 1.0f / (float)n);

    // layer 2: h2 = bf16(bn(y1)@W2) via MFMA ; out = relu(prop(h2) + b2)
    wt_kernel<<<64, 256, 0, stream>>>(W2, Wt);
    gemm2_mfma_kernel<<<(n + 127) / 128, 256, 0, stream>>>(y1, Wt, sclshift, sclshift + 128, h, n);
    propagate_kernel<<<(n + 3) / 4, 256, 0, stream>>>(h, rowptr, edge_src, dinv, b2, out, n);
}

// Round 27
// 253.240 us; speedup vs baseline: 1.7396x; 1.0087x over previous
//
#include <hip/hip_runtime.h>
#include <stdint.h>

// ---------------------------------------------------------------------------
// 2-layer GCN: relu(gcn(x,W1,b1)) -> batchnorm -> relu(gcn(.,W2,b2))
// n=100000, E=1.6M, f_in=25, hid=128.
// R2 scan / R6 bf16+tile / R10 scatter / R14 pipelined gather / R15 MFMA /
// R18 zero-atomic build / R19 commuted layer-1 / R21 BN-fuse / R22 bf16 y1 /
// R24 l1 fusion + propagate tail (265 -> 255).
// R27: l1_kernel was 103us: occupancy capped at 37% (grid 1024 = 4 blk/CU)
//     and ONE dependent gather in flight (R14 lesson lost). Fix: grid 2048
//     (8 blk/CU, 32 waves/CU) + 4-deep gather prefetch (shfl 4 (src,w)
//     pairs, 4 independent loads, then 8 FMAs; e<=63 & zero self-masking).
// ---------------------------------------------------------------------------

#define HID 128
#define NBB 512          // binning blocks (power of 2; segment index j = q*512+b)

typedef short bf16x8 __attribute__((ext_vector_type(8)));
typedef float f32x4 __attribute__((ext_vector_type(4)));

__device__ __forceinline__ unsigned short f2bf(float f) {
    unsigned int u = __float_as_uint(f);
    unsigned int r = (u + 0x7FFFu + ((u >> 16) & 1u)) >> 16;  // RNE
    return (unsigned short)r;
}
__device__ __forceinline__ unsigned int pack2bf(float lo, float hi) {
    return (unsigned int)f2bf(lo) | ((unsigned int)f2bf(hi) << 16);
}
__device__ __forceinline__ float bflo(unsigned int v) { return __uint_as_float(v << 16); }
__device__ __forceinline__ float bfhi(unsigned int v) { return __uint_as_float(v & 0xffff0000u); }

// --- detect whether edge_index buffer is int64 or int32 --------------------
__global__ void detect_kernel(const unsigned int* __restrict__ w, int* __restrict__ mode, int nwords) {
    __shared__ int any;
    if (threadIdx.x == 0) any = 0;
    __syncthreads();
    for (int i = threadIdx.x * 2 + 1; i < nwords && i < 8192; i += 512) {
        if (w[i] != 0) atomicOr(&any, 1);
    }
    __syncthreads();
    if (threadIdx.x == 0) *mode = any ? 0 : 1;  // 1 => int64 layout
}

__device__ __forceinline__ int load_idx(const void* ei, size_t i, int mode) {
    return mode ? (int)((const long long*)ei)[i] : ((const int*)ei)[i];
}

// --- count_q: per-(block, 256-node-chunk) tallies, LDS only ----------------
__global__ __launch_bounds__(256) void count_q_kernel(const void* __restrict__ ei,
                                                      const int* __restrict__ modep,
                                                      int* __restrict__ qcnt,
                                                      int E, int CHUNK, int nchunk) {
    __shared__ int qc[512];
    for (int i = threadIdx.x; i < nchunk; i += 256) qc[i] = 0;
    __syncthreads();
    int mode = *modep;
    int beg = blockIdx.x * CHUNK;
    int end = beg + CHUNK; if (end > E) end = E;
    for (int e = beg + threadIdx.x; e < end; e += 256) {
        int c = load_idx(ei, (size_t)E + e, mode);
        atomicAdd(&qc[c >> 8], 1);       // LDS atomic
    }
    __syncthreads();
    for (int i = threadIdx.x; i < nchunk; i += 256)
        qcnt[blockIdx.x * nchunk + i] = qc[i];   // b-major storage, coalesced
}

// --- scan_q phase 1: partial sums over scan-order positions ----------------
// scan order j = q*NBB + b  (q-major);  qcnt stored b-major: qcnt[b*nchunk+q]
__global__ __launch_bounds__(256) void scanq_partial_kernel(const int* __restrict__ qcnt,
                                                            int* __restrict__ blocksum,
                                                            int NQ, int nchunk) {
    int j0 = blockIdx.x * 2048 + threadIdx.x * 8;
    int s = 0;
    #pragma unroll
    for (int i = 0; i < 8; ++i) {
        int j = j0 + i;
        if (j < NQ) {
            int q = j >> 9, b = j & (NBB - 1);
            s += qcnt[b * nchunk + q];
        }
    }
    #pragma unroll
    for (int off = 32; off > 0; off >>= 1) s += __shfl_down(s, off);
    __shared__ int ls[4];
    if ((threadIdx.x & 63) == 0) ls[threadIdx.x >> 6] = s;
    __syncthreads();
    if (threadIdx.x == 0) blocksum[blockIdx.x] = ls[0] + ls[1] + ls[2] + ls[3];
}

// --- scan_q phase 2: scan block sums (nsb <= 1024) -------------------------
__global__ __launch_bounds__(1024) void scanq_blocksums_kernel(const int* __restrict__ blocksum,
                                                               int* __restrict__ blockoff,
                                                               int* __restrict__ qoff,
                                                               int nsb, int NQ) {
    __shared__ int s[1024];
    int t = threadIdx.x;
    int own = (t < nsb) ? blocksum[t] : 0;
    s[t] = own;
    __syncthreads();
    for (int off = 1; off < 1024; off <<= 1) {
        int v = s[t] + ((t >= off) ? s[t - off] : 0);
        __syncthreads();
        s[t] = v;
        __syncthreads();
    }
    if (t < nsb) blockoff[t] = s[t] - own;   // exclusive
    if (t == 1023) qoff[NQ] = s[1023];       // total == E
}

// --- scan_q phase 3: per-position exclusive prefix -> qoff -----------------
__global__ __launch_bounds__(256) void scanq_finalize_kernel(const int* __restrict__ qcnt,
                                                             const int* __restrict__ blockoff,
                                                             int* __restrict__ qoff,
                                                             int NQ, int nchunk) {
    int t = threadIdx.x;
    int j0 = blockIdx.x * 2048 + t * 8;
    int v[8], own = 0;
    #pragma unroll
    for (int i = 0; i < 8; ++i) {
        int j = j0 + i;
        v[i] = 0;
        if (j < NQ) {
            int q = j >> 9, b = j & (NBB - 1);
            v[i] = qcnt[b * nchunk + q];
        }
        own += v[i];
    }
    __shared__ int s[256];
    s[t] = own;
    __syncthreads();
    for (int off = 1; off < 256; off <<= 1) {
        int x = s[t] + ((t >= off) ? s[t - off] : 0);
        __syncthreads();
        s[t] = x;
        __syncthreads();
    }
    int e = blockoff[blockIdx.x] + s[t] - own;
    #pragma unroll
    for (int i = 0; i < 8; ++i) {
        int j = j0 + i;
        if (j < NQ) qoff[j] = e;
        e += v[i];
    }
}

// --- bin: append packed (c&255)<<24 | r into private segments (LDS cursors)-
__global__ __launch_bounds__(256) void bin_kernel(const void* __restrict__ ei,
                                                  const int* __restrict__ modep,
                                                  const int* __restrict__ qoff,
                                                  unsigned int* __restrict__ packed,
                                                  int E, int CHUNK, int nchunk) {
    __shared__ int cur[512];
    for (int i = threadIdx.x; i < nchunk; i += 256)
        cur[i] = qoff[i * NBB + blockIdx.x];
    __syncthreads();
    int mode = *modep;
    int beg = blockIdx.x * CHUNK;
    int end = beg + CHUNK; if (end > E) end = E;
    for (int e = beg + threadIdx.x; e < end; e += 256) {
        int c = load_idx(ei, (size_t)E + e, mode);
        int r = load_idx(ei, (size_t)e, mode);
        int pos = atomicAdd(&cur[c >> 8], 1);    // LDS atomic
        packed[pos] = ((unsigned)(c & 255) << 24) | (unsigned)r;
    }
}

// --- chunk_build: per-chunk histogram + scan -> rowptr/dinv, then place ----
__global__ __launch_bounds__(256) void chunk_build_kernel(
    const unsigned int* __restrict__ packed, const int* __restrict__ qoff,
    int* __restrict__ rowptr, float* __restrict__ dinv,
    int* __restrict__ edge_src, int n, int E) {
    int q = blockIdx.x;
    int t = threadIdx.x;
    int pbeg = qoff[q * NBB];
    int pend = qoff[(q + 1) * NBB];   // last chunk: (q+1)*NBB == NQ, qoff[NQ]=E
    __shared__ int cnt256[256], cur[256], s[256];
    cnt256[t] = 0;
    __syncthreads();
    for (int i = pbeg + t; i < pend; i += 256)
        atomicAdd(&cnt256[packed[i] >> 24], 1);  // LDS atomic
    __syncthreads();
    int own = cnt256[t];
    s[t] = own;
    __syncthreads();
    for (int off = 1; off < 256; off <<= 1) {
        int x = s[t] + ((t >= off) ? s[t - off] : 0);
        __syncthreads();
        s[t] = x;
        __syncthreads();
    }
    int pref = s[t] - own;   // exclusive within chunk
    int node = (q << 8) + t;
    if (node < n) {
        rowptr[node] = pbeg + pref;
        dinv[node] = rsqrtf((float)(own + 1));   // +1 self loop
    }
    cur[t] = pbeg + pref;
    if (q == gridDim.x - 1 && t == 0) rowptr[n] = E;
    __syncthreads();
    for (int i = pbeg + t; i < pend; i += 256) {
        unsigned int u = packed[i];
        int pos = atomicAdd(&cur[u >> 24], 1);   // LDS atomic
        edge_src[pos] = (int)(u & 0xFFFFFFu);
    }
}

// --- xpad: x fp32 [n][25] -> bf16 [n][32] (zero-padded) --------------------
__global__ __launch_bounds__(256) void xpad_kernel(const float* __restrict__ x,
                                                   unsigned int* __restrict__ xp, int n) {
    int r = blockIdx.x * 256 + threadIdx.x;
    if (r >= n) return;
    const float* xr = x + (size_t)r * 25;
    unsigned int* o = xp + (size_t)r * 16;
    #pragma unroll
    for (int j = 0; j < 12; ++j)
        o[j] = pack2bf(xr[j * 2], xr[j * 2 + 1]);
    o[12] = pack2bf(xr[24], 0.f);
    o[13] = 0u; o[14] = 0u; o[15] = 0u;
}

// --- l1: fused y0 = A_hat@x (32-dim gather, 4-deep prefetch) ;
// y1 = bf16(relu(y0@W1+b1)) + BN stats. Grid 2048 (8 blk/CU).
__global__ __launch_bounds__(256) void l1_kernel(
    const unsigned int* __restrict__ xp, const int* __restrict__ rowptr,
    const int* __restrict__ edge_src, const float* __restrict__ dinv,
    const float* __restrict__ W, const float* __restrict__ bias,
    unsigned short* __restrict__ y1, float* __restrict__ bnsum,
    float* __restrict__ bnsumsq, int n) {
    __shared__ float lw[25 * HID];
    __shared__ float lb[HID];
    for (int i = threadIdx.x; i < 25 * HID; i += 256) lw[i] = W[i];
    if (threadIdx.x < HID) lb[threadIdx.x] = bias[threadIdx.x];
    __syncthreads();
    int lane = threadIdx.x & 63;
    int g = lane >> 4, i = lane & 15;
    int wid0 = (blockIdx.x * 256 + threadIdx.x) >> 6;
    int nwaves = gridDim.x << 2;    // 4 waves per 256-thread block
    float s0 = 0.f, q0 = 0.f, s1 = 0.f, q1 = 0.f;   // bn partials c=lane, lane+64
    for (int node = wid0; node < n; node += nwaves) {
        int beg = rowptr[node], end = rowptr[node + 1];
        float dc = dinv[node];
        float ax = 0.f, ay = 0.f;
        for (int b = beg; b < end; b += 64) {
            int m = end - b; if (m > 64) m = 64;
            int s = 0; float w = 0.f;
            if (lane < m) { s = edge_src[b + lane]; w = dinv[s]; }
            int nsteps = (m + 3) >> 2;
            // 4-deep prefetch: t in {0,4,8,12}; e = 4t+g+{0,4,8,12} <= 63;
            // lanes >= m hold zeros (self-masking).
            for (int t = 0; t < nsteps; t += 4) {
                int e0 = 4 * t + g;
                int sj0 = __shfl(s, e0);
                int sj1 = __shfl(s, e0 + 4);
                int sj2 = __shfl(s, e0 + 8);
                int sj3 = __shfl(s, e0 + 12);
                unsigned int u0 = xp[(size_t)sj0 * 16 + i];
                unsigned int u1 = xp[(size_t)sj1 * 16 + i];
                unsigned int u2 = xp[(size_t)sj2 * 16 + i];
                unsigned int u3 = xp[(size_t)sj3 * 16 + i];
                float wj0 = __shfl(w, e0);
                float wj1 = __shfl(w, e0 + 4);
                float wj2 = __shfl(w, e0 + 8);
                float wj3 = __shfl(w, e0 + 12);
                ax = fmaf(bflo(u0), wj0, ax); ay = fmaf(bfhi(u0), wj0, ay);
                ax = fmaf(bflo(u1), wj1, ax); ay = fmaf(bfhi(u1), wj1, ay);
                ax = fmaf(bflo(u2), wj2, ax); ay = fmaf(bfhi(u2), wj2, ay);
                ax = fmaf(bflo(u3), wj3, ax); ay = fmaf(bfhi(u3), wj3, ay);
            }
        }
        if (g == 0) {   // self loop, once
            unsigned int u = xp[(size_t)node * 16 + i];
            ax = fmaf(bflo(u), dc, ax);
            ay = fmaf(bfhi(u), dc, ay);
        }
        ax += __shfl_xor(ax, 16); ax += __shfl_xor(ax, 32);
        ay += __shfl_xor(ay, 16); ay += __shfl_xor(ay, 32);
        ax *= dc; ay *= dc;   // lane holds y0[2i], y0[2i+1] (fp32)
        float acc0 = lb[lane], acc1 = lb[lane + 64];
        #pragma unroll
        for (int k = 0; k < 25; ++k) {
            float yk = (k & 1) ? __shfl(ay, k >> 1) : __shfl(ax, k >> 1);
            acc0 = fmaf(yk, lw[k * HID + lane], acc0);
            acc1 = fmaf(yk, lw[k * HID + lane + 64], acc1);
        }
        acc0 = fmaxf(acc0, 0.f);
        acc1 = fmaxf(acc1, 0.f);
        y1[(size_t)node * HID + lane] = f2bf(acc0);
        y1[(size_t)node * HID + lane + 64] = f2bf(acc1);
        s0 += acc0; q0 = fmaf(acc0, acc0, q0);
        s1 += acc1; q1 = fmaf(acc1, acc1, q1);
    }
    __shared__ float r0[256], r1[256], r2[256], r3[256];
    r0[threadIdx.x] = s0; r1[threadIdx.x] = q0;
    r2[threadIdx.x] = s1; r3[threadIdx.x] = q1;
    __syncthreads();
    if (threadIdx.x < 64) {
        int l = threadIdx.x;
        float a = r0[l] + r0[l + 64] + r0[l + 128] + r0[l + 192];
        float b = r1[l] + r1[l + 64] + r1[l + 128] + r1[l + 192];
        float c = r2[l] + r2[l + 64] + r2[l + 128] + r2[l + 192];
        float d = r3[l] + r3[l + 64] + r3[l + 128] + r3[l + 192];
        atomicAdd(&bnsum[l], a);
        atomicAdd(&bnsumsq[l], b);
        atomicAdd(&bnsum[l + 64], c);
        atomicAdd(&bnsumsq[l + 64], d);
    }
}

// --- propagation (128-dim, layer 2): full 8-batches (zeros self-mask) ------
__global__ __launch_bounds__(256) void propagate_kernel(
    const unsigned short* __restrict__ h, const int* __restrict__ rowptr,
    const int* __restrict__ edge_src, const float* __restrict__ dinv,
    const float* __restrict__ bias, float* __restrict__ out, int n) {
    int wid = (blockIdx.x * 256 + threadIdx.x) >> 6;
    if (wid >= n) return;
    int lane = threadIdx.x & 63;
    int beg = rowptr[wid], end = rowptr[wid + 1];
    float dc = dinv[wid];
    float ax = 0.f, ay = 0.f;
    const unsigned int* hp = (const unsigned int*)h;  // 64 uints per row
    for (int b = beg; b < end; b += 64) {
        int m = end - b; if (m > 64) m = 64;
        int s = 0; float w = 0.f;
        if (lane < m) { s = edge_src[b + lane]; w = dinv[s]; }
        // j+7 <= 63 always (j multiple of 8, j < m <= 64); lanes >= m are zero
        for (int j = 0; j < m; j += 8) {
            int s0 = __shfl(s, j + 0), s1 = __shfl(s, j + 1);
            int s2 = __shfl(s, j + 2), s3 = __shfl(s, j + 3);
            int s4 = __shfl(s, j + 4), s5 = __shfl(s, j + 5);
            int s6 = __shfl(s, j + 6), s7 = __shfl(s, j + 7);
            unsigned int v0 = hp[(size_t)s0 * 64 + lane];
            unsigned int v1 = hp[(size_t)s1 * 64 + lane];
            unsigned int v2 = hp[(size_t)s2 * 64 + lane];
            unsigned int v3 = hp[(size_t)s3 * 64 + lane];
            unsigned int v4 = hp[(size_t)s4 * 64 + lane];
            unsigned int v5 = hp[(size_t)s5 * 64 + lane];
            unsigned int v6 = hp[(size_t)s6 * 64 + lane];
            unsigned int v7 = hp[(size_t)s7 * 64 + lane];
            float w0 = __shfl(w, j + 0), w1 = __shfl(w, j + 1);
            float w2 = __shfl(w, j + 2), w3 = __shfl(w, j + 3);
            float w4 = __shfl(w, j + 4), w5 = __shfl(w, j + 5);
            float w6 = __shfl(w, j + 6), w7 = __shfl(w, j + 7);
            ax = fmaf(bflo(v0), w0, ax); ay = fmaf(bfhi(v0), w0, ay);
            ax = fmaf(bflo(v1), w1, ax); ay = fmaf(bfhi(v1), w1, ay);
            ax = fmaf(bflo(v2), w2, ax); ay = fmaf(bfhi(v2), w2, ay);
            ax = fmaf(bflo(v3), w3, ax); ay = fmaf(bfhi(v3), w3, ay);
            ax = fmaf(bflo(v4), w4, ax); ay = fmaf(bfhi(v4), w4, ay);
            ax = fmaf(bflo(v5), w5, ax); ay = fmaf(bfhi(v5), w5, ay);
            ax = fmaf(bflo(v6), w6, ax); ay = fmaf(bfhi(v6), w6, ay);
            ax = fmaf(bflo(v7), w7, ax); ay = fmaf(bfhi(v7), w7, ay);
        }
    }
    {   // self loop
        unsigned int v = hp[(size_t)wid * 64 + lane];
        ax = fmaf(bflo(v), dc, ax);
        ay = fmaf(bfhi(v), dc, ay);
    }
    float bx = bias[lane * 2], by = bias[lane * 2 + 1];
    ax = fmaxf(fmaf(ax, dc, bx), 0.f);
    ay = fmaxf(fmaf(ay, dc, by), 0.f);
    *(float2*)(out + (size_t)wid * HID + lane * 2) = make_float2(ax, ay);
}

__global__ void bn_finalize_kernel(const float* __restrict__ sum, const float* __restrict__ sumsq,
                                   const float* __restrict__ gamma, const float* __restrict__ beta,
                                   float* __restrict__ scale, float* __restrict__ shift, float inv_n) {
    int c = threadIdx.x;
    float mean = sum[c] * inv_n;
    float var = sumsq[c] * inv_n - mean * mean;
    float sc = gamma[c] * rsqrtf(var + 1e-5f);
    scale[c] = sc;
    shift[c] = beta[c] - mean * sc;
}

// --- W2 transpose + bf16 cast: Wt[c][k] = bf16(W2[k][c]) -------------------
__global__ __launch_bounds__(256) void wt_kernel(const float* __restrict__ W,
                                                 unsigned short* __restrict__ Wt) {
    int idx = blockIdx.x * 256 + threadIdx.x;
    int c = idx >> 7, k = idx & 127;
    Wt[c * 128 + k] = f2bf(W[k * 128 + c]);
}

// --- GEMM2 via MFMA: h2 = bf16(bn(y1) @ W2), K=128, y1 bf16 ----------------
__global__ __launch_bounds__(256) void gemm2_mfma_kernel(
    const unsigned short* __restrict__ yb, const unsigned short* __restrict__ Wt,
    const float* __restrict__ scale, const float* __restrict__ shift,
    unsigned short* __restrict__ out, int n) {
    __shared__ unsigned short lwt[128 * 136];
    __shared__ unsigned short ly[128 * 136];
    int t = threadIdx.x;
    int base = blockIdx.x * 128;

    {
        const unsigned int* w32 = (const unsigned int*)Wt;
        unsigned int* l32 = (unsigned int*)lwt;
        #pragma unroll
        for (int i = 0; i < 32; ++i) {
            int idx = t + i * 256;
            int r = idx >> 6, cp = idx & 63;
            l32[r * 68 + cp] = w32[r * 64 + cp];
        }
    }
    {
        int r = t >> 1, hh = t & 1;
        int gr = base + r;
        unsigned int* l32 = (unsigned int*)ly;
        const uint4* yrow = (const uint4*)(yb + (size_t)gr * HID + hh * 64);
        #pragma unroll
        for (int j = 0; j < 8; ++j) {
            uint4 u = make_uint4(0u, 0u, 0u, 0u);
            if (gr < n) u = yrow[j];
            int gk = hh * 64 + j * 8;
            float a0 = fmaf(bflo(u.x), scale[gk + 0], shift[gk + 0]);
            float a1 = fmaf(bfhi(u.x), scale[gk + 1], shift[gk + 1]);
            float a2 = fmaf(bflo(u.y), scale[gk + 2], shift[gk + 2]);
            float a3 = fmaf(bfhi(u.y), scale[gk + 3], shift[gk + 3]);
            float a4 = fmaf(bflo(u.z), scale[gk + 4], shift[gk + 4]);
            float a5 = fmaf(bfhi(u.z), scale[gk + 5], shift[gk + 5]);
            float a6 = fmaf(bflo(u.w), scale[gk + 6], shift[gk + 6]);
            float a7 = fmaf(bfhi(u.w), scale[gk + 7], shift[gk + 7]);
            l32[r * 68 + hh * 32 + j * 4 + 0] = pack2bf(a0, a1);
            l32[r * 68 + hh * 32 + j * 4 + 1] = pack2bf(a2, a3);
            l32[r * 68 + hh * 32 + j * 4 + 2] = pack2bf(a4, a5);
            l32[r * 68 + hh * 32 + j * 4 + 3] = pack2bf(a6, a7);
        }
    }
    __syncthreads();

    int w = t >> 6, lane = t & 63;
    int li = lane & 15, lg = lane >> 4;
    f32x4 acc[2][8];
    #pragma unroll
    for (int a = 0; a < 2; ++a)
        #pragma unroll
        for (int b = 0; b < 8; ++b) acc[a][b] = (f32x4){0.f, 0.f, 0.f, 0.f};

    #pragma unroll
    for (int ks = 0; ks < 4; ++ks) {
        int kb = ks * 32 + lg * 8;
        bf16x8 af[2], bfr[8];
        #pragma unroll
        for (int rt = 0; rt < 2; ++rt)
            af[rt] = *(const bf16x8*)&ly[(w * 32 + rt * 16 + li) * 136 + kb];
        #pragma unroll
        for (int cf = 0; cf < 8; ++cf)
            bfr[cf] = *(const bf16x8*)&lwt[(cf * 16 + li) * 136 + kb];
        #pragma unroll
        for (int rt = 0; rt < 2; ++rt)
            #pragma unroll
            for (int cf = 0; cf < 8; ++cf)
                acc[rt][cf] = __builtin_amdgcn_mfma_f32_16x16x32_bf16(
                    af[rt], bfr[cf], acc[rt][cf], 0, 0, 0);
    }

    #pragma unroll
    for (int rt = 0; rt < 2; ++rt) {
        #pragma unroll
        for (int reg = 0; reg < 4; ++reg) {
            int gr = base + w * 32 + rt * 16 + lg * 4 + reg;
            if (gr < n) {
                #pragma unroll
                for (int cf = 0; cf < 8; ++cf)
                    out[(size_t)gr * HID + cf * 16 + li] = f2bf(acc[rt][cf][reg]);
            }
        }
    }
}

extern "C" void kernel_launch(void* const* d_in, const int* in_sizes, int n_in,
                              void* d_out, int out_size, void* d_ws, size_t ws_size,
                              hipStream_t stream) {
    const float* x     = (const float*)d_in[0];
    const void*  ei    = d_in[1];
    const float* W1    = (const float*)d_in[2];
    const float* b1    = (const float*)d_in[3];
    const float* gamma = (const float*)d_in[4];
    const float* beta  = (const float*)d_in[5];
    const float* W2    = (const float*)d_in[6];
    const float* b2    = (const float*)d_in[7];
    float* out = (float*)d_out;

    const int f_in = 25;
    int n = in_sizes[0] / f_in;
    int E = in_sizes[1] / 2;
    int nchunk = (n + 255) >> 8;                 // 256-node chunks (391)
    int NQ = nchunk * NBB;                       // queue segments (200192)
    int nsb = (NQ + 2047) / 2048;                // scan blocks (98, <=1024)
    int CHUNK = (E + NBB - 1) / NBB;             // edges per bin block

    char* ws = (char*)d_ws;
    size_t off = 0;
    auto alloc = [&](size_t bytes) -> void* {
        void* p = ws + off;
        off += (bytes + 511) & ~(size_t)511;
        return p;
    };
    int*   rowptr    = (int*)alloc(((size_t)n + 1) * 4);
    float* dinv      = (float*)alloc((size_t)n * 4);
    int*   edge_src  = (int*)alloc((size_t)E * 4);
    unsigned int* packed = (unsigned int*)alloc((size_t)E * 4);
    int*   qcnt      = (int*)alloc((size_t)NQ * 4);
    int*   qoff      = (int*)alloc(((size_t)NQ + 1) * 4);
    int*   blocksum  = (int*)alloc((size_t)nsb * 4);
    int*   blockoff  = (int*)alloc((size_t)nsb * 4);
    float* bnacc     = (float*)alloc(256 * 4);   // sum[128] ++ sumsq[128]
    float* sclshift  = (float*)alloc(256 * 4);   // scale[128] ++ shift[128]
    int*   mode      = (int*)alloc(4);
    unsigned int* xp   = (unsigned int*)alloc((size_t)n * 16 * 4);   // bf16[n][32]
    unsigned short* y1 = (unsigned short*)alloc((size_t)n * HID * 2);// bf16[n][128]
    unsigned short* Wt = (unsigned short*)alloc(128 * 128 * 2);      // bf16 W2^T
    unsigned short* h  = (unsigned short*)alloc((size_t)n * HID * 2);// bf16 h2

    hipMemsetAsync(bnacc, 0, 256 * 4, stream);

    detect_kernel<<<1, 256, 0, stream>>>((const unsigned int*)ei, mode, 2 * E);
    count_q_kernel<<<NBB, 256, 0, stream>>>(ei, mode, qcnt, E, CHUNK, nchunk);
    scanq_partial_kernel<<<nsb, 256, 0, stream>>>(qcnt, blocksum, NQ, nchunk);
    scanq_blocksums_kernel<<<1, 1024, 0, stream>>>(blocksum, blockoff, qoff, nsb, NQ);
    scanq_finalize_kernel<<<nsb, 256, 0, stream>>>(qcnt, blockoff, qoff, NQ, nchunk);
    bin_kernel<<<NBB, 256, 0, stream>>>(ei, mode, qoff, packed, E, CHUNK, nchunk);
    chunk_build_kernel<<<nchunk, 256, 0, stream>>>(packed, qoff, rowptr, dinv, edge_src, n, E);

    // layer 1 (commuted, fused): y1 = bf16(relu((A_hat@x)@W1 + b1)) + BN stats
    xpad_kernel<<<(n + 255) / 256, 256, 0, stream>>>(x, xp, n);
    l1_kernel<<<2048, 256, 0, stream>>>(xp, rowptr, edge_src, dinv, W1, b1,
                                        y1, bnacc, bnacc + 128, n);

    bn_finalize_kernel<<<1, 128, 0, stream>>>(bnacc, bnacc + 128, gamma, beta,
                                              sclshift, sclshift + 128, 1.0f / (float)n);

    // layer 2: h2 = bf16(bn(y1)@W2) via MFMA ; out = relu(prop(h2) + b2)
    wt_kernel<<<64, 256, 0, stream>>>(W2, Wt);
    gemm2_mfma_kernel<<<(n + 127) / 128, 256, 0, stream>>>(y1, Wt, sclshift, sclshift + 128, h, n);
    propagate_kernel<<<(n + 3) / 4, 256, 0, stream>>>(h, rowptr, edge_src, dinv, b2, out, n);
}